// Round 6
// baseline (475.980 us; speedup 1.0000x reference)
//
#include <hip/hip_runtime.h>
#include <hip/hip_bf16.h>
#include <stdint.h>

// Bayesian MHA forward for MI355X (round 6).
// Attn: swapped QK^T (mfma(K,Q)) with permuted K-row feed so P lands in
// PV's A-fragment layout with ZERO cross-lane traffic; sP eliminated.
// LDS 48KB -> 3 blocks/CU. RBF x2 terms folded into the MFMA (split f16).
// All softmax math in exp2 domain.

#define D_MODEL 1024
#define NSEQ    1024
#define BATCH   8
#define NHEADS  16
#define DK      64
#define TOK     8192   // BATCH*NSEQ

typedef _Float16  h8  __attribute__((ext_vector_type(8)));
typedef float     f4  __attribute__((ext_vector_type(4)));

__device__ __forceinline__ f4 mfma_h(h8 a, h8 b, f4 c){
  return __builtin_amdgcn_mfma_f32_16x16x32_f16(a, b, c, 0, 0, 0);
}

// global -> LDS async copy, 16B per lane. LDS dest must be (uniform base + lane*16).
__device__ __forceinline__ void async_copy16(void* lds, const void* g){
  __builtin_amdgcn_global_load_lds(
      (const __attribute__((address_space(1))) unsigned int*)(uintptr_t)g,
      (__attribute__((address_space(3))) unsigned int*)(unsigned int)(uintptr_t)lds,
      16, 0, 0);
}

__device__ __forceinline__ float softplusf(float x){
  return (x > 20.f) ? x : log1pf(__expf(x));
}

// ---------------- prep kernels ----------------

// Hh = f16(H), H2h = f16(H*H)
__global__ __launch_bounds__(256) void prep_H(
    const float* __restrict__ in, _Float16* __restrict__ o, _Float16* __restrict__ sq, int n){
  int i = (blockIdx.x*256 + threadIdx.x)*4;
  if (i >= n) return;
  float4 v = *(const float4*)(in + i);
  float vv[4] = {v.x, v.y, v.z, v.w};
  #pragma unroll
  for (int j=0;j<4;j++){
    o[i+j]  = (_Float16)vv[j];
    sq[i+j] = (_Float16)(vv[j]*vv[j]);
  }
}

__global__ __launch_bounds__(256) void cast_f16(
    const float* __restrict__ in, _Float16* __restrict__ out, int n){
  int i = (blockIdx.x*256 + threadIdx.x)*4;
  if (i >= n) return;
  float4 v = *(const float4*)(in + i);
  out[i+0] = (_Float16)v.x; out[i+1] = (_Float16)v.y;
  out[i+2] = (_Float16)v.z; out[i+3] = (_Float16)v.w;
}

// out = f16(softplus(x)^2)
__global__ __launch_bounds__(256) void sp2_f16(
    const float* __restrict__ in, _Float16* __restrict__ out, int n){
  int i = (blockIdx.x*256 + threadIdx.x)*4;
  if (i >= n) return;
  float4 v = *(const float4*)(in + i);
  float vv[4] = {v.x, v.y, v.z, v.w};
  #pragma unroll
  for (int j=0;j<4;j++){ float s = softplusf(vv[j]); out[i+j] = (_Float16)(s*s); }
}

// xk[t][32] = [x(16), x2hi, x2lo, 1, 1, 0(12)]   (K-side RBF rows)
// xq[t][32] = [2x(16), -1, -1, -x2hi, -x2lo, 0(12)]  (Q-side RBF rows)
// => dot(xk[m], xq[q]) = 2*x_m.x_q - x2_m - x2_q = -dist2
__global__ __launch_bounds__(256) void prep_x(
    const float* __restrict__ x, _Float16* __restrict__ xk, _Float16* __restrict__ xq, int T){
  int t = blockIdx.x*256 + threadIdx.x;
  if (t >= T) return;
  const float* p = x + (size_t)t*16;
  _Float16 a[32], bb[32];
  float s = 0.f;
  #pragma unroll
  for (int j=0;j<16;j++){
    float f = p[j];
    a[j]  = (_Float16)f;
    bb[j] = (_Float16)(2.f*f);
    s += f*f;
  }
  _Float16 shi = (_Float16)s;
  _Float16 slo = (_Float16)(s - (float)shi);
  a[16]=shi; a[17]=slo; a[18]=(_Float16)1.f; a[19]=(_Float16)1.f;
  bb[16]=(_Float16)-1.f; bb[17]=(_Float16)-1.f; bb[18]=-shi; bb[19]=-slo;
  #pragma unroll
  for (int j=20;j<32;j++){ a[j]=(_Float16)0.f; bb[j]=(_Float16)0.f; }
  #pragma unroll
  for (int j=0;j<4;j++){
    *(h8*)(xk + (size_t)t*32 + j*8) = *(const h8*)&a[j*8];
    *(h8*)(xq + (size_t)t*32 + j*8) = *(const h8*)&bb[j*8];
  }
}

// ---------------- fused GEMM: C = A @ Wcat^T (+bias) ----------------
// MODE 0: projections. 4 segments of 1024 cols: Q, K, V, Vv.
//   A = Hh (segs 0-2) or H2h (seg 3). Outputs: Qh/Kh [row][col] f16,
//   Vt/Vvt transposed [b][col][row&1023] f16.
// MODE 1: outputs. 2 segments: out_mean (f32), out_var (f32, += addend in place).
// 128x128 tile, BK=32, 4 waves (2x2). XOR-swizzled LDS chunks. XCD block swizzle.
template<int MODE>
__global__ __launch_bounds__(256) void gemm_fused(
    const _Float16* __restrict__ A0, const _Float16* __restrict__ A1,
    const _Float16* __restrict__ Wcat,
    const float* __restrict__ bias0, const float* __restrict__ bias1,
    const float* __restrict__ bias2, const float* __restrict__ bias3,
    _Float16* __restrict__ Qo, _Float16* __restrict__ Ko,
    _Float16* __restrict__ Vto, _Float16* __restrict__ Vvto,
    float* __restrict__ meanO, float* __restrict__ varO)
{
  constexpr int NBN = (MODE==0) ? 32 : 16;     // n-tiles (4096 or 2048 cols)
  __shared__ _Float16 sA[128*32];
  __shared__ _Float16 sB[128*32];
  const int tid = threadIdx.x;
  const int lane = tid & 63;
  const int wid  = tid >> 6;
  const int wm = wid >> 1, wn = wid & 1;
  const int l15 = lane & 15, l4 = lane >> 4;
  const int nwg = 64*NBN;
  const int bid = blockIdx.x;
  const int swz = (bid & 7) * (nwg >> 3) + (bid >> 3);
  const int bm = swz / NBN, bn = swz % NBN;
  const int row0 = bm << 7, col0 = bn << 7;
  const int seg = col0 >> 10;

  const _Float16* A = (MODE==0) ? (seg < 3 ? A0 : A1) : (seg == 0 ? A0 : A1);
  const _Float16* B = Wcat + (size_t)col0 * 1024;

  f4 acc[4][4];
  #pragma unroll
  for (int i=0;i<4;i++)
    #pragma unroll
    for (int j=0;j<4;j++)
      #pragma unroll
      for (int r=0;r<4;r++) acc[i][j][r] = 0.f;

  const int c0 = tid, c1 = tid + 256;
  const int r0 = c0 >> 2, ch0 = c0 & 3;
  const int r1 = c1 >> 2, ch1 = c1 & 3;
  const int k0off = ((ch0 ^ (r0 & 3)) << 3);
  const int k1off = ((ch1 ^ (r1 & 3)) << 3);

  for (int kt = 0; kt < 1024; kt += 32){
    __syncthreads();
    async_copy16(&sA[c0*8], A + (size_t)(row0+r0)*1024 + kt + k0off);
    async_copy16(&sA[c1*8], A + (size_t)(row0+r1)*1024 + kt + k1off);
    async_copy16(&sB[c0*8], B + (size_t)r0*1024 + kt + k0off);
    async_copy16(&sB[c1*8], B + (size_t)r1*1024 + kt + k1off);
    __syncthreads();

    h8 a[4], b[4];
    #pragma unroll
    for (int mf=0; mf<4; mf++){
      int r  = (wm<<6) + (mf<<4) + l15;
      int ck = l4 ^ (r & 3);
      a[mf] = *(const h8*)&sA[r*32 + ck*8];
    }
    #pragma unroll
    for (int nf=0; nf<4; nf++){
      int r  = (wn<<6) + (nf<<4) + l15;
      int ck = l4 ^ (r & 3);
      b[nf] = *(const h8*)&sB[r*32 + ck*8];
    }
    #pragma unroll
    for (int mf=0; mf<4; mf++)
      #pragma unroll
      for (int nf=0; nf<4; nf++)
        acc[mf][nf] = mfma_h(a[mf], b[nf], acc[mf][nf]);
  }

  const float* bias = (MODE==0)
      ? (seg==0 ? bias0 : seg==1 ? bias1 : seg==2 ? bias2 : bias3)
      : (seg==0 ? bias0 : bias1);
  const bool sp2 = (MODE==0) ? (seg==3) : (seg==1);

  #pragma unroll
  for (int nf=0; nf<4; nf++){
    int colg = col0 + (wn<<6) + (nf<<4) + l15;
    int colm = colg & 1023;
    float bb = bias[colm];
    float bv = sp2 ? ({ float s = softplusf(bb); s*s; }) : bb;
    #pragma unroll
    for (int mf=0; mf<4; mf++){
      int rbase = row0 + (wm<<6) + (mf<<4) + (l4<<2);
      #pragma unroll
      for (int r=0;r<4;r++){
        int row = rbase + r;
        float v = acc[mf][nf][r] + bv;
        if (MODE==0){
          if (seg==0)      Qo[(size_t)row*1024 + colm] = (_Float16)v;
          else if (seg==1) Ko[(size_t)row*1024 + colm] = (_Float16)v;
          else {
            _Float16* T = (seg==2) ? Vto : Vvto;
            T[((size_t)(row>>10)<<20) + ((size_t)colm<<10) + (row & 1023)] = (_Float16)v;
          }
        } else {
          size_t idx = (size_t)row*1024 + colm;
          if (seg==0) meanO[idx] = v;
          else        varO[idx] = v + varO[idx];
        }
      }
    }
  }
}

// ---------------- fused attention (flash-style, + RBF scores) ----------------
// 1024 blocks = 8 q-tiles x (B*H), 4 waves x 32 q-rows. All-dbuf staging,
// ONE barrier/iter (lockstep blocks -> L2 reuse). Swapped QK^T with K-row
// permutation rho(fm,w) = (fm&1)*4 + (w&3) + (w>>2)*8 + (fm>>1)*32 so the
// score C-regs repack in-lane straight into PV's A-fragment k-slots.
__global__ __launch_bounds__(256, 3) void attn_kernel(
    const _Float16* __restrict__ Qh, const _Float16* __restrict__ Kh,
    const _Float16* __restrict__ Vt, const _Float16* __restrict__ Vvt,
    const _Float16* __restrict__ xk, const _Float16* __restrict__ xq,
    const float* __restrict__ log_sigma_f, const float* __restrict__ log_length,
    _Float16* __restrict__ ctx_out, _Float16* __restrict__ ctx2_out,
    float* __restrict__ var_out)
{
  const int bid = blockIdx.x;
  const int swz = (bid & 7) * 128 + (bid >> 3);
  const int qt = swz & 7;
  const int bh = swz >> 3;
  const int b  = bh >> 4, h = bh & 15;
  const int tid = threadIdx.x;
  const int lane = tid & 63, wid = tid >> 6;
  const int l15 = lane & 15, l4 = lane >> 4;
  const float L2E   = 1.44269504f;
  const float sig2l = __expf(2.f*log_sigma_f[h]) * L2E;     // sigma_f^2 * log2(e)
  const float e2c   = 0.5f*__expf(-2.f*log_length[h]) * L2E; // 1/(2 l^2) * log2(e)
  const float cqk   = 0.125f * L2E;

  __shared__ _Float16 sK[2][4096];   // [m][d] 64x64, g-swizzled
  __shared__ _Float16 sV[2][4096];   // [d][m]
  __shared__ _Float16 sVv[2][4096];  // [d][m]

  const int t0 = b*NSEQ + qt*128;
  const int wq = wid*32;

  // Q fragments (B-side: lane l15 = q-row)
  h8 qf[2][2];
  #pragma unroll
  for (int fq=0; fq<2; fq++)
    #pragma unroll
    for (int ks=0; ks<2; ks++){
      size_t off = (size_t)(t0 + wq + fq*16 + l15)*D_MODEL + h*DK + ks*32 + l4*8;
      qf[fq][ks] = *(const h8*)(Qh + off);
    }
  // RBF Q-side rows (full 32-slot padded vector, no branches)
  h8 xqf[2];
  #pragma unroll
  for (int fq=0; fq<2; fq++)
    xqf[fq] = *(const h8*)(xq + (size_t)(t0 + wq + fq*16 + l15)*32 + l4*8);

  h8 ones;
  #pragma unroll
  for (int j=0;j<8;j++) ones[j] = (_Float16)1.f;

  float mrun[2] = {-1e30f, -1e30f};   // log2 domain
  f4 lacc[2], ctx[2][4], var[2][4];
  #pragma unroll
  for (int fq=0; fq<2; fq++){
    #pragma unroll
    for (int r=0;r<4;r++) lacc[fq][r] = 0.f;
    #pragma unroll
    for (int fd=0; fd<4; fd++)
      #pragma unroll
      for (int r=0;r<4;r++){ ctx[fq][fd][r] = 0.f; var[fq][fd][r] = 0.f; }
  }

  // staging: 1536 chunks of 16B (K 512 w/ g-swizzle, V 512, Vv 512)
  auto stage = [&](int bi, int mt){
    #pragma unroll
    for (int k=0;k<6;k++){
      int c = tid + k*256;
      if (k < 2){
        int rg = c >> 3, ch = c & 7;
        int g  = (rg & 3) | (((rg >> 3) & 1) << 2);
        int sw = ((ch ^ g) << 3);
        async_copy16(&sK[bi][c*8], Kh + (size_t)(b*NSEQ + mt + rg)*D_MODEL + h*DK + sw);
      } else if (k < 4){
        int cc = c - 512; int rg = cc >> 3, sw = (((cc & 7) ^ (rg & 7)) << 3);
        async_copy16(&sV[bi][cc*8], Vt + ((size_t)b << 20) + (size_t)(h*DK + rg)*NSEQ + mt + sw);
      } else {
        int cc = c - 1024; int rg = cc >> 3, sw = (((cc & 7) ^ (rg & 7)) << 3);
        async_copy16(&sVv[bi][cc*8], Vvt + ((size_t)b << 20) + (size_t)(h*DK + rg)*NSEQ + mt + sw);
      }
    }
  };

  stage(0, 0);
  __syncthreads();

  for (int it = 0; it < NSEQ/64; it++){
    const int bi = it & 1;
    const int mt = it*64;
    if (it + 1 < NSEQ/64) stage(bi^1, mt + 64);

    // scores (swapped): S'[fq][fm][r] for m-row rho(fm, l4*4+r), q = l15
    f4 S[2][4];
    #pragma unroll
    for (int fm=0; fm<4; fm++){
      const int krow = ((fm&1)<<2) + (l15&3) + ((l15>>2)<<3) + ((fm>>1)<<5);
      const int g    = (krow & 3) | (((krow >> 3) & 1) << 2);
      h8 kb0 = *(const h8*)&sK[bi][krow*64 + ((l4      ^ g))*8];
      h8 kb1 = *(const h8*)&sK[bi][krow*64 + (((4+l4) ^ g))*8];
      h8 xkb = *(const h8*)(xk + (size_t)(b*NSEQ + mt + krow)*32 + l4*8);
      #pragma unroll
      for (int fq=0; fq<2; fq++){
        f4 s, xd;
        #pragma unroll
        for (int r=0;r<4;r++){ s[r]=0.f; xd[r]=0.f; }
        s  = mfma_h(kb0, qf[fq][0], s);
        s  = mfma_h(kb1, qf[fq][1], s);
        xd = mfma_h(xkb, xqf[fq], xd);            // = -dist2
        #pragma unroll
        for (int r=0;r<4;r++)
          S[fq][fm][r] = s[r]*cqk + sig2l*exp2f(fminf(xd[r],0.f)*e2c);
      }
    }

    // softmax (log2 domain), defer-max thr = 4*log2e = 5.77
    h8 pa[2][2];
    #pragma unroll
    for (int fq=0; fq<2; fq++){
      float tm = S[fq][0][0];
      #pragma unroll
      for (int fm=0; fm<4; fm++)
        #pragma unroll
        for (int r=0;r<4;r++) tm = fmaxf(tm, S[fq][fm][r]);
      tm = fmaxf(tm, __shfl_xor(tm, 16));
      tm = fmaxf(tm, __shfl_xor(tm, 32));
      int nd = tm > mrun[fq] + 5.7708f;
      if (__any(nd)){
        float mn = fmaxf(mrun[fq], tm);
        float sc = exp2f(mrun[fq] - mn);          // per q = l15
        mrun[fq] = mn;
        float scr[4];
        #pragma unroll
        for (int r=0;r<4;r++) scr[r] = __shfl(sc, (l4<<2) + r);  // q = l4*4+r
        #pragma unroll
        for (int r=0;r<4;r++) lacc[fq][r] *= scr[r];
        #pragma unroll
        for (int fd=0; fd<4; fd++)
          #pragma unroll
          for (int r=0;r<4;r++){
            ctx[fq][fd][r] *= scr[r];
            var[fq][fd][r] *= scr[r]*scr[r];
          }
      }
      // P = exp2(S' - m'); in-lane repack: slot(ks=fm>>1, j=(fm&1)*4+r) -> m = ks*32+l4*8+j
      #pragma unroll
      for (int fm=0; fm<4; fm++)
        #pragma unroll
        for (int r=0;r<4;r++)
          pa[fq][fm>>1][((fm&1)<<2) + r] = (_Float16)exp2f(S[fq][fm][r] - mrun[fq]);
    }

    // PV: ctx += P@V, var += P^2@Vv, l += P@1
    #pragma unroll
    for (int ks=0; ks<2; ks++){
      h8 pa2[2];
      #pragma unroll
      for (int fq=0; fq<2; fq++){
        pa2[fq] = pa[fq][ks]*pa[fq][ks];
        lacc[fq] = mfma_h(pa[fq][ks], ones, lacc[fq]);
      }
      #pragma unroll
      for (int fd=0; fd<4; fd++){
        int drow = fd*16 + l15;
        int ck = (ks*4 + l4) ^ (drow & 7);
        h8 vb  = *(const h8*)&sV[bi][drow*64 + ck*8];
        h8 vvb = *(const h8*)&sVv[bi][drow*64 + ck*8];
        #pragma unroll
        for (int fq=0; fq<2; fq++){
          ctx[fq][fd] = mfma_h(pa[fq][ks], vb,  ctx[fq][fd]);
          var[fq][fd] = mfma_h(pa2[fq],    vvb, var[fq][fd]);
        }
      }
    }
    __syncthreads();
  }

  // epilogue: normalize; write ctx/ctx^2 f16 + var f32 (line-grouped)
  #pragma unroll
  for (int fq=0; fq<2; fq++)
    #pragma unroll
    for (int r=0;r<4;r++){
      int t = t0 + wq + fq*16 + l4*4 + r;
      float linv = 1.f / lacc[fq][r];
      size_t base = (size_t)t*D_MODEL + h*DK + l15;
      float c[4];
      #pragma unroll
      for (int fd=0; fd<4; fd++) c[fd] = ctx[fq][fd][r] * linv;
      #pragma unroll
      for (int fd=0; fd<4; fd++) ctx_out[base + fd*16]  = (_Float16)c[fd];
      #pragma unroll
      for (int fd=0; fd<4; fd++) ctx2_out[base + fd*16] = (_Float16)(c[fd]*c[fd]);
      #pragma unroll
      for (int fd=0; fd<4; fd++) var_out[base + fd*16]  = var[fq][fd][r] * linv * linv;
    }
}

// ---------------- host launch ----------------

extern "C" void kernel_launch(void* const* d_in, const int* in_sizes, int n_in,
                              void* d_out, int out_size, void* d_ws, size_t ws_size,
                              hipStream_t stream){
  (void)in_sizes; (void)n_in; (void)out_size; (void)ws_size;
  const float* H      = (const float*)d_in[0];
  const float* x_raw  = (const float*)d_in[1];
  const float* Wq_mu  = (const float*)d_in[2];
  const float* bq_mu  = (const float*)d_in[4];
  const float* Wk_mu  = (const float*)d_in[6];
  const float* bk_mu  = (const float*)d_in[8];
  const float* Wv_mu  = (const float*)d_in[10];
  const float* Wv_rho = (const float*)d_in[11];
  const float* bv_mu  = (const float*)d_in[12];
  const float* bv_rho = (const float*)d_in[13];
  const float* Wo_mu  = (const float*)d_in[14];
  const float* Wo_rho = (const float*)d_in[15];
  const float* bo_mu  = (const float*)d_in[16];
  const float* bo_rho = (const float*)d_in[17];
  const float* lsf    = (const float*)d_in[18];
  const float* lln    = (const float*)d_in[19];

  char* ws = (char*)d_ws;
  const size_t MB = 1024*1024;
  _Float16* Hh    = (_Float16*)(ws + 0*MB);     // 16MB
  _Float16* H2h   = (_Float16*)(ws + 16*MB);    // 16MB
  _Float16* Wcat  = (_Float16*)(ws + 32*MB);    // 8MB: [Wq|Wk|Wv|Wvs2] rows
  _Float16* Wocat = (_Float16*)(ws + 40*MB);    // 4MB: [Wo|Wos2] rows
  _Float16* Qh    = (_Float16*)(ws + 46*MB);    // 16MB
  _Float16* Kh    = (_Float16*)(ws + 62*MB);    // 16MB
  _Float16* Vt    = (_Float16*)(ws + 78*MB);    // 16MB, transposed [b][o][n]
  _Float16* Vvt   = (_Float16*)(ws + 94*MB);    // 16MB
  _Float16* ctxh  = (_Float16*)(ws + 110*MB);   // 16MB
  _Float16* ctx2h = (_Float16*)(ws + 126*MB);   // 16MB
  _Float16* xk    = (_Float16*)(ws + 142*MB);   // 512KB
  _Float16* xqb   = (_Float16*)(ws + 142*MB + 512*1024);  // 512KB

  float* out_mean = (float*)d_out;
  float* out_var  = out_mean + (size_t)TOK*D_MODEL;

  const int TD = TOK*D_MODEL;
  const int DD = D_MODEL*D_MODEL;

  // prep
  prep_H  <<<TD/1024, 256, 0, stream>>>(H, Hh, H2h, TD);
  cast_f16<<<DD/1024, 256, 0, stream>>>(Wq_mu, Wcat, DD);
  cast_f16<<<DD/1024, 256, 0, stream>>>(Wk_mu, Wcat + (size_t)DD, DD);
  cast_f16<<<DD/1024, 256, 0, stream>>>(Wv_mu, Wcat + 2*(size_t)DD, DD);
  sp2_f16 <<<DD/1024, 256, 0, stream>>>(Wv_rho, Wcat + 3*(size_t)DD, DD);
  cast_f16<<<DD/1024, 256, 0, stream>>>(Wo_mu, Wocat, DD);
  sp2_f16 <<<DD/1024, 256, 0, stream>>>(Wo_rho, Wocat + (size_t)DD, DD);
  prep_x  <<<TOK/256, 256, 0, stream>>>(x_raw, xk, xqb, TOK);

  // fused projections: Q | K | V | Vv in one launch (grid 64 x 32)
  gemm_fused<0><<<2048, 256, 0, stream>>>(Hh, H2h, Wcat,
      bq_mu, bk_mu, bv_mu, bv_rho,
      Qh, Kh, Vt, Vvt, nullptr, nullptr);

  // attention (writes ctxh/ctx2h f16 and var_attn into out_var)
  attn_kernel<<<1024, 256, 0, stream>>>(Qh, Kh, Vt, Vvt, xk, xqb, lsf, lln,
      ctxh, ctx2h, out_var);

  // fused output projections: out_mean | out_var (grid 64 x 16)
  gemm_fused<1><<<1024, 256, 0, stream>>>(ctxh, ctx2h, Wocat,
      bo_mu, bo_rho, nullptr, nullptr,
      nullptr, nullptr, nullptr, nullptr, out_mean, out_var);
}

// Round 7
// 454.290 us; speedup vs baseline: 1.0477x; 1.0477x over previous
//
#include <hip/hip_runtime.h>
#include <hip/hip_bf16.h>
#include <stdint.h>

// Bayesian MHA forward for MI355X (round 7).
// r6 structure (swapped QK^T with permuted K-row feed; sP eliminated; exp2
// softmax; 48KB LDS) + fix: xk RBF fragments register-prefetched one KV-tile
// ahead (r6 read them in-loop from global -> dependent-stall, 244us).

#define D_MODEL 1024
#define NSEQ    1024
#define BATCH   8
#define NHEADS  16
#define DK      64
#define TOK     8192   // BATCH*NSEQ

typedef _Float16  h8  __attribute__((ext_vector_type(8)));
typedef float     f4  __attribute__((ext_vector_type(4)));

__device__ __forceinline__ f4 mfma_h(h8 a, h8 b, f4 c){
  return __builtin_amdgcn_mfma_f32_16x16x32_f16(a, b, c, 0, 0, 0);
}

// global -> LDS async copy, 16B per lane. LDS dest must be (uniform base + lane*16).
__device__ __forceinline__ void async_copy16(void* lds, const void* g){
  __builtin_amdgcn_global_load_lds(
      (const __attribute__((address_space(1))) unsigned int*)(uintptr_t)g,
      (__attribute__((address_space(3))) unsigned int*)(unsigned int)(uintptr_t)lds,
      16, 0, 0);
}

__device__ __forceinline__ float softplusf(float x){
  return (x > 20.f) ? x : log1pf(__expf(x));
}

// ---------------- prep kernels ----------------

// Hh = f16(H), H2h = f16(H*H)
__global__ __launch_bounds__(256) void prep_H(
    const float* __restrict__ in, _Float16* __restrict__ o, _Float16* __restrict__ sq, int n){
  int i = (blockIdx.x*256 + threadIdx.x)*4;
  if (i >= n) return;
  float4 v = *(const float4*)(in + i);
  float vv[4] = {v.x, v.y, v.z, v.w};
  #pragma unroll
  for (int j=0;j<4;j++){
    o[i+j]  = (_Float16)vv[j];
    sq[i+j] = (_Float16)(vv[j]*vv[j]);
  }
}

__global__ __launch_bounds__(256) void cast_f16(
    const float* __restrict__ in, _Float16* __restrict__ out, int n){
  int i = (blockIdx.x*256 + threadIdx.x)*4;
  if (i >= n) return;
  float4 v = *(const float4*)(in + i);
  out[i+0] = (_Float16)v.x; out[i+1] = (_Float16)v.y;
  out[i+2] = (_Float16)v.z; out[i+3] = (_Float16)v.w;
}

// out = f16(softplus(x)^2)
__global__ __launch_bounds__(256) void sp2_f16(
    const float* __restrict__ in, _Float16* __restrict__ out, int n){
  int i = (blockIdx.x*256 + threadIdx.x)*4;
  if (i >= n) return;
  float4 v = *(const float4*)(in + i);
  float vv[4] = {v.x, v.y, v.z, v.w};
  #pragma unroll
  for (int j=0;j<4;j++){ float s = softplusf(vv[j]); out[i+j] = (_Float16)(s*s); }
}

// xk[t][32] = [x(16), x2hi, x2lo, 1, 1, 0(12)]   (K-side RBF rows)
// xq[t][32] = [2x(16), -1, -1, -x2hi, -x2lo, 0(12)]  (Q-side RBF rows)
// => dot(xk[m], xq[q]) = 2*x_m.x_q - x2_m - x2_q = -dist2
__global__ __launch_bounds__(256) void prep_x(
    const float* __restrict__ x, _Float16* __restrict__ xk, _Float16* __restrict__ xq, int T){
  int t = blockIdx.x*256 + threadIdx.x;
  if (t >= T) return;
  const float* p = x + (size_t)t*16;
  _Float16 a[32], bb[32];
  float s = 0.f;
  #pragma unroll
  for (int j=0;j<16;j++){
    float f = p[j];
    a[j]  = (_Float16)f;
    bb[j] = (_Float16)(2.f*f);
    s += f*f;
  }
  _Float16 shi = (_Float16)s;
  _Float16 slo = (_Float16)(s - (float)shi);
  a[16]=shi; a[17]=slo; a[18]=(_Float16)1.f; a[19]=(_Float16)1.f;
  bb[16]=(_Float16)-1.f; bb[17]=(_Float16)-1.f; bb[18]=-shi; bb[19]=-slo;
  #pragma unroll
  for (int j=20;j<32;j++){ a[j]=(_Float16)0.f; bb[j]=(_Float16)0.f; }
  #pragma unroll
  for (int j=0;j<4;j++){
    *(h8*)(xk + (size_t)t*32 + j*8) = *(const h8*)&a[j*8];
    *(h8*)(xq + (size_t)t*32 + j*8) = *(const h8*)&bb[j*8];
  }
}

// ---------------- fused GEMM: C = A @ Wcat^T (+bias) ----------------
// MODE 0: projections. 4 segments of 1024 cols: Q, K, V, Vv.
//   A = Hh (segs 0-2) or H2h (seg 3). Outputs: Qh/Kh [row][col] f16,
//   Vt/Vvt transposed [b][col][row&1023] f16.
// MODE 1: outputs. 2 segments: out_mean (f32), out_var (f32, += addend in place).
// 128x128 tile, BK=32, 4 waves (2x2). XOR-swizzled LDS chunks. XCD block swizzle.
template<int MODE>
__global__ __launch_bounds__(256) void gemm_fused(
    const _Float16* __restrict__ A0, const _Float16* __restrict__ A1,
    const _Float16* __restrict__ Wcat,
    const float* __restrict__ bias0, const float* __restrict__ bias1,
    const float* __restrict__ bias2, const float* __restrict__ bias3,
    _Float16* __restrict__ Qo, _Float16* __restrict__ Ko,
    _Float16* __restrict__ Vto, _Float16* __restrict__ Vvto,
    float* __restrict__ meanO, float* __restrict__ varO)
{
  constexpr int NBN = (MODE==0) ? 32 : 16;     // n-tiles (4096 or 2048 cols)
  __shared__ _Float16 sA[128*32];
  __shared__ _Float16 sB[128*32];
  const int tid = threadIdx.x;
  const int lane = tid & 63;
  const int wid  = tid >> 6;
  const int wm = wid >> 1, wn = wid & 1;
  const int l15 = lane & 15, l4 = lane >> 4;
  const int nwg = 64*NBN;
  const int bid = blockIdx.x;
  const int swz = (bid & 7) * (nwg >> 3) + (bid >> 3);
  const int bm = swz / NBN, bn = swz % NBN;
  const int row0 = bm << 7, col0 = bn << 7;
  const int seg = col0 >> 10;

  const _Float16* A = (MODE==0) ? (seg < 3 ? A0 : A1) : (seg == 0 ? A0 : A1);
  const _Float16* B = Wcat + (size_t)col0 * 1024;

  f4 acc[4][4];
  #pragma unroll
  for (int i=0;i<4;i++)
    #pragma unroll
    for (int j=0;j<4;j++)
      #pragma unroll
      for (int r=0;r<4;r++) acc[i][j][r] = 0.f;

  const int c0 = tid, c1 = tid + 256;
  const int r0 = c0 >> 2, ch0 = c0 & 3;
  const int r1 = c1 >> 2, ch1 = c1 & 3;
  const int k0off = ((ch0 ^ (r0 & 3)) << 3);
  const int k1off = ((ch1 ^ (r1 & 3)) << 3);

  for (int kt = 0; kt < 1024; kt += 32){
    __syncthreads();
    async_copy16(&sA[c0*8], A + (size_t)(row0+r0)*1024 + kt + k0off);
    async_copy16(&sA[c1*8], A + (size_t)(row0+r1)*1024 + kt + k1off);
    async_copy16(&sB[c0*8], B + (size_t)r0*1024 + kt + k0off);
    async_copy16(&sB[c1*8], B + (size_t)r1*1024 + kt + k1off);
    __syncthreads();

    h8 a[4], b[4];
    #pragma unroll
    for (int mf=0; mf<4; mf++){
      int r  = (wm<<6) + (mf<<4) + l15;
      int ck = l4 ^ (r & 3);
      a[mf] = *(const h8*)&sA[r*32 + ck*8];
    }
    #pragma unroll
    for (int nf=0; nf<4; nf++){
      int r  = (wn<<6) + (nf<<4) + l15;
      int ck = l4 ^ (r & 3);
      b[nf] = *(const h8*)&sB[r*32 + ck*8];
    }
    #pragma unroll
    for (int mf=0; mf<4; mf++)
      #pragma unroll
      for (int nf=0; nf<4; nf++)
        acc[mf][nf] = mfma_h(a[mf], b[nf], acc[mf][nf]);
  }

  const float* bias = (MODE==0)
      ? (seg==0 ? bias0 : seg==1 ? bias1 : seg==2 ? bias2 : bias3)
      : (seg==0 ? bias0 : bias1);
  const bool sp2 = (MODE==0) ? (seg==3) : (seg==1);

  #pragma unroll
  for (int nf=0; nf<4; nf++){
    int colg = col0 + (wn<<6) + (nf<<4) + l15;
    int colm = colg & 1023;
    float bb = bias[colm];
    float bv = sp2 ? ({ float s = softplusf(bb); s*s; }) : bb;
    #pragma unroll
    for (int mf=0; mf<4; mf++){
      int rbase = row0 + (wm<<6) + (mf<<4) + (l4<<2);
      #pragma unroll
      for (int r=0;r<4;r++){
        int row = rbase + r;
        float v = acc[mf][nf][r] + bv;
        if (MODE==0){
          if (seg==0)      Qo[(size_t)row*1024 + colm] = (_Float16)v;
          else if (seg==1) Ko[(size_t)row*1024 + colm] = (_Float16)v;
          else {
            _Float16* T = (seg==2) ? Vto : Vvto;
            T[((size_t)(row>>10)<<20) + ((size_t)colm<<10) + (row & 1023)] = (_Float16)v;
          }
        } else {
          size_t idx = (size_t)row*1024 + colm;
          if (seg==0) meanO[idx] = v;
          else        varO[idx] = v + varO[idx];
        }
      }
    }
  }
}

// ---------------- fused attention (flash-style, + RBF scores) ----------------
// 1024 blocks = 8 q-tiles x (B*H), 4 waves x 32 q-rows. All-dbuf staging,
// ONE barrier/iter (lockstep blocks -> L2 reuse). Swapped QK^T with K-row
// permutation rho(fm,w) = (fm&1)*4 + (w&3) + (w>>2)*8 + (fm>>1)*32 so the
// score C-regs repack in-lane straight into PV's A-fragment k-slots.
// xk RBF fragments register-prefetched one KV-tile ahead (latency hidden
// under the full iteration; barrier's vmcnt drain covers the wait).
__global__ __launch_bounds__(256, 3) void attn_kernel(
    const _Float16* __restrict__ Qh, const _Float16* __restrict__ Kh,
    const _Float16* __restrict__ Vt, const _Float16* __restrict__ Vvt,
    const _Float16* __restrict__ xk, const _Float16* __restrict__ xq,
    const float* __restrict__ log_sigma_f, const float* __restrict__ log_length,
    _Float16* __restrict__ ctx_out, _Float16* __restrict__ ctx2_out,
    float* __restrict__ var_out)
{
  const int bid = blockIdx.x;
  const int swz = (bid & 7) * 128 + (bid >> 3);
  const int qt = swz & 7;
  const int bh = swz >> 3;
  const int b  = bh >> 4, h = bh & 15;
  const int tid = threadIdx.x;
  const int lane = tid & 63, wid = tid >> 6;
  const int l15 = lane & 15, l4 = lane >> 4;
  const float L2E   = 1.44269504f;
  const float sig2l = __expf(2.f*log_sigma_f[h]) * L2E;      // sigma_f^2 * log2(e)
  const float e2c   = 0.5f*__expf(-2.f*log_length[h]) * L2E; // 1/(2 l^2) * log2(e)
  const float cqk   = 0.125f * L2E;

  __shared__ _Float16 sK[2][4096];   // [m][d] 64x64, g-swizzled
  __shared__ _Float16 sV[2][4096];   // [d][m]
  __shared__ _Float16 sVv[2][4096];  // [d][m]

  const int t0 = b*NSEQ + qt*128;
  const int wq = wid*32;

  // permuted K-row for this lane per fm (constant across tiles)
  int krow_[4];
  #pragma unroll
  for (int fm=0; fm<4; fm++)
    krow_[fm] = ((fm&1)<<2) + (l15&3) + ((l15>>2)<<3) + ((fm>>1)<<5);

  // Q fragments (B-side: lane l15 = q-row)
  h8 qf[2][2];
  #pragma unroll
  for (int fq=0; fq<2; fq++)
    #pragma unroll
    for (int ks=0; ks<2; ks++){
      size_t off = (size_t)(t0 + wq + fq*16 + l15)*D_MODEL + h*DK + ks*32 + l4*8;
      qf[fq][ks] = *(const h8*)(Qh + off);
    }
  // RBF Q-side rows (full 32-slot padded vector, no branches)
  h8 xqf[2];
  #pragma unroll
  for (int fq=0; fq<2; fq++)
    xqf[fq] = *(const h8*)(xq + (size_t)(t0 + wq + fq*16 + l15)*32 + l4*8);

  h8 ones;
  #pragma unroll
  for (int j=0;j<8;j++) ones[j] = (_Float16)1.f;

  float mrun[2] = {-1e30f, -1e30f};   // log2 domain
  f4 lacc[2], ctx[2][4], var[2][4];
  #pragma unroll
  for (int fq=0; fq<2; fq++){
    #pragma unroll
    for (int r=0;r<4;r++) lacc[fq][r] = 0.f;
    #pragma unroll
    for (int fd=0; fd<4; fd++)
      #pragma unroll
      for (int r=0;r<4;r++){ ctx[fq][fd][r] = 0.f; var[fq][fd][r] = 0.f; }
  }

  // staging: 1536 chunks of 16B (K 512 w/ g-swizzle, V 512, Vv 512)
  auto stage = [&](int bi, int mt){
    #pragma unroll
    for (int k=0;k<6;k++){
      int c = tid + k*256;
      if (k < 2){
        int rg = c >> 3, ch = c & 7;
        int g  = (rg & 3) | (((rg >> 3) & 1) << 2);
        int sw = ((ch ^ g) << 3);
        async_copy16(&sK[bi][c*8], Kh + (size_t)(b*NSEQ + mt + rg)*D_MODEL + h*DK + sw);
      } else if (k < 4){
        int cc = c - 512; int rg = cc >> 3, sw = (((cc & 7) ^ (rg & 7)) << 3);
        async_copy16(&sV[bi][cc*8], Vt + ((size_t)b << 20) + (size_t)(h*DK + rg)*NSEQ + mt + sw);
      } else {
        int cc = c - 1024; int rg = cc >> 3, sw = (((cc & 7) ^ (rg & 7)) << 3);
        async_copy16(&sVv[bi][cc*8], Vvt + ((size_t)b << 20) + (size_t)(h*DK + rg)*NSEQ + mt + sw);
      }
    }
  };

  // xk fragments: current tile (xkf) + next tile (xknxt), register-prefetched
  h8 xkf[4], xknxt[4];
  #pragma unroll
  for (int fm=0; fm<4; fm++)
    xkf[fm] = *(const h8*)(xk + (size_t)(b*NSEQ + krow_[fm])*32 + l4*8);

  stage(0, 0);
  __syncthreads();

  for (int it = 0; it < NSEQ/64; it++){
    const int bi = it & 1;
    const int mt = it*64;
    if (it + 1 < NSEQ/64){
      stage(bi^1, mt + 64);
      #pragma unroll
      for (int fm=0; fm<4; fm++)
        xknxt[fm] = *(const h8*)(xk + (size_t)(b*NSEQ + mt + 64 + krow_[fm])*32 + l4*8);
    }

    // scores (swapped): S'[fq][fm][r] for m-row rho(fm, l4*4+r), q = l15
    f4 S[2][4];
    #pragma unroll
    for (int fm=0; fm<4; fm++){
      const int krow = krow_[fm];
      const int g    = (krow & 3) | (((krow >> 3) & 1) << 2);
      h8 kb0 = *(const h8*)&sK[bi][krow*64 + ((l4      ^ g))*8];
      h8 kb1 = *(const h8*)&sK[bi][krow*64 + (((4+l4) ^ g))*8];
      #pragma unroll
      for (int fq=0; fq<2; fq++){
        f4 s, xd;
        #pragma unroll
        for (int r=0;r<4;r++){ s[r]=0.f; xd[r]=0.f; }
        s  = mfma_h(kb0, qf[fq][0], s);
        s  = mfma_h(kb1, qf[fq][1], s);
        xd = mfma_h(xkf[fm], xqf[fq], xd);         // = -dist2
        #pragma unroll
        for (int r=0;r<4;r++)
          S[fq][fm][r] = s[r]*cqk + sig2l*exp2f(fminf(xd[r],0.f)*e2c);
      }
    }

    // softmax (log2 domain), defer-max thr = 4*log2e = 5.77
    h8 pa[2][2];
    #pragma unroll
    for (int fq=0; fq<2; fq++){
      float tm = S[fq][0][0];
      #pragma unroll
      for (int fm=0; fm<4; fm++)
        #pragma unroll
        for (int r=0;r<4;r++) tm = fmaxf(tm, S[fq][fm][r]);
      tm = fmaxf(tm, __shfl_xor(tm, 16));
      tm = fmaxf(tm, __shfl_xor(tm, 32));
      int nd = tm > mrun[fq] + 5.7708f;
      if (__any(nd)){
        float mn = fmaxf(mrun[fq], tm);
        float sc = exp2f(mrun[fq] - mn);          // per q = l15
        mrun[fq] = mn;
        float scr[4];
        #pragma unroll
        for (int r=0;r<4;r++) scr[r] = __shfl(sc, (l4<<2) + r);  // q = l4*4+r
        #pragma unroll
        for (int r=0;r<4;r++) lacc[fq][r] *= scr[r];
        #pragma unroll
        for (int fd=0; fd<4; fd++)
          #pragma unroll
          for (int r=0;r<4;r++){
            ctx[fq][fd][r] *= scr[r];
            var[fq][fd][r] *= scr[r]*scr[r];
          }
      }
      // P = exp2(S' - m'); in-lane repack: slot(ks=fm>>1, j=(fm&1)*4+r) -> m = ks*32+l4*8+j
      #pragma unroll
      for (int fm=0; fm<4; fm++)
        #pragma unroll
        for (int r=0;r<4;r++)
          pa[fq][fm>>1][((fm&1)<<2) + r] = (_Float16)exp2f(S[fq][fm][r] - mrun[fq]);
    }

    // PV: ctx += P@V, var += P^2@Vv, l += P@1
    #pragma unroll
    for (int ks=0; ks<2; ks++){
      h8 pa2[2];
      #pragma unroll
      for (int fq=0; fq<2; fq++){
        pa2[fq] = pa[fq][ks]*pa[fq][ks];
        lacc[fq] = mfma_h(pa[fq][ks], ones, lacc[fq]);
      }
      #pragma unroll
      for (int fd=0; fd<4; fd++){
        int drow = fd*16 + l15;
        int ck = (ks*4 + l4) ^ (drow & 7);
        h8 vb  = *(const h8*)&sV[bi][drow*64 + ck*8];
        h8 vvb = *(const h8*)&sVv[bi][drow*64 + ck*8];
        #pragma unroll
        for (int fq=0; fq<2; fq++){
          ctx[fq][fd] = mfma_h(pa[fq][ks], vb,  ctx[fq][fd]);
          var[fq][fd] = mfma_h(pa2[fq],    vvb, var[fq][fd]);
        }
      }
    }
    __syncthreads();
    #pragma unroll
    for (int fm=0; fm<4; fm++) xkf[fm] = xknxt[fm];
  }

  // epilogue: normalize; write ctx/ctx^2 f16 + var f32 (line-grouped)
  #pragma unroll
  for (int fq=0; fq<2; fq++)
    #pragma unroll
    for (int r=0;r<4;r++){
      int t = t0 + wq + fq*16 + l4*4 + r;
      float linv = 1.f / lacc[fq][r];
      size_t base = (size_t)t*D_MODEL + h*DK + l15;
      float c[4];
      #pragma unroll
      for (int fd=0; fd<4; fd++) c[fd] = ctx[fq][fd][r] * linv;
      #pragma unroll
      for (int fd=0; fd<4; fd++) ctx_out[base + fd*16]  = (_Float16)c[fd];
      #pragma unroll
      for (int fd=0; fd<4; fd++) ctx2_out[base + fd*16] = (_Float16)(c[fd]*c[fd]);
      #pragma unroll
      for (int fd=0; fd<4; fd++) var_out[base + fd*16]  = var[fq][fd][r] * linv * linv;
    }
}

// ---------------- host launch ----------------

extern "C" void kernel_launch(void* const* d_in, const int* in_sizes, int n_in,
                              void* d_out, int out_size, void* d_ws, size_t ws_size,
                              hipStream_t stream){
  (void)in_sizes; (void)n_in; (void)out_size; (void)ws_size;
  const float* H      = (const float*)d_in[0];
  const float* x_raw  = (const float*)d_in[1];
  const float* Wq_mu  = (const float*)d_in[2];
  const float* bq_mu  = (const float*)d_in[4];
  const float* Wk_mu  = (const float*)d_in[6];
  const float* bk_mu  = (const float*)d_in[8];
  const float* Wv_mu  = (const float*)d_in[10];
  const float* Wv_rho = (const float*)d_in[11];
  const float* bv_mu  = (const float*)d_in[12];
  const float* bv_rho = (const float*)d_in[13];
  const float* Wo_mu  = (const float*)d_in[14];
  const float* Wo_rho = (const float*)d_in[15];
  const float* bo_mu  = (const float*)d_in[16];
  const float* bo_rho = (const float*)d_in[17];
  const float* lsf    = (const float*)d_in[18];
  const float* lln    = (const float*)d_in[19];

  char* ws = (char*)d_ws;
  const size_t MB = 1024*1024;
  _Float16* Hh    = (_Float16*)(ws + 0*MB);     // 16MB
  _Float16* H2h   = (_Float16*)(ws + 16*MB);    // 16MB
  _Float16* Wcat  = (_Float16*)(ws + 32*MB);    // 8MB: [Wq|Wk|Wv|Wvs2] rows
  _Float16* Wocat = (_Float16*)(ws + 40*MB);    // 4MB: [Wo|Wos2] rows
  _Float16* Qh    = (_Float16*)(ws + 46*MB);    // 16MB
  _Float16* Kh    = (_Float16*)(ws + 62*MB);    // 16MB
  _Float16* Vt    = (_Float16*)(ws + 78*MB);    // 16MB, transposed [b][o][n]
  _Float16* Vvt   = (_Float16*)(ws + 94*MB);    // 16MB
  _Float16* ctxh  = (_Float16*)(ws + 110*MB);   // 16MB
  _Float16* ctx2h = (_Float16*)(ws + 126*MB);   // 16MB
  _Float16* xk    = (_Float16*)(ws + 142*MB);   // 512KB
  _Float16* xqb   = (_Float16*)(ws + 142*MB + 512*1024);  // 512KB

  float* out_mean = (float*)d_out;
  float* out_var  = out_mean + (size_t)TOK*D_MODEL;

  const int TD = TOK*D_MODEL;
  const int DD = D_MODEL*D_MODEL;

  // prep
  prep_H  <<<TD/1024, 256, 0, stream>>>(H, Hh, H2h, TD);
  cast_f16<<<DD/1024, 256, 0, stream>>>(Wq_mu, Wcat, DD);
  cast_f16<<<DD/1024, 256, 0, stream>>>(Wk_mu, Wcat + (size_t)DD, DD);
  cast_f16<<<DD/1024, 256, 0, stream>>>(Wv_mu, Wcat + 2*(size_t)DD, DD);
  sp2_f16 <<<DD/1024, 256, 0, stream>>>(Wv_rho, Wcat + 3*(size_t)DD, DD);
  cast_f16<<<DD/1024, 256, 0, stream>>>(Wo_mu, Wocat, DD);
  sp2_f16 <<<DD/1024, 256, 0, stream>>>(Wo_rho, Wocat + (size_t)DD, DD);
  prep_x  <<<TOK/256, 256, 0, stream>>>(x_raw, xk, xqb, TOK);

  // fused projections: Q | K | V | Vv in one launch (grid 64 x 32)
  gemm_fused<0><<<2048, 256, 0, stream>>>(Hh, H2h, Wcat,
      bq_mu, bk_mu, bv_mu, bv_rho,
      Qh, Kh, Vt, Vvt, nullptr, nullptr);

  // attention (writes ctxh/ctx2h f16 and var_attn into out_var)
  attn_kernel<<<1024, 256, 0, stream>>>(Qh, Kh, Vt, Vvt, xk, xqb, lsf, lln,
      ctxh, ctx2h, out_var);

  // fused output projections: out_mean | out_var (grid 64 x 16)
  gemm_fused<1><<<1024, 256, 0, stream>>>(ctxh, ctx2h, Wocat,
      bo_mu, bo_rho, nullptr, nullptr,
      nullptr, nullptr, nullptr, nullptr, out_mean, out_var);
}

// Round 8
// 350.652 us; speedup vs baseline: 1.3574x; 1.2956x over previous
//
#include <hip/hip_runtime.h>
#include <hip/hip_bf16.h>
#include <stdint.h>

// Bayesian MHA forward for MI355X (round 8).
// r7 attn structure (swapped QK^T, permuted K-feed, no sP, exp2 softmax,
// xk reg-prefetch) but at 2 blocks/CU: the 3/CU occupancy put 12 bh-groups
// (4.6MB) on each XCD's 4MB L2 -> thrash (r7 FETCH 154MB). 2/CU = 8 groups
// = 3MB, fits (r5-proven regime, FETCH 33MB).
// Preps fused 8 launches -> 2.

#define D_MODEL 1024
#define NSEQ    1024
#define BATCH   8
#define NHEADS  16
#define DK      64
#define TOK     8192   // BATCH*NSEQ

typedef _Float16  h8  __attribute__((ext_vector_type(8)));
typedef float     f4  __attribute__((ext_vector_type(4)));

__device__ __forceinline__ f4 mfma_h(h8 a, h8 b, f4 c){
  return __builtin_amdgcn_mfma_f32_16x16x32_f16(a, b, c, 0, 0, 0);
}

// global -> LDS async copy, 16B per lane. LDS dest must be (uniform base + lane*16).
__device__ __forceinline__ void async_copy16(void* lds, const void* g){
  __builtin_amdgcn_global_load_lds(
      (const __attribute__((address_space(1))) unsigned int*)(uintptr_t)g,
      (__attribute__((address_space(3))) unsigned int*)(unsigned int)(uintptr_t)lds,
      16, 0, 0);
}

__device__ __forceinline__ float softplusf(float x){
  return (x > 20.f) ? x : log1pf(__expf(x));
}

// ---------------- prep kernels (fused) ----------------

// One launch for all weight preprocessing. 6 segments of DD=1M elements:
// 0: f16(Wq) 1: f16(Wk) 2: f16(Wv) 3: f16(sp(Wv_rho)^2) 4: f16(Wo) 5: f16(sp(Wo_rho)^2)
__global__ __launch_bounds__(256) void prep_W(
    const float* __restrict__ Wq, const float* __restrict__ Wk,
    const float* __restrict__ Wv, const float* __restrict__ Wvr,
    const float* __restrict__ Wo, const float* __restrict__ Wor,
    _Float16* __restrict__ Wcat, _Float16* __restrict__ Wocat)
{
  const int bid = blockIdx.x;
  const int seg = bid >> 10;                 // 1024 blocks per segment
  const int i   = ((bid & 1023)*256 + threadIdx.x)*4;
  const float* src = seg==0 ? Wq : seg==1 ? Wk : seg==2 ? Wv : seg==3 ? Wvr : seg==4 ? Wo : Wor;
  _Float16* dst = (seg < 4) ? (Wcat + (size_t)seg*1048576)
                            : (Wocat + (size_t)(seg-4)*1048576);
  const bool sp2 = (seg==3) || (seg==5);
  float4 v = *(const float4*)(src + i);
  float vv[4] = {v.x, v.y, v.z, v.w};
  #pragma unroll
  for (int j=0;j<4;j++){
    float f = vv[j];
    if (sp2){ float s = softplusf(f); f = s*s; }
    dst[i+j] = (_Float16)f;
  }
}

// One launch for H and x_raw preprocessing.
// bids [0,8192): Hh = f16(H), H2h = f16(H*H)  (1024 elems/block)
// bids [8192,8224): xk/xq padded RBF rows (256 tokens/block)
//   xk[t][32] = [x(16), x2hi, x2lo, 1, 1, 0(12)]
//   xq[t][32] = [2x(16), -1, -1, -x2hi, -x2lo, 0(12)]
//   => dot(xk[m], xq[q]) = -dist2(m,q)
__global__ __launch_bounds__(256) void prep_Hx(
    const float* __restrict__ H, const float* __restrict__ x,
    _Float16* __restrict__ Hh, _Float16* __restrict__ H2h,
    _Float16* __restrict__ xk, _Float16* __restrict__ xq)
{
  const int bid = blockIdx.x;
  if (bid < 8192){
    int i = (bid*256 + threadIdx.x)*4;
    float4 v = *(const float4*)(H + i);
    float vv[4] = {v.x, v.y, v.z, v.w};
    #pragma unroll
    for (int j=0;j<4;j++){
      Hh[i+j]  = (_Float16)vv[j];
      H2h[i+j] = (_Float16)(vv[j]*vv[j]);
    }
  } else {
    int t = (bid - 8192)*256 + threadIdx.x;
    const float* p = x + (size_t)t*16;
    _Float16 a[32], bb[32];
    float s = 0.f;
    #pragma unroll
    for (int j=0;j<16;j++){
      float f = p[j];
      a[j]  = (_Float16)f;
      bb[j] = (_Float16)(2.f*f);
      s += f*f;
    }
    _Float16 shi = (_Float16)s;
    _Float16 slo = (_Float16)(s - (float)shi);
    a[16]=shi; a[17]=slo; a[18]=(_Float16)1.f; a[19]=(_Float16)1.f;
    bb[16]=(_Float16)-1.f; bb[17]=(_Float16)-1.f; bb[18]=-shi; bb[19]=-slo;
    #pragma unroll
    for (int j=20;j<32;j++){ a[j]=(_Float16)0.f; bb[j]=(_Float16)0.f; }
    #pragma unroll
    for (int j=0;j<4;j++){
      *(h8*)(xk + (size_t)t*32 + j*8) = *(const h8*)&a[j*8];
      *(h8*)(xq + (size_t)t*32 + j*8) = *(const h8*)&bb[j*8];
    }
  }
}

// ---------------- fused GEMM: C = A @ Wcat^T (+bias) ----------------
// MODE 0: projections. 4 segments of 1024 cols: Q, K, V, Vv.
//   A = Hh (segs 0-2) or H2h (seg 3). Outputs: Qh/Kh [row][col] f16,
//   Vt/Vvt transposed [b][col][row&1023] f16.
// MODE 1: outputs. 2 segments: out_mean (f32), out_var (f32, += addend in place).
// 128x128 tile, BK=32, 4 waves (2x2). XOR-swizzled LDS chunks. XCD block swizzle.
template<int MODE>
__global__ __launch_bounds__(256) void gemm_fused(
    const _Float16* __restrict__ A0, const _Float16* __restrict__ A1,
    const _Float16* __restrict__ Wcat,
    const float* __restrict__ bias0, const float* __restrict__ bias1,
    const float* __restrict__ bias2, const float* __restrict__ bias3,
    _Float16* __restrict__ Qo, _Float16* __restrict__ Ko,
    _Float16* __restrict__ Vto, _Float16* __restrict__ Vvto,
    float* __restrict__ meanO, float* __restrict__ varO)
{
  constexpr int NBN = (MODE==0) ? 32 : 16;     // n-tiles (4096 or 2048 cols)
  __shared__ _Float16 sA[128*32];
  __shared__ _Float16 sB[128*32];
  const int tid = threadIdx.x;
  const int lane = tid & 63;
  const int wid  = tid >> 6;
  const int wm = wid >> 1, wn = wid & 1;
  const int l15 = lane & 15, l4 = lane >> 4;
  const int nwg = 64*NBN;
  const int bid = blockIdx.x;
  const int swz = (bid & 7) * (nwg >> 3) + (bid >> 3);
  const int bm = swz / NBN, bn = swz % NBN;
  const int row0 = bm << 7, col0 = bn << 7;
  const int seg = col0 >> 10;

  const _Float16* A = (MODE==0) ? (seg < 3 ? A0 : A1) : (seg == 0 ? A0 : A1);
  const _Float16* B = Wcat + (size_t)col0 * 1024;

  f4 acc[4][4];
  #pragma unroll
  for (int i=0;i<4;i++)
    #pragma unroll
    for (int j=0;j<4;j++)
      #pragma unroll
      for (int r=0;r<4;r++) acc[i][j][r] = 0.f;

  const int c0 = tid, c1 = tid + 256;
  const int r0 = c0 >> 2, ch0 = c0 & 3;
  const int r1 = c1 >> 2, ch1 = c1 & 3;
  const int k0off = ((ch0 ^ (r0 & 3)) << 3);
  const int k1off = ((ch1 ^ (r1 & 3)) << 3);

  for (int kt = 0; kt < 1024; kt += 32){
    __syncthreads();
    async_copy16(&sA[c0*8], A + (size_t)(row0+r0)*1024 + kt + k0off);
    async_copy16(&sA[c1*8], A + (size_t)(row0+r1)*1024 + kt + k1off);
    async_copy16(&sB[c0*8], B + (size_t)r0*1024 + kt + k0off);
    async_copy16(&sB[c1*8], B + (size_t)r1*1024 + kt + k1off);
    __syncthreads();

    h8 a[4], b[4];
    #pragma unroll
    for (int mf=0; mf<4; mf++){
      int r  = (wm<<6) + (mf<<4) + l15;
      int ck = l4 ^ (r & 3);
      a[mf] = *(const h8*)&sA[r*32 + ck*8];
    }
    #pragma unroll
    for (int nf=0; nf<4; nf++){
      int r  = (wn<<6) + (nf<<4) + l15;
      int ck = l4 ^ (r & 3);
      b[nf] = *(const h8*)&sB[r*32 + ck*8];
    }
    #pragma unroll
    for (int mf=0; mf<4; mf++)
      #pragma unroll
      for (int nf=0; nf<4; nf++)
        acc[mf][nf] = mfma_h(a[mf], b[nf], acc[mf][nf]);
  }

  const float* bias = (MODE==0)
      ? (seg==0 ? bias0 : seg==1 ? bias1 : seg==2 ? bias2 : bias3)
      : (seg==0 ? bias0 : bias1);
  const bool sp2 = (MODE==0) ? (seg==3) : (seg==1);

  #pragma unroll
  for (int nf=0; nf<4; nf++){
    int colg = col0 + (wn<<6) + (nf<<4) + l15;
    int colm = colg & 1023;
    float bb = bias[colm];
    float bv = sp2 ? ({ float s = softplusf(bb); s*s; }) : bb;
    #pragma unroll
    for (int mf=0; mf<4; mf++){
      int rbase = row0 + (wm<<6) + (mf<<4) + (l4<<2);
      #pragma unroll
      for (int r=0;r<4;r++){
        int row = rbase + r;
        float v = acc[mf][nf][r] + bv;
        if (MODE==0){
          if (seg==0)      Qo[(size_t)row*1024 + colm] = (_Float16)v;
          else if (seg==1) Ko[(size_t)row*1024 + colm] = (_Float16)v;
          else {
            _Float16* T = (seg==2) ? Vto : Vvto;
            T[((size_t)(row>>10)<<20) + ((size_t)colm<<10) + (row & 1023)] = (_Float16)v;
          }
        } else {
          size_t idx = (size_t)row*1024 + colm;
          if (seg==0) meanO[idx] = v;
          else        varO[idx] = v + varO[idx];
        }
      }
    }
  }
}

// ---------------- fused attention (flash-style, + RBF scores) ----------------
// 1024 blocks = 8 q-tiles x (B*H), 4 waves x 32 q-rows. All-dbuf staging,
// ONE barrier/iter (lockstep blocks -> L2 reuse). Swapped QK^T with K-row
// permutation rho(fm,w) = (fm&1)*4 + (w&3) + (w>>2)*8 + (fm>>1)*32 so the
// score C-regs repack in-lane straight into PV's A-fragment k-slots.
// 2 blocks/CU: 8 bh-groups x 384KB = 3MB per XCD L2 (fits; 3/CU thrashed).
__global__ __launch_bounds__(256, 2) void attn_kernel(
    const _Float16* __restrict__ Qh, const _Float16* __restrict__ Kh,
    const _Float16* __restrict__ Vt, const _Float16* __restrict__ Vvt,
    const _Float16* __restrict__ xk, const _Float16* __restrict__ xq,
    const float* __restrict__ log_sigma_f, const float* __restrict__ log_length,
    _Float16* __restrict__ ctx_out, _Float16* __restrict__ ctx2_out,
    float* __restrict__ var_out)
{
  const int bid = blockIdx.x;
  const int swz = (bid & 7) * 128 + (bid >> 3);
  const int qt = swz & 7;
  const int bh = swz >> 3;
  const int b  = bh >> 4, h = bh & 15;
  const int tid = threadIdx.x;
  const int lane = tid & 63, wid = tid >> 6;
  const int l15 = lane & 15, l4 = lane >> 4;
  const float L2E   = 1.44269504f;
  const float sig2l = __expf(2.f*log_sigma_f[h]) * L2E;      // sigma_f^2 * log2(e)
  const float e2c   = 0.5f*__expf(-2.f*log_length[h]) * L2E; // 1/(2 l^2) * log2(e)
  const float cqk   = 0.125f * L2E;

  __shared__ _Float16 sK[2][4096];   // [m][d] 64x64, g-swizzled
  __shared__ _Float16 sV[2][4096];   // [d][m]
  __shared__ _Float16 sVv[2][4096];  // [d][m]

  const int t0 = b*NSEQ + qt*128;
  const int wq = wid*32;

  // permuted K-row for this lane per fm (constant across tiles)
  int krow_[4];
  #pragma unroll
  for (int fm=0; fm<4; fm++)
    krow_[fm] = ((fm&1)<<2) + (l15&3) + ((l15>>2)<<3) + ((fm>>1)<<5);

  // Q fragments (B-side: lane l15 = q-row)
  h8 qf[2][2];
  #pragma unroll
  for (int fq=0; fq<2; fq++)
    #pragma unroll
    for (int ks=0; ks<2; ks++){
      size_t off = (size_t)(t0 + wq + fq*16 + l15)*D_MODEL + h*DK + ks*32 + l4*8;
      qf[fq][ks] = *(const h8*)(Qh + off);
    }
  // RBF Q-side rows (full 32-slot padded vector, no branches)
  h8 xqf[2];
  #pragma unroll
  for (int fq=0; fq<2; fq++)
    xqf[fq] = *(const h8*)(xq + (size_t)(t0 + wq + fq*16 + l15)*32 + l4*8);

  h8 ones;
  #pragma unroll
  for (int j=0;j<8;j++) ones[j] = (_Float16)1.f;

  float mrun[2] = {-1e30f, -1e30f};   // log2 domain
  f4 lacc[2], ctx[2][4], var[2][4];
  #pragma unroll
  for (int fq=0; fq<2; fq++){
    #pragma unroll
    for (int r=0;r<4;r++) lacc[fq][r] = 0.f;
    #pragma unroll
    for (int fd=0; fd<4; fd++)
      #pragma unroll
      for (int r=0;r<4;r++){ ctx[fq][fd][r] = 0.f; var[fq][fd][r] = 0.f; }
  }

  // staging: 1536 chunks of 16B (K 512 w/ g-swizzle, V 512, Vv 512)
  auto stage = [&](int bi, int mt){
    #pragma unroll
    for (int k=0;k<6;k++){
      int c = tid + k*256;
      if (k < 2){
        int rg = c >> 3, ch = c & 7;
        int g  = (rg & 3) | (((rg >> 3) & 1) << 2);
        int sw = ((ch ^ g) << 3);
        async_copy16(&sK[bi][c*8], Kh + (size_t)(b*NSEQ + mt + rg)*D_MODEL + h*DK + sw);
      } else if (k < 4){
        int cc = c - 512; int rg = cc >> 3, sw = (((cc & 7) ^ (rg & 7)) << 3);
        async_copy16(&sV[bi][cc*8], Vt + ((size_t)b << 20) + (size_t)(h*DK + rg)*NSEQ + mt + sw);
      } else {
        int cc = c - 1024; int rg = cc >> 3, sw = (((cc & 7) ^ (rg & 7)) << 3);
        async_copy16(&sVv[bi][cc*8], Vvt + ((size_t)b << 20) + (size_t)(h*DK + rg)*NSEQ + mt + sw);
      }
    }
  };

  // xk fragments: current tile (xkf) + next tile (xknxt), register-prefetched
  h8 xkf[4], xknxt[4];
  #pragma unroll
  for (int fm=0; fm<4; fm++)
    xkf[fm] = *(const h8*)(xk + (size_t)(b*NSEQ + krow_[fm])*32 + l4*8);

  stage(0, 0);
  __syncthreads();

  for (int it = 0; it < NSEQ/64; it++){
    const int bi = it & 1;
    const int mt = it*64;
    if (it + 1 < NSEQ/64){
      stage(bi^1, mt + 64);
      #pragma unroll
      for (int fm=0; fm<4; fm++)
        xknxt[fm] = *(const h8*)(xk + (size_t)(b*NSEQ + mt + 64 + krow_[fm])*32 + l4*8);
    }

    // scores (swapped): S'[fq][fm][r] for m-row rho(fm, l4*4+r), q = l15
    f4 S[2][4];
    #pragma unroll
    for (int fm=0; fm<4; fm++){
      const int krow = krow_[fm];
      const int g    = (krow & 3) | (((krow >> 3) & 1) << 2);
      h8 kb0 = *(const h8*)&sK[bi][krow*64 + ((l4      ^ g))*8];
      h8 kb1 = *(const h8*)&sK[bi][krow*64 + (((4+l4) ^ g))*8];
      #pragma unroll
      for (int fq=0; fq<2; fq++){
        f4 s, xd;
        #pragma unroll
        for (int r=0;r<4;r++){ s[r]=0.f; xd[r]=0.f; }
        s  = mfma_h(kb0, qf[fq][0], s);
        s  = mfma_h(kb1, qf[fq][1], s);
        xd = mfma_h(xkf[fm], xqf[fq], xd);         // = -dist2
        #pragma unroll
        for (int r=0;r<4;r++)
          S[fq][fm][r] = s[r]*cqk + sig2l*exp2f(fminf(xd[r],0.f)*e2c);
      }
    }

    // softmax (log2 domain), defer-max thr = 4*log2e = 5.77
    h8 pa[2][2];
    #pragma unroll
    for (int fq=0; fq<2; fq++){
      float tm = S[fq][0][0];
      #pragma unroll
      for (int fm=0; fm<4; fm++)
        #pragma unroll
        for (int r=0;r<4;r++) tm = fmaxf(tm, S[fq][fm][r]);
      tm = fmaxf(tm, __shfl_xor(tm, 16));
      tm = fmaxf(tm, __shfl_xor(tm, 32));
      int nd = tm > mrun[fq] + 5.7708f;
      if (__any(nd)){
        float mn = fmaxf(mrun[fq], tm);
        float sc = exp2f(mrun[fq] - mn);          // per q = l15
        mrun[fq] = mn;
        float scr[4];
        #pragma unroll
        for (int r=0;r<4;r++) scr[r] = __shfl(sc, (l4<<2) + r);  // q = l4*4+r
        #pragma unroll
        for (int r=0;r<4;r++) lacc[fq][r] *= scr[r];
        #pragma unroll
        for (int fd=0; fd<4; fd++)
          #pragma unroll
          for (int r=0;r<4;r++){
            ctx[fq][fd][r] *= scr[r];
            var[fq][fd][r] *= scr[r]*scr[r];
          }
      }
      // P = exp2(S' - m'); in-lane repack: slot(ks=fm>>1, j=(fm&1)*4+r) -> m = ks*32+l4*8+j
      #pragma unroll
      for (int fm=0; fm<4; fm++)
        #pragma unroll
        for (int r=0;r<4;r++)
          pa[fq][fm>>1][((fm&1)<<2) + r] = (_Float16)exp2f(S[fq][fm][r] - mrun[fq]);
    }

    // PV: ctx += P@V, var += P^2@Vv, l += P@1
    #pragma unroll
    for (int ks=0; ks<2; ks++){
      h8 pa2[2];
      #pragma unroll
      for (int fq=0; fq<2; fq++){
        pa2[fq] = pa[fq][ks]*pa[fq][ks];
        lacc[fq] = mfma_h(pa[fq][ks], ones, lacc[fq]);
      }
      #pragma unroll
      for (int fd=0; fd<4; fd++){
        int drow = fd*16 + l15;
        int ck = (ks*4 + l4) ^ (drow & 7);
        h8 vb  = *(const h8*)&sV[bi][drow*64 + ck*8];
        h8 vvb = *(const h8*)&sVv[bi][drow*64 + ck*8];
        #pragma unroll
        for (int fq=0; fq<2; fq++){
          ctx[fq][fd] = mfma_h(pa[fq][ks], vb,  ctx[fq][fd]);
          var[fq][fd] = mfma_h(pa2[fq],    vvb, var[fq][fd]);
        }
      }
    }
    __syncthreads();
    #pragma unroll
    for (int fm=0; fm<4; fm++) xkf[fm] = xknxt[fm];
  }

  // epilogue: normalize; write ctx/ctx^2 f16 + var f32 (line-grouped)
  #pragma unroll
  for (int fq=0; fq<2; fq++)
    #pragma unroll
    for (int r=0;r<4;r++){
      int t = t0 + wq + fq*16 + l4*4 + r;
      float linv = 1.f / lacc[fq][r];
      size_t base = (size_t)t*D_MODEL + h*DK + l15;
      float c[4];
      #pragma unroll
      for (int fd=0; fd<4; fd++) c[fd] = ctx[fq][fd][r] * linv;
      #pragma unroll
      for (int fd=0; fd<4; fd++) ctx_out[base + fd*16]  = (_Float16)c[fd];
      #pragma unroll
      for (int fd=0; fd<4; fd++) ctx2_out[base + fd*16] = (_Float16)(c[fd]*c[fd]);
      #pragma unroll
      for (int fd=0; fd<4; fd++) var_out[base + fd*16]  = var[fq][fd][r] * linv * linv;
    }
}

// ---------------- host launch ----------------

extern "C" void kernel_launch(void* const* d_in, const int* in_sizes, int n_in,
                              void* d_out, int out_size, void* d_ws, size_t ws_size,
                              hipStream_t stream){
  (void)in_sizes; (void)n_in; (void)out_size; (void)ws_size;
  const float* H      = (const float*)d_in[0];
  const float* x_raw  = (const float*)d_in[1];
  const float* Wq_mu  = (const float*)d_in[2];
  const float* bq_mu  = (const float*)d_in[4];
  const float* Wk_mu  = (const float*)d_in[6];
  const float* bk_mu  = (const float*)d_in[8];
  const float* Wv_mu  = (const float*)d_in[10];
  const float* Wv_rho = (const float*)d_in[11];
  const float* bv_mu  = (const float*)d_in[12];
  const float* bv_rho = (const float*)d_in[13];
  const float* Wo_mu  = (const float*)d_in[14];
  const float* Wo_rho = (const float*)d_in[15];
  const float* bo_mu  = (const float*)d_in[16];
  const float* bo_rho = (const float*)d_in[17];
  const float* lsf    = (const float*)d_in[18];
  const float* lln    = (const float*)d_in[19];

  char* ws = (char*)d_ws;
  const size_t MB = 1024*1024;
  _Float16* Hh    = (_Float16*)(ws + 0*MB);     // 16MB
  _Float16* H2h   = (_Float16*)(ws + 16*MB);    // 16MB
  _Float16* Wcat  = (_Float16*)(ws + 32*MB);    // 8MB: [Wq|Wk|Wv|Wvs2] rows
  _Float16* Wocat = (_Float16*)(ws + 40*MB);    // 4MB: [Wo|Wos2] rows
  _Float16* Qh    = (_Float16*)(ws + 46*MB);    // 16MB
  _Float16* Kh    = (_Float16*)(ws + 62*MB);    // 16MB
  _Float16* Vt    = (_Float16*)(ws + 78*MB);    // 16MB, transposed [b][o][n]
  _Float16* Vvt   = (_Float16*)(ws + 94*MB);    // 16MB
  _Float16* ctxh  = (_Float16*)(ws + 110*MB);   // 16MB
  _Float16* ctx2h = (_Float16*)(ws + 126*MB);   // 16MB
  _Float16* xk    = (_Float16*)(ws + 142*MB);   // 512KB
  _Float16* xqb   = (_Float16*)(ws + 142*MB + 512*1024);  // 512KB

  float* out_mean = (float*)d_out;
  float* out_var  = out_mean + (size_t)TOK*D_MODEL;

  // prep (2 launches)
  prep_W <<<6144, 256, 0, stream>>>(Wq_mu, Wk_mu, Wv_mu, Wv_rho, Wo_mu, Wo_rho,
                                    Wcat, Wocat);
  prep_Hx<<<8224, 256, 0, stream>>>(H, x_raw, Hh, H2h, xk, xqb);

  // fused projections: Q | K | V | Vv in one launch (grid 64 x 32)
  gemm_fused<0><<<2048, 256, 0, stream>>>(Hh, H2h, Wcat,
      bq_mu, bk_mu, bv_mu, bv_rho,
      Qh, Kh, Vt, Vvt, nullptr, nullptr);

  // attention (writes ctxh/ctx2h f16 and var_attn into out_var)
  attn_kernel<<<1024, 256, 0, stream>>>(Qh, Kh, Vt, Vvt, xk, xqb, lsf, lln,
      ctxh, ctx2h, out_var);

  // fused output projections: out_mean | out_var (grid 64 x 16)
  gemm_fused<1><<<1024, 256, 0, stream>>>(ctxh, ctx2h, Wocat,
      bo_mu, bo_rho, nullptr, nullptr,
      nullptr, nullptr, nullptr, nullptr, out_mean, out_var);
}

// Round 9
// 318.251 us; speedup vs baseline: 1.4956x; 1.1018x over previous
//
#include <hip/hip_runtime.h>
#include <hip/hip_bf16.h>
#include <stdint.h>

// Bayesian MHA forward for MI355X (round 9).
// Attn frozen at r8 (139.8us, L2-lockstep regime). GEMM changes:
// (1) V/Vv transposed outputs now go through a 16KB LDS transpose
//     (reuses sA/sB) -> coalesced 16B stores instead of scattered 2B.
// (2) XCD-grouped block swizzle: XCD x owns bm in [8x,8x+8), iterated in
//     8bm x 8bn groups -> A(2MB)+B(2MB) working set fits the 4MB L2.

#define D_MODEL 1024
#define NSEQ    1024
#define BATCH   8
#define NHEADS  16
#define DK      64
#define TOK     8192   // BATCH*NSEQ

typedef _Float16  h8  __attribute__((ext_vector_type(8)));
typedef _Float16  h4  __attribute__((ext_vector_type(4)));
typedef float     f4  __attribute__((ext_vector_type(4)));

__device__ __forceinline__ f4 mfma_h(h8 a, h8 b, f4 c){
  return __builtin_amdgcn_mfma_f32_16x16x32_f16(a, b, c, 0, 0, 0);
}

// global -> LDS async copy, 16B per lane. LDS dest must be (uniform base + lane*16).
__device__ __forceinline__ void async_copy16(void* lds, const void* g){
  __builtin_amdgcn_global_load_lds(
      (const __attribute__((address_space(1))) unsigned int*)(uintptr_t)g,
      (__attribute__((address_space(3))) unsigned int*)(unsigned int)(uintptr_t)lds,
      16, 0, 0);
}

__device__ __forceinline__ float softplusf(float x){
  return (x > 20.f) ? x : log1pf(__expf(x));
}

// ---------------- prep kernels (fused) ----------------

// One launch for all weight preprocessing. 6 segments of DD=1M elements:
// 0: f16(Wq) 1: f16(Wk) 2: f16(Wv) 3: f16(sp(Wv_rho)^2) 4: f16(Wo) 5: f16(sp(Wo_rho)^2)
__global__ __launch_bounds__(256) void prep_W(
    const float* __restrict__ Wq, const float* __restrict__ Wk,
    const float* __restrict__ Wv, const float* __restrict__ Wvr,
    const float* __restrict__ Wo, const float* __restrict__ Wor,
    _Float16* __restrict__ Wcat, _Float16* __restrict__ Wocat)
{
  const int bid = blockIdx.x;
  const int seg = bid >> 10;                 // 1024 blocks per segment
  const int i   = ((bid & 1023)*256 + threadIdx.x)*4;
  const float* src = seg==0 ? Wq : seg==1 ? Wk : seg==2 ? Wv : seg==3 ? Wvr : seg==4 ? Wo : Wor;
  _Float16* dst = (seg < 4) ? (Wcat + (size_t)seg*1048576)
                            : (Wocat + (size_t)(seg-4)*1048576);
  const bool sp2 = (seg==3) || (seg==5);
  float4 v = *(const float4*)(src + i);
  float vv[4] = {v.x, v.y, v.z, v.w};
  #pragma unroll
  for (int j=0;j<4;j++){
    float f = vv[j];
    if (sp2){ float s = softplusf(f); f = s*s; }
    dst[i+j] = (_Float16)f;
  }
}

// One launch for H and x_raw preprocessing.
// bids [0,8192): Hh = f16(H), H2h = f16(H*H)  (1024 elems/block)
// bids [8192,8224): xk/xq padded RBF rows (256 tokens/block)
//   xk[t][32] = [x(16), x2hi, x2lo, 1, 1, 0(12)]
//   xq[t][32] = [2x(16), -1, -1, -x2hi, -x2lo, 0(12)]
//   => dot(xk[m], xq[q]) = -dist2(m,q)
__global__ __launch_bounds__(256) void prep_Hx(
    const float* __restrict__ H, const float* __restrict__ x,
    _Float16* __restrict__ Hh, _Float16* __restrict__ H2h,
    _Float16* __restrict__ xk, _Float16* __restrict__ xq)
{
  const int bid = blockIdx.x;
  if (bid < 8192){
    int i = (bid*256 + threadIdx.x)*4;
    float4 v = *(const float4*)(H + i);
    float vv[4] = {v.x, v.y, v.z, v.w};
    #pragma unroll
    for (int j=0;j<4;j++){
      Hh[i+j]  = (_Float16)vv[j];
      H2h[i+j] = (_Float16)(vv[j]*vv[j]);
    }
  } else {
    int t = (bid - 8192)*256 + threadIdx.x;
    const float* p = x + (size_t)t*16;
    _Float16 a[32], bb[32];
    float s = 0.f;
    #pragma unroll
    for (int j=0;j<16;j++){
      float f = p[j];
      a[j]  = (_Float16)f;
      bb[j] = (_Float16)(2.f*f);
      s += f*f;
    }
    _Float16 shi = (_Float16)s;
    _Float16 slo = (_Float16)(s - (float)shi);
    a[16]=shi; a[17]=slo; a[18]=(_Float16)1.f; a[19]=(_Float16)1.f;
    bb[16]=(_Float16)-1.f; bb[17]=(_Float16)-1.f; bb[18]=-shi; bb[19]=-slo;
    #pragma unroll
    for (int j=20;j<32;j++){ a[j]=(_Float16)0.f; bb[j]=(_Float16)0.f; }
    #pragma unroll
    for (int j=0;j<4;j++){
      *(h8*)(xk + (size_t)t*32 + j*8) = *(const h8*)&a[j*8];
      *(h8*)(xq + (size_t)t*32 + j*8) = *(const h8*)&bb[j*8];
    }
  }
}

// ---------------- fused GEMM: C = A @ Wcat^T (+bias) ----------------
// MODE 0: projections. 4 segments of 1024 cols: Q, K, V, Vv.
//   A = Hh (segs 0-2) or H2h (seg 3). Q/K stored [row][col] f16 directly;
//   V/Vv transposed to [b][col][row&1023] via LDS transpose (coalesced).
// MODE 1: outputs. 2 segments: out_mean (f32), out_var (f32, += addend in place).
// 128x128 tile, BK=32, 4 waves (2x2). XOR-swizzled LDS chunks.
template<int MODE>
__global__ __launch_bounds__(256) void gemm_fused(
    const _Float16* __restrict__ A0, const _Float16* __restrict__ A1,
    const _Float16* __restrict__ Wcat,
    const float* __restrict__ bias0, const float* __restrict__ bias1,
    const float* __restrict__ bias2, const float* __restrict__ bias3,
    _Float16* __restrict__ Qo, _Float16* __restrict__ Ko,
    _Float16* __restrict__ Vto, _Float16* __restrict__ Vvto,
    float* __restrict__ meanO, float* __restrict__ varO)
{
  constexpr int NBN = (MODE==0) ? 32 : 16;     // n-tiles (4096 or 2048 cols)
  __shared__ _Float16 smem[8192];              // sA | sB; reused as transpose buf
  _Float16* sA = smem;
  _Float16* sB = smem + 4096;
  const int tid = threadIdx.x;
  const int lane = tid & 63;
  const int wid  = tid >> 6;
  const int wm = wid >> 1, wn = wid & 1;
  const int l15 = lane & 15, l4 = lane >> 4;
  // XCD-grouped bijective swizzle: XCD x owns bm in [8x,8x+8); within the
  // XCD, 8bm x 8bn groups keep A(2MB)+B(2MB) ~ L2-resident.
  const int bid = blockIdx.x;
  const int x   = bid & 7;
  const int idx = bid >> 3;
  const int grp = idx >> 6;                    // 0..(NBN/8-1)
  const int inr = idx & 63;
  const int bm  = (x << 3) + (inr & 7);
  const int bn  = (grp << 3) + (inr >> 3);
  const int row0 = bm << 7, col0 = bn << 7;
  const int seg = col0 >> 10;

  const _Float16* A = (MODE==0) ? (seg < 3 ? A0 : A1) : (seg == 0 ? A0 : A1);
  const _Float16* B = Wcat + (size_t)col0 * 1024;

  f4 acc[4][4];
  #pragma unroll
  for (int i=0;i<4;i++)
    #pragma unroll
    for (int j=0;j<4;j++)
      #pragma unroll
      for (int r=0;r<4;r++) acc[i][j][r] = 0.f;

  const int c0 = tid, c1 = tid + 256;
  const int r0 = c0 >> 2, ch0 = c0 & 3;
  const int r1 = c1 >> 2, ch1 = c1 & 3;
  const int k0off = ((ch0 ^ (r0 & 3)) << 3);
  const int k1off = ((ch1 ^ (r1 & 3)) << 3);

  for (int kt = 0; kt < 1024; kt += 32){
    __syncthreads();
    async_copy16(&sA[c0*8], A + (size_t)(row0+r0)*1024 + kt + k0off);
    async_copy16(&sA[c1*8], A + (size_t)(row0+r1)*1024 + kt + k1off);
    async_copy16(&sB[c0*8], B + (size_t)r0*1024 + kt + k0off);
    async_copy16(&sB[c1*8], B + (size_t)r1*1024 + kt + k1off);
    __syncthreads();

    h8 a[4], b[4];
    #pragma unroll
    for (int mf=0; mf<4; mf++){
      int r  = (wm<<6) + (mf<<4) + l15;
      int ck = l4 ^ (r & 3);
      a[mf] = *(const h8*)&sA[r*32 + ck*8];
    }
    #pragma unroll
    for (int nf=0; nf<4; nf++){
      int r  = (wn<<6) + (nf<<4) + l15;
      int ck = l4 ^ (r & 3);
      b[nf] = *(const h8*)&sB[r*32 + ck*8];
    }
    #pragma unroll
    for (int mf=0; mf<4; mf++)
      #pragma unroll
      for (int nf=0; nf<4; nf++)
        acc[mf][nf] = mfma_h(a[mf], b[nf], acc[mf][nf]);
  }

  if (MODE==0 && seg >= 2){
    // --- V/Vv: transpose through LDS (XOR-swizzled), coalesced 16B stores ---
    _Float16* T = (seg==2) ? Vto : Vvto;
    const size_t tbase = ((size_t)(row0>>10)<<20)
                       + (size_t)(col0 & 1023)*1024 + (row0 & 1023);
    const int o  = tid >> 1;        // output row (= C col), 0..127
    const int hf = tid & 1;
    #pragma unroll
    for (int rh=0; rh<2; rh++){     // half-passes over C rows [rh*64, rh*64+64)
      __syncthreads();              // protect smem vs K-loop / prev pass reads
      if (wm == rh){
        #pragma unroll
        for (int nf=0; nf<4; nf++){
          int col = (wn<<6) + (nf<<4) + l15;          // 0..127
          float bb2 = (seg==2) ? bias2[(col0 + col) & 1023]
                               : bias3[(col0 + col) & 1023];
          float bv;
          if (seg==3){ float s = softplusf(bb2); bv = s*s; } else bv = bb2;
          #pragma unroll
          for (int mf=0; mf<4; mf++){
            int n   = (mf<<4) + (l4<<2);              // row-in-half, 4-aligned
            int nsw = n ^ ((col & 7) << 3);
            h4 hv;
            #pragma unroll
            for (int r=0;r<4;r++) hv[r] = (_Float16)(acc[mf][nf][r] + bv);
            *(h4*)&smem[col*64 + nsw] = hv;
          }
        }
      }
      __syncthreads();
      #pragma unroll
      for (int j=0; j<4; j++){
        int n   = hf*8 + j*16;                        // 8-aligned
        int nsw = n ^ ((o & 7) << 3);
        h8 v = *(const h8*)&smem[o*64 + nsw];
        *(h8*)(T + tbase + (size_t)o*1024 + rh*64 + n) = v;
      }
    }
    return;
  }

  // --- direct epilogues (Q/K f16 rows; MODE1 f32 outputs) ---
  const float* bias = (MODE==0) ? (seg==0 ? bias0 : bias1)
                                : (seg==0 ? bias0 : bias1);
  const bool sp2 = (MODE==1) && (seg==1);

  #pragma unroll
  for (int nf=0; nf<4; nf++){
    int colg = col0 + (wn<<6) + (nf<<4) + l15;
    int colm = colg & 1023;
    float bb = bias[colm];
    float bv = sp2 ? ({ float s = softplusf(bb); s*s; }) : bb;
    #pragma unroll
    for (int mf=0; mf<4; mf++){
      int rbase = row0 + (wm<<6) + (mf<<4) + (l4<<2);
      #pragma unroll
      for (int r=0;r<4;r++){
        int row = rbase + r;
        float v = acc[mf][nf][r] + bv;
        if (MODE==0){
          if (seg==0) Qo[(size_t)row*1024 + colm] = (_Float16)v;
          else        Ko[(size_t)row*1024 + colm] = (_Float16)v;
        } else {
          size_t idxo = (size_t)row*1024 + colm;
          if (seg==0) meanO[idxo] = v;
          else        varO[idxo] = v + varO[idxo];
        }
      }
    }
  }
}

// ---------------- fused attention (flash-style, + RBF scores) ----------------
// 1024 blocks = 8 q-tiles x (B*H), 4 waves x 32 q-rows. All-dbuf staging,
// ONE barrier/iter (lockstep blocks -> L2 reuse). Swapped QK^T with K-row
// permutation rho(fm,w) = (fm&1)*4 + (w&3) + (w>>2)*8 + (fm>>1)*32 so the
// score C-regs repack in-lane straight into PV's A-fragment k-slots.
// 2 blocks/CU: 8 bh-groups x 384KB = 3MB per XCD L2 (fits; 3/CU thrashed).
__global__ __launch_bounds__(256, 2) void attn_kernel(
    const _Float16* __restrict__ Qh, const _Float16* __restrict__ Kh,
    const _Float16* __restrict__ Vt, const _Float16* __restrict__ Vvt,
    const _Float16* __restrict__ xk, const _Float16* __restrict__ xq,
    const float* __restrict__ log_sigma_f, const float* __restrict__ log_length,
    _Float16* __restrict__ ctx_out, _Float16* __restrict__ ctx2_out,
    float* __restrict__ var_out)
{
  const int bid = blockIdx.x;
  const int swz = (bid & 7) * 128 + (bid >> 3);
  const int qt = swz & 7;
  const int bh = swz >> 3;
  const int b  = bh >> 4, h = bh & 15;
  const int tid = threadIdx.x;
  const int lane = tid & 63, wid = tid >> 6;
  const int l15 = lane & 15, l4 = lane >> 4;
  const float L2E   = 1.44269504f;
  const float sig2l = __expf(2.f*log_sigma_f[h]) * L2E;      // sigma_f^2 * log2(e)
  const float e2c   = 0.5f*__expf(-2.f*log_length[h]) * L2E; // 1/(2 l^2) * log2(e)
  const float cqk   = 0.125f * L2E;

  __shared__ _Float16 sK[2][4096];   // [m][d] 64x64, g-swizzled
  __shared__ _Float16 sV[2][4096];   // [d][m]
  __shared__ _Float16 sVv[2][4096];  // [d][m]

  const int t0 = b*NSEQ + qt*128;
  const int wq = wid*32;

  // permuted K-row for this lane per fm (constant across tiles)
  int krow_[4];
  #pragma unroll
  for (int fm=0; fm<4; fm++)
    krow_[fm] = ((fm&1)<<2) + (l15&3) + ((l15>>2)<<3) + ((fm>>1)<<5);

  // Q fragments (B-side: lane l15 = q-row)
  h8 qf[2][2];
  #pragma unroll
  for (int fq=0; fq<2; fq++)
    #pragma unroll
    for (int ks=0; ks<2; ks++){
      size_t off = (size_t)(t0 + wq + fq*16 + l15)*D_MODEL + h*DK + ks*32 + l4*8;
      qf[fq][ks] = *(const h8*)(Qh + off);
    }
  // RBF Q-side rows (full 32-slot padded vector, no branches)
  h8 xqf[2];
  #pragma unroll
  for (int fq=0; fq<2; fq++)
    xqf[fq] = *(const h8*)(xq + (size_t)(t0 + wq + fq*16 + l15)*32 + l4*8);

  h8 ones;
  #pragma unroll
  for (int j=0;j<8;j++) ones[j] = (_Float16)1.f;

  float mrun[2] = {-1e30f, -1e30f};   // log2 domain
  f4 lacc[2], ctx[2][4], var[2][4];
  #pragma unroll
  for (int fq=0; fq<2; fq++){
    #pragma unroll
    for (int r=0;r<4;r++) lacc[fq][r] = 0.f;
    #pragma unroll
    for (int fd=0; fd<4; fd++)
      #pragma unroll
      for (int r=0;r<4;r++){ ctx[fq][fd][r] = 0.f; var[fq][fd][r] = 0.f; }
  }

  // staging: 1536 chunks of 16B (K 512 w/ g-swizzle, V 512, Vv 512)
  auto stage = [&](int bi, int mt){
    #pragma unroll
    for (int k=0;k<6;k++){
      int c = tid + k*256;
      if (k < 2){
        int rg = c >> 3, ch = c & 7;
        int g  = (rg & 3) | (((rg >> 3) & 1) << 2);
        int sw = ((ch ^ g) << 3);
        async_copy16(&sK[bi][c*8], Kh + (size_t)(b*NSEQ + mt + rg)*D_MODEL + h*DK + sw);
      } else if (k < 4){
        int cc = c - 512; int rg = cc >> 3, sw = (((cc & 7) ^ (rg & 7)) << 3);
        async_copy16(&sV[bi][cc*8], Vt + ((size_t)b << 20) + (size_t)(h*DK + rg)*NSEQ + mt + sw);
      } else {
        int cc = c - 1024; int rg = cc >> 3, sw = (((cc & 7) ^ (rg & 7)) << 3);
        async_copy16(&sVv[bi][cc*8], Vvt + ((size_t)b << 20) + (size_t)(h*DK + rg)*NSEQ + mt + sw);
      }
    }
  };

  // xk fragments: current tile (xkf) + next tile (xknxt), register-prefetched
  h8 xkf[4], xknxt[4];
  #pragma unroll
  for (int fm=0; fm<4; fm++)
    xkf[fm] = *(const h8*)(xk + (size_t)(b*NSEQ + krow_[fm])*32 + l4*8);

  stage(0, 0);
  __syncthreads();

  for (int it = 0; it < NSEQ/64; it++){
    const int bi = it & 1;
    const int mt = it*64;
    if (it + 1 < NSEQ/64){
      stage(bi^1, mt + 64);
      #pragma unroll
      for (int fm=0; fm<4; fm++)
        xknxt[fm] = *(const h8*)(xk + (size_t)(b*NSEQ + mt + 64 + krow_[fm])*32 + l4*8);
    }

    // scores (swapped): S'[fq][fm][r] for m-row rho(fm, l4*4+r), q = l15
    f4 S[2][4];
    #pragma unroll
    for (int fm=0; fm<4; fm++){
      const int krow = krow_[fm];
      const int g    = (krow & 3) | (((krow >> 3) & 1) << 2);
      h8 kb0 = *(const h8*)&sK[bi][krow*64 + ((l4      ^ g))*8];
      h8 kb1 = *(const h8*)&sK[bi][krow*64 + (((4+l4) ^ g))*8];
      #pragma unroll
      for (int fq=0; fq<2; fq++){
        f4 s, xd;
        #pragma unroll
        for (int r=0;r<4;r++){ s[r]=0.f; xd[r]=0.f; }
        s  = mfma_h(kb0, qf[fq][0], s);
        s  = mfma_h(kb1, qf[fq][1], s);
        xd = mfma_h(xkf[fm], xqf[fq], xd);         // = -dist2
        #pragma unroll
        for (int r=0;r<4;r++)
          S[fq][fm][r] = s[r]*cqk + sig2l*exp2f(fminf(xd[r],0.f)*e2c);
      }
    }

    // softmax (log2 domain), defer-max thr = 4*log2e = 5.77
    h8 pa[2][2];
    #pragma unroll
    for (int fq=0; fq<2; fq++){
      float tm = S[fq][0][0];
      #pragma unroll
      for (int fm=0; fm<4; fm++)
        #pragma unroll
        for (int r=0;r<4;r++) tm = fmaxf(tm, S[fq][fm][r]);
      tm = fmaxf(tm, __shfl_xor(tm, 16));
      tm = fmaxf(tm, __shfl_xor(tm, 32));
      int nd = tm > mrun[fq] + 5.7708f;
      if (__any(nd)){
        float mn = fmaxf(mrun[fq], tm);
        float sc = exp2f(mrun[fq] - mn);          // per q = l15
        mrun[fq] = mn;
        float scr[4];
        #pragma unroll
        for (int r=0;r<4;r++) scr[r] = __shfl(sc, (l4<<2) + r);  // q = l4*4+r
        #pragma unroll
        for (int r=0;r<4;r++) lacc[fq][r] *= scr[r];
        #pragma unroll
        for (int fd=0; fd<4; fd++)
          #pragma unroll
          for (int r=0;r<4;r++){
            ctx[fq][fd][r] *= scr[r];
            var[fq][fd][r] *= scr[r]*scr[r];
          }
      }
      // P = exp2(S' - m'); in-lane repack: slot(ks=fm>>1, j=(fm&1)*4+r) -> m = ks*32+l4*8+j
      #pragma unroll
      for (int fm=0; fm<4; fm++)
        #pragma unroll
        for (int r=0;r<4;r++)
          pa[fq][fm>>1][((fm&1)<<2) + r] = (_Float16)exp2f(S[fq][fm][r] - mrun[fq]);
    }

    // PV: ctx += P@V, var += P^2@Vv, l += P@1
    #pragma unroll
    for (int ks=0; ks<2; ks++){
      h8 pa2[2];
      #pragma unroll
      for (int fq=0; fq<2; fq++){
        pa2[fq] = pa[fq][ks]*pa[fq][ks];
        lacc[fq] = mfma_h(pa[fq][ks], ones, lacc[fq]);
      }
      #pragma unroll
      for (int fd=0; fd<4; fd++){
        int drow = fd*16 + l15;
        int ck = (ks*4 + l4) ^ (drow & 7);
        h8 vb  = *(const h8*)&sV[bi][drow*64 + ck*8];
        h8 vvb = *(const h8*)&sVv[bi][drow*64 + ck*8];
        #pragma unroll
        for (int fq=0; fq<2; fq++){
          ctx[fq][fd] = mfma_h(pa[fq][ks], vb,  ctx[fq][fd]);
          var[fq][fd] = mfma_h(pa2[fq],    vvb, var[fq][fd]);
        }
      }
    }
    __syncthreads();
    #pragma unroll
    for (int fm=0; fm<4; fm++) xkf[fm] = xknxt[fm];
  }

  // epilogue: normalize; write ctx/ctx^2 f16 + var f32 (line-grouped)
  #pragma unroll
  for (int fq=0; fq<2; fq++)
    #pragma unroll
    for (int r=0;r<4;r++){
      int t = t0 + wq + fq*16 + l4*4 + r;
      float linv = 1.f / lacc[fq][r];
      size_t base = (size_t)t*D_MODEL + h*DK + l15;
      float c[4];
      #pragma unroll
      for (int fd=0; fd<4; fd++) c[fd] = ctx[fq][fd][r] * linv;
      #pragma unroll
      for (int fd=0; fd<4; fd++) ctx_out[base + fd*16]  = (_Float16)c[fd];
      #pragma unroll
      for (int fd=0; fd<4; fd++) ctx2_out[base + fd*16] = (_Float16)(c[fd]*c[fd]);
      #pragma unroll
      for (int fd=0; fd<4; fd++) var_out[base + fd*16]  = var[fq][fd][r] * linv * linv;
    }
}

// ---------------- host launch ----------------

extern "C" void kernel_launch(void* const* d_in, const int* in_sizes, int n_in,
                              void* d_out, int out_size, void* d_ws, size_t ws_size,
                              hipStream_t stream){
  (void)in_sizes; (void)n_in; (void)out_size; (void)ws_size;
  const float* H      = (const float*)d_in[0];
  const float* x_raw  = (const float*)d_in[1];
  const float* Wq_mu  = (const float*)d_in[2];
  const float* bq_mu  = (const float*)d_in[4];
  const float* Wk_mu  = (const float*)d_in[6];
  const float* bk_mu  = (const float*)d_in[8];
  const float* Wv_mu  = (const float*)d_in[10];
  const float* Wv_rho = (const float*)d_in[11];
  const float* bv_mu  = (const float*)d_in[12];
  const float* bv_rho = (const float*)d_in[13];
  const float* Wo_mu  = (const float*)d_in[14];
  const float* Wo_rho = (const float*)d_in[15];
  const float* bo_mu  = (const float*)d_in[16];
  const float* bo_rho = (const float*)d_in[17];
  const float* lsf    = (const float*)d_in[18];
  const float* lln    = (const float*)d_in[19];

  char* ws = (char*)d_ws;
  const size_t MB = 1024*1024;
  _Float16* Hh    = (_Float16*)(ws + 0*MB);     // 16MB
  _Float16* H2h   = (_Float16*)(ws + 16*MB);    // 16MB
  _Float16* Wcat  = (_Float16*)(ws + 32*MB);    // 8MB: [Wq|Wk|Wv|Wvs2] rows
  _Float16* Wocat = (_Float16*)(ws + 40*MB);    // 4MB: [Wo|Wos2] rows
  _Float16* Qh    = (_Float16*)(ws + 46*MB);    // 16MB
  _Float16* Kh    = (_Float16*)(ws + 62*MB);    // 16MB
  _Float16* Vt    = (_Float16*)(ws + 78*MB);    // 16MB, transposed [b][o][n]
  _Float16* Vvt   = (_Float16*)(ws + 94*MB);    // 16MB
  _Float16* ctxh  = (_Float16*)(ws + 110*MB);   // 16MB
  _Float16* ctx2h = (_Float16*)(ws + 126*MB);   // 16MB
  _Float16* xk    = (_Float16*)(ws + 142*MB);   // 512KB
  _Float16* xqb   = (_Float16*)(ws + 142*MB + 512*1024);  // 512KB

  float* out_mean = (float*)d_out;
  float* out_var  = out_mean + (size_t)TOK*D_MODEL;

  // prep (2 launches)
  prep_W <<<6144, 256, 0, stream>>>(Wq_mu, Wk_mu, Wv_mu, Wv_rho, Wo_mu, Wo_rho,
                                    Wcat, Wocat);
  prep_Hx<<<8224, 256, 0, stream>>>(H, x_raw, Hh, H2h, xk, xqb);

  // fused projections: Q | K | V | Vv in one launch (grid 64 x 32)
  gemm_fused<0><<<2048, 256, 0, stream>>>(Hh, H2h, Wcat,
      bq_mu, bk_mu, bv_mu, bv_rho,
      Qh, Kh, Vt, Vvt, nullptr, nullptr);

  // attention (writes ctxh/ctx2h f16 and var_attn into out_var)
  attn_kernel<<<1024, 256, 0, stream>>>(Qh, Kh, Vt, Vvt, xk, xqb, lsf, lln,
      ctxh, ctx2h, out_var);

  // fused output projections: out_mean | out_var (grid 64 x 16)
  gemm_fused<1><<<1024, 256, 0, stream>>>(ctxh, ctx2h, Wocat,
      bo_mu, bo_rho, nullptr, nullptr,
      nullptr, nullptr, nullptr, nullptr, out_mean, out_var);
}

// Round 10
// 304.291 us; speedup vs baseline: 1.5642x; 1.0459x over previous
//
#include <hip/hip_runtime.h>
#include <hip/hip_bf16.h>
#include <stdint.h>

// Bayesian MHA forward for MI355X (round 10).
// r9 structure. Attn VALU trims via constant folding:
//  - cqk (0.125*log2e) folded into Q at the projection epilogue
//  - e2c folded into the xq RBF fragment (one-time f16 scale per block)
//  - fminf clamp on xd dropped (xd<=0 up to rounding; exp2(+eps)~1)
// Preps merged into one launch.

#define D_MODEL 1024
#define NSEQ    1024
#define BATCH   8
#define NHEADS  16
#define DK      64
#define TOK     8192   // BATCH*NSEQ

typedef _Float16  h8  __attribute__((ext_vector_type(8)));
typedef _Float16  h4  __attribute__((ext_vector_type(4)));
typedef float     f4  __attribute__((ext_vector_type(4)));

__device__ __forceinline__ f4 mfma_h(h8 a, h8 b, f4 c){
  return __builtin_amdgcn_mfma_f32_16x16x32_f16(a, b, c, 0, 0, 0);
}

// global -> LDS async copy, 16B per lane. LDS dest must be (uniform base + lane*16).
__device__ __forceinline__ void async_copy16(void* lds, const void* g){
  __builtin_amdgcn_global_load_lds(
      (const __attribute__((address_space(1))) unsigned int*)(uintptr_t)g,
      (__attribute__((address_space(3))) unsigned int*)(unsigned int)(uintptr_t)lds,
      16, 0, 0);
}

__device__ __forceinline__ float softplusf(float x){
  return (x > 20.f) ? x : log1pf(__expf(x));
}

// ---------------- prep (single launch) ----------------
// bids [0,6144): weights -> 6 segments of 1M: f16(Wq|Wk|Wv|sp2(Wvr)) -> Wcat,
//                f16(Wo|sp2(Wor)) -> Wocat
// bids [6144,14336): Hh = f16(H), H2h = f16(H*H)
// bids [14336,14368): xk/xq padded RBF rows (256 tokens/block)
//   xk[t][32] = [x(16), x2hi, x2lo, 1, 1, 0(12)]
//   xq[t][32] = [2x(16), -1, -1, -x2hi, -x2lo, 0(12)]
//   => dot(xk[m], xq[q]) = -dist2(m,q)
__global__ __launch_bounds__(256) void prep_all(
    const float* __restrict__ Wq, const float* __restrict__ Wk,
    const float* __restrict__ Wv, const float* __restrict__ Wvr,
    const float* __restrict__ Wo, const float* __restrict__ Wor,
    const float* __restrict__ H, const float* __restrict__ x,
    _Float16* __restrict__ Wcat, _Float16* __restrict__ Wocat,
    _Float16* __restrict__ Hh, _Float16* __restrict__ H2h,
    _Float16* __restrict__ xk, _Float16* __restrict__ xq)
{
  const int bid = blockIdx.x;
  if (bid < 6144){
    const int seg = bid >> 10;
    const int i   = ((bid & 1023)*256 + threadIdx.x)*4;
    const float* src = seg==0 ? Wq : seg==1 ? Wk : seg==2 ? Wv : seg==3 ? Wvr : seg==4 ? Wo : Wor;
    _Float16* dst = (seg < 4) ? (Wcat + (size_t)seg*1048576)
                              : (Wocat + (size_t)(seg-4)*1048576);
    const bool sp2 = (seg==3) || (seg==5);
    float4 v = *(const float4*)(src + i);
    float vv[4] = {v.x, v.y, v.z, v.w};
    #pragma unroll
    for (int j=0;j<4;j++){
      float f = vv[j];
      if (sp2){ float s = softplusf(f); f = s*s; }
      dst[i+j] = (_Float16)f;
    }
  } else if (bid < 14336){
    int i = ((bid - 6144)*256 + threadIdx.x)*4;
    float4 v = *(const float4*)(H + i);
    float vv[4] = {v.x, v.y, v.z, v.w};
    #pragma unroll
    for (int j=0;j<4;j++){
      Hh[i+j]  = (_Float16)vv[j];
      H2h[i+j] = (_Float16)(vv[j]*vv[j]);
    }
  } else {
    int t = (bid - 14336)*256 + threadIdx.x;
    const float* p = x + (size_t)t*16;
    _Float16 a[32], bb[32];
    float s = 0.f;
    #pragma unroll
    for (int j=0;j<16;j++){
      float f = p[j];
      a[j]  = (_Float16)f;
      bb[j] = (_Float16)(2.f*f);
      s += f*f;
    }
    _Float16 shi = (_Float16)s;
    _Float16 slo = (_Float16)(s - (float)shi);
    a[16]=shi; a[17]=slo; a[18]=(_Float16)1.f; a[19]=(_Float16)1.f;
    bb[16]=(_Float16)-1.f; bb[17]=(_Float16)-1.f; bb[18]=-shi; bb[19]=-slo;
    #pragma unroll
    for (int j=20;j<32;j++){ a[j]=(_Float16)0.f; bb[j]=(_Float16)0.f; }
    #pragma unroll
    for (int j=0;j<4;j++){
      *(h8*)(xk + (size_t)t*32 + j*8) = *(const h8*)&a[j*8];
      *(h8*)(xq + (size_t)t*32 + j*8) = *(const h8*)&bb[j*8];
    }
  }
}

// ---------------- fused GEMM: C = A @ Wcat^T (+bias) ----------------
// MODE 0: projections. 4 segments of 1024 cols: Q, K, V, Vv.
//   A = Hh (segs 0-2) or H2h (seg 3). Q (scaled by cqk) / K stored
//   [row][col] f16; V/Vv transposed to [b][col][row&1023] via LDS transpose.
// MODE 1: outputs. 2 segments: out_mean (f32), out_var (f32, += addend in place).
// 128x128 tile, BK=32, 4 waves (2x2). XOR-swizzled LDS chunks. XCD-grouped swizzle.
template<int MODE>
__global__ __launch_bounds__(256) void gemm_fused(
    const _Float16* __restrict__ A0, const _Float16* __restrict__ A1,
    const _Float16* __restrict__ Wcat,
    const float* __restrict__ bias0, const float* __restrict__ bias1,
    const float* __restrict__ bias2, const float* __restrict__ bias3,
    _Float16* __restrict__ Qo, _Float16* __restrict__ Ko,
    _Float16* __restrict__ Vto, _Float16* __restrict__ Vvto,
    float* __restrict__ meanO, float* __restrict__ varO)
{
  constexpr int NBN = (MODE==0) ? 32 : 16;     // n-tiles (4096 or 2048 cols)
  __shared__ _Float16 smem[8192];              // sA | sB; reused as transpose buf
  _Float16* sA = smem;
  _Float16* sB = smem + 4096;
  const int tid = threadIdx.x;
  const int lane = tid & 63;
  const int wid  = tid >> 6;
  const int wm = wid >> 1, wn = wid & 1;
  const int l15 = lane & 15, l4 = lane >> 4;
  // XCD-grouped bijective swizzle: XCD x owns bm in [8x,8x+8); within the
  // XCD, 8bm x 8bn groups keep A(2MB)+B(2MB) ~ L2-resident.
  const int bid = blockIdx.x;
  const int x   = bid & 7;
  const int idx = bid >> 3;
  const int grp = idx >> 6;                    // 0..(NBN/8-1)
  const int inr = idx & 63;
  const int bm  = (x << 3) + (inr & 7);
  const int bn  = (grp << 3) + (inr >> 3);
  const int row0 = bm << 7, col0 = bn << 7;
  const int seg = col0 >> 10;

  const _Float16* A = (MODE==0) ? (seg < 3 ? A0 : A1) : (seg == 0 ? A0 : A1);
  const _Float16* B = Wcat + (size_t)col0 * 1024;

  f4 acc[4][4];
  #pragma unroll
  for (int i=0;i<4;i++)
    #pragma unroll
    for (int j=0;j<4;j++)
      #pragma unroll
      for (int r=0;r<4;r++) acc[i][j][r] = 0.f;

  const int c0 = tid, c1 = tid + 256;
  const int r0 = c0 >> 2, ch0 = c0 & 3;
  const int r1 = c1 >> 2, ch1 = c1 & 3;
  const int k0off = ((ch0 ^ (r0 & 3)) << 3);
  const int k1off = ((ch1 ^ (r1 & 3)) << 3);

  for (int kt = 0; kt < 1024; kt += 32){
    __syncthreads();
    async_copy16(&sA[c0*8], A + (size_t)(row0+r0)*1024 + kt + k0off);
    async_copy16(&sA[c1*8], A + (size_t)(row0+r1)*1024 + kt + k1off);
    async_copy16(&sB[c0*8], B + (size_t)r0*1024 + kt + k0off);
    async_copy16(&sB[c1*8], B + (size_t)r1*1024 + kt + k1off);
    __syncthreads();

    h8 a[4], b[4];
    #pragma unroll
    for (int mf=0; mf<4; mf++){
      int r  = (wm<<6) + (mf<<4) + l15;
      int ck = l4 ^ (r & 3);
      a[mf] = *(const h8*)&sA[r*32 + ck*8];
    }
    #pragma unroll
    for (int nf=0; nf<4; nf++){
      int r  = (wn<<6) + (nf<<4) + l15;
      int ck = l4 ^ (r & 3);
      b[nf] = *(const h8*)&sB[r*32 + ck*8];
    }
    #pragma unroll
    for (int mf=0; mf<4; mf++)
      #pragma unroll
      for (int nf=0; nf<4; nf++)
        acc[mf][nf] = mfma_h(a[mf], b[nf], acc[mf][nf]);
  }

  if (MODE==0 && seg >= 2){
    // --- V/Vv: transpose through LDS (XOR-swizzled), coalesced 16B stores ---
    _Float16* T = (seg==2) ? Vto : Vvto;
    const size_t tbase = ((size_t)(row0>>10)<<20)
                       + (size_t)(col0 & 1023)*1024 + (row0 & 1023);
    const int o  = tid >> 1;        // output row (= C col), 0..127
    const int hf = tid & 1;
    #pragma unroll
    for (int rh=0; rh<2; rh++){     // half-passes over C rows [rh*64, rh*64+64)
      __syncthreads();              // protect smem vs K-loop / prev pass reads
      if (wm == rh){
        #pragma unroll
        for (int nf=0; nf<4; nf++){
          int col = (wn<<6) + (nf<<4) + l15;          // 0..127
          float bb2 = (seg==2) ? bias2[(col0 + col) & 1023]
                               : bias3[(col0 + col) & 1023];
          float bv;
          if (seg==3){ float s = softplusf(bb2); bv = s*s; } else bv = bb2;
          #pragma unroll
          for (int mf=0; mf<4; mf++){
            int n   = (mf<<4) + (l4<<2);              // row-in-half, 4-aligned
            int nsw = n ^ ((col & 7) << 3);
            h4 hv;
            #pragma unroll
            for (int r=0;r<4;r++) hv[r] = (_Float16)(acc[mf][nf][r] + bv);
            *(h4*)&smem[col*64 + nsw] = hv;
          }
        }
      }
      __syncthreads();
      #pragma unroll
      for (int j=0; j<4; j++){
        int n   = hf*8 + j*16;                        // 8-aligned
        int nsw = n ^ ((o & 7) << 3);
        h8 v = *(const h8*)&smem[o*64 + nsw];
        *(h8*)(T + tbase + (size_t)o*1024 + rh*64 + n) = v;
      }
    }
    return;
  }

  // --- direct epilogues (Q/K f16 rows; MODE1 f32 outputs) ---
  const float* bias = (seg==0) ? bias0 : bias1;
  const bool sp2 = (MODE==1) && (seg==1);
  const float CQK = 0.18033688f;   // 0.125 * log2(e), folded into Q

  #pragma unroll
  for (int nf=0; nf<4; nf++){
    int colg = col0 + (wn<<6) + (nf<<4) + l15;
    int colm = colg & 1023;
    float bb = bias[colm];
    float bv = sp2 ? ({ float s = softplusf(bb); s*s; }) : bb;
    #pragma unroll
    for (int mf=0; mf<4; mf++){
      int rbase = row0 + (wm<<6) + (mf<<4) + (l4<<2);
      #pragma unroll
      for (int r=0;r<4;r++){
        int row = rbase + r;
        float v = acc[mf][nf][r] + bv;
        if (MODE==0){
          if (seg==0) Qo[(size_t)row*1024 + colm] = (_Float16)(v * CQK);
          else        Ko[(size_t)row*1024 + colm] = (_Float16)v;
        } else {
          size_t idxo = (size_t)row*1024 + colm;
          if (seg==0) meanO[idxo] = v;
          else        varO[idxo] = v + varO[idxo];
        }
      }
    }
  }
}

// ---------------- fused attention (flash-style, + RBF scores) ----------------
// 1024 blocks = 8 q-tiles x (B*H), 4 waves x 32 q-rows. All-dbuf staging,
// ONE barrier/iter (lockstep blocks -> L2 reuse). Swapped QK^T with K-row
// permutation rho(fm,w) = (fm&1)*4 + (w&3) + (w>>2)*8 + (fm>>1)*32 so the
// score C-regs repack in-lane straight into PV's A-fragment k-slots.
// Q pre-scaled by cqk; xq pre-scaled by e2c at block init (VALU folding).
// 2 blocks/CU: 8 bh-groups x 384KB = 3MB per XCD L2 (fits; 3/CU thrashed).
__global__ __launch_bounds__(256, 2) void attn_kernel(
    const _Float16* __restrict__ Qh, const _Float16* __restrict__ Kh,
    const _Float16* __restrict__ Vt, const _Float16* __restrict__ Vvt,
    const _Float16* __restrict__ xk, const _Float16* __restrict__ xq,
    const float* __restrict__ log_sigma_f, const float* __restrict__ log_length,
    _Float16* __restrict__ ctx_out, _Float16* __restrict__ ctx2_out,
    float* __restrict__ var_out)
{
  const int bid = blockIdx.x;
  const int swz = (bid & 7) * 128 + (bid >> 3);
  const int qt = swz & 7;
  const int bh = swz >> 3;
  const int b  = bh >> 4, h = bh & 15;
  const int tid = threadIdx.x;
  const int lane = tid & 63, wid = tid >> 6;
  const int l15 = lane & 15, l4 = lane >> 4;
  const float L2E   = 1.44269504f;
  const float sig2l = __expf(2.f*log_sigma_f[h]) * L2E;      // sigma_f^2 * log2(e)
  const float e2c   = 0.5f*__expf(-2.f*log_length[h]) * L2E; // 1/(2 l^2) * log2(e)

  __shared__ _Float16 sK[2][4096];   // [m][d] 64x64, g-swizzled
  __shared__ _Float16 sV[2][4096];   // [d][m]
  __shared__ _Float16 sVv[2][4096];  // [d][m]

  const int t0 = b*NSEQ + qt*128;
  const int wq = wid*32;

  // permuted K-row for this lane per fm (constant across tiles)
  int krow_[4];
  #pragma unroll
  for (int fm=0; fm<4; fm++)
    krow_[fm] = ((fm&1)<<2) + (l15&3) + ((l15>>2)<<3) + ((fm>>1)<<5);

  // Q fragments (B-side: lane l15 = q-row); Q already carries cqk
  h8 qf[2][2];
  #pragma unroll
  for (int fq=0; fq<2; fq++)
    #pragma unroll
    for (int ks=0; ks<2; ks++){
      size_t off = (size_t)(t0 + wq + fq*16 + l15)*D_MODEL + h*DK + ks*32 + l4*8;
      qf[fq][ks] = *(const h8*)(Qh + off);
    }
  // RBF Q-side rows, scaled once by e2c (folds the per-score multiply)
  const _Float16 e2ch = (_Float16)e2c;
  h8 xqf[2];
  #pragma unroll
  for (int fq=0; fq<2; fq++){
    xqf[fq] = *(const h8*)(xq + (size_t)(t0 + wq + fq*16 + l15)*32 + l4*8);
    xqf[fq] = xqf[fq] * e2ch;
  }

  h8 ones;
  #pragma unroll
  for (int j=0;j<8;j++) ones[j] = (_Float16)1.f;

  float mrun[2] = {-1e30f, -1e30f};   // log2 domain
  f4 lacc[2], ctx[2][4], var[2][4];
  #pragma unroll
  for (int fq=0; fq<2; fq++){
    #pragma unroll
    for (int r=0;r<4;r++) lacc[fq][r] = 0.f;
    #pragma unroll
    for (int fd=0; fd<4; fd++)
      #pragma unroll
      for (int r=0;r<4;r++){ ctx[fq][fd][r] = 0.f; var[fq][fd][r] = 0.f; }
  }

  // staging: 1536 chunks of 16B (K 512 w/ g-swizzle, V 512, Vv 512)
  auto stage = [&](int bi, int mt){
    #pragma unroll
    for (int k=0;k<6;k++){
      int c = tid + k*256;
      if (k < 2){
        int rg = c >> 3, ch = c & 7;
        int g  = (rg & 3) | (((rg >> 3) & 1) << 2);
        int sw = ((ch ^ g) << 3);
        async_copy16(&sK[bi][c*8], Kh + (size_t)(b*NSEQ + mt + rg)*D_MODEL + h*DK + sw);
      } else if (k < 4){
        int cc = c - 512; int rg = cc >> 3, sw = (((cc & 7) ^ (rg & 7)) << 3);
        async_copy16(&sV[bi][cc*8], Vt + ((size_t)b << 20) + (size_t)(h*DK + rg)*NSEQ + mt + sw);
      } else {
        int cc = c - 1024; int rg = cc >> 3, sw = (((cc & 7) ^ (rg & 7)) << 3);
        async_copy16(&sVv[bi][cc*8], Vvt + ((size_t)b << 20) + (size_t)(h*DK + rg)*NSEQ + mt + sw);
      }
    }
  };

  // xk fragments: current tile (xkf) + next tile (xknxt), register-prefetched
  h8 xkf[4], xknxt[4];
  #pragma unroll
  for (int fm=0; fm<4; fm++)
    xkf[fm] = *(const h8*)(xk + (size_t)(b*NSEQ + krow_[fm])*32 + l4*8);

  stage(0, 0);
  __syncthreads();

  for (int it = 0; it < NSEQ/64; it++){
    const int bi = it & 1;
    const int mt = it*64;
    if (it + 1 < NSEQ/64){
      stage(bi^1, mt + 64);
      #pragma unroll
      for (int fm=0; fm<4; fm++)
        xknxt[fm] = *(const h8*)(xk + (size_t)(b*NSEQ + mt + 64 + krow_[fm])*32 + l4*8);
    }

    // scores (swapped): S'[fq][fm][r] for m-row rho(fm, l4*4+r), q = l15
    // S = qk*cqk (folded into Q) + sig2l * exp2(-dist2*e2c (folded into xq))
    f4 S[2][4];
    #pragma unroll
    for (int fm=0; fm<4; fm++){
      const int krow = krow_[fm];
      const int g    = (krow & 3) | (((krow >> 3) & 1) << 2);
      h8 kb0 = *(const h8*)&sK[bi][krow*64 + ((l4      ^ g))*8];
      h8 kb1 = *(const h8*)&sK[bi][krow*64 + (((4+l4) ^ g))*8];
      #pragma unroll
      for (int fq=0; fq<2; fq++){
        f4 s, xd;
        #pragma unroll
        for (int r=0;r<4;r++){ s[r]=0.f; xd[r]=0.f; }
        s  = mfma_h(kb0, qf[fq][0], s);
        s  = mfma_h(kb1, qf[fq][1], s);
        xd = mfma_h(xkf[fm], xqf[fq], xd);         // = -dist2*e2c
        #pragma unroll
        for (int r=0;r<4;r++)
          S[fq][fm][r] = s[r] + sig2l*exp2f(xd[r]);
      }
    }

    // softmax (log2 domain), defer-max thr = 4*log2e = 5.77
    h8 pa[2][2];
    #pragma unroll
    for (int fq=0; fq<2; fq++){
      float tm = S[fq][0][0];
      #pragma unroll
      for (int fm=0; fm<4; fm++)
        #pragma unroll
        for (int r=0;r<4;r++) tm = fmaxf(tm, S[fq][fm][r]);
      tm = fmaxf(tm, __shfl_xor(tm, 16));
      tm = fmaxf(tm, __shfl_xor(tm, 32));
      int nd = tm > mrun[fq] + 5.7708f;
      if (__any(nd)){
        float mn = fmaxf(mrun[fq], tm);
        float sc = exp2f(mrun[fq] - mn);          // per q = l15
        mrun[fq] = mn;
        float scr[4];
        #pragma unroll
        for (int r=0;r<4;r++) scr[r] = __shfl(sc, (l4<<2) + r);  // q = l4*4+r
        #pragma unroll
        for (int r=0;r<4;r++) lacc[fq][r] *= scr[r];
        #pragma unroll
        for (int fd=0; fd<4; fd++)
          #pragma unroll
          for (int r=0;r<4;r++){
            ctx[fq][fd][r] *= scr[r];
            var[fq][fd][r] *= scr[r]*scr[r];
          }
      }
      // P = exp2(S' - m'); in-lane repack: slot(ks=fm>>1, j=(fm&1)*4+r) -> m = ks*32+l4*8+j
      #pragma unroll
      for (int fm=0; fm<4; fm++)
        #pragma unroll
        for (int r=0;r<4;r++)
          pa[fq][fm>>1][((fm&1)<<2) + r] = (_Float16)exp2f(S[fq][fm][r] - mrun[fq]);
    }

    // PV: ctx += P@V, var += P^2@Vv, l += P@1
    #pragma unroll
    for (int ks=0; ks<2; ks++){
      h8 pa2[2];
      #pragma unroll
      for (int fq=0; fq<2; fq++){
        pa2[fq] = pa[fq][ks]*pa[fq][ks];
        lacc[fq] = mfma_h(pa[fq][ks], ones, lacc[fq]);
      }
      #pragma unroll
      for (int fd=0; fd<4; fd++){
        int drow = fd*16 + l15;
        int ck = (ks*4 + l4) ^ (drow & 7);
        h8 vb  = *(const h8*)&sV[bi][drow*64 + ck*8];
        h8 vvb = *(const h8*)&sVv[bi][drow*64 + ck*8];
        #pragma unroll
        for (int fq=0; fq<2; fq++){
          ctx[fq][fd] = mfma_h(pa[fq][ks], vb,  ctx[fq][fd]);
          var[fq][fd] = mfma_h(pa2[fq],    vvb, var[fq][fd]);
        }
      }
    }
    __syncthreads();
    #pragma unroll
    for (int fm=0; fm<4; fm++) xkf[fm] = xknxt[fm];
  }

  // epilogue: normalize; write ctx/ctx^2 f16 + var f32 (line-grouped)
  #pragma unroll
  for (int fq=0; fq<2; fq++)
    #pragma unroll
    for (int r=0;r<4;r++){
      int t = t0 + wq + fq*16 + l4*4 + r;
      float linv = 1.f / lacc[fq][r];
      size_t base = (size_t)t*D_MODEL + h*DK + l15;
      float c[4];
      #pragma unroll
      for (int fd=0; fd<4; fd++) c[fd] = ctx[fq][fd][r] * linv;
      #pragma unroll
      for (int fd=0; fd<4; fd++) ctx_out[base + fd*16]  = (_Float16)c[fd];
      #pragma unroll
      for (int fd=0; fd<4; fd++) ctx2_out[base + fd*16] = (_Float16)(c[fd]*c[fd]);
      #pragma unroll
      for (int fd=0; fd<4; fd++) var_out[base + fd*16]  = var[fq][fd][r] * linv * linv;
    }
}

// ---------------- host launch ----------------

extern "C" void kernel_launch(void* const* d_in, const int* in_sizes, int n_in,
                              void* d_out, int out_size, void* d_ws, size_t ws_size,
                              hipStream_t stream){
  (void)in_sizes; (void)n_in; (void)out_size; (void)ws_size;
  const float* H      = (const float*)d_in[0];
  const float* x_raw  = (const float*)d_in[1];
  const float* Wq_mu  = (const float*)d_in[2];
  const float* bq_mu  = (const float*)d_in[4];
  const float* Wk_mu  = (const float*)d_in[6];
  const float* bk_mu  = (const float*)d_in[8];
  const float* Wv_mu  = (const float*)d_in[10];
  const float* Wv_rho = (const float*)d_in[11];
  const float* bv_mu  = (const float*)d_in[12];
  const float* bv_rho = (const float*)d_in[13];
  const float* Wo_mu  = (const float*)d_in[14];
  const float* Wo_rho = (const float*)d_in[15];
  const float* bo_mu  = (const float*)d_in[16];
  const float* bo_rho = (const float*)d_in[17];
  const float* lsf    = (const float*)d_in[18];
  const float* lln    = (const float*)d_in[19];

  char* ws = (char*)d_ws;
  const size_t MB = 1024*1024;
  _Float16* Hh    = (_Float16*)(ws + 0*MB);     // 16MB
  _Float16* H2h   = (_Float16*)(ws + 16*MB);    // 16MB
  _Float16* Wcat  = (_Float16*)(ws + 32*MB);    // 8MB: [Wq|Wk|Wv|Wvs2] rows
  _Float16* Wocat = (_Float16*)(ws + 40*MB);    // 4MB: [Wo|Wos2] rows
  _Float16* Qh    = (_Float16*)(ws + 46*MB);    // 16MB
  _Float16* Kh    = (_Float16*)(ws + 62*MB);    // 16MB
  _Float16* Vt    = (_Float16*)(ws + 78*MB);    // 16MB, transposed [b][o][n]
  _Float16* Vvt   = (_Float16*)(ws + 94*MB);    // 16MB
  _Float16* ctxh  = (_Float16*)(ws + 110*MB);   // 16MB
  _Float16* ctx2h = (_Float16*)(ws + 126*MB);   // 16MB
  _Float16* xk    = (_Float16*)(ws + 142*MB);   // 512KB
  _Float16* xqb   = (_Float16*)(ws + 142*MB + 512*1024);  // 512KB

  float* out_mean = (float*)d_out;
  float* out_var  = out_mean + (size_t)TOK*D_MODEL;

  // prep (single launch: 6144 W-blocks + 8192 H-blocks + 32 x-blocks)
  prep_all<<<14368, 256, 0, stream>>>(Wq_mu, Wk_mu, Wv_mu, Wv_rho, Wo_mu, Wo_rho,
      H, x_raw, Wcat, Wocat, Hh, H2h, xk, xqb);

  // fused projections: Q | K | V | Vv in one launch (grid 64 x 32)
  gemm_fused<0><<<2048, 256, 0, stream>>>(Hh, H2h, Wcat,
      bq_mu, bk_mu, bv_mu, bv_rho,
      Qh, Kh, Vt, Vvt, nullptr, nullptr);

  // attention (writes ctxh/ctx2h f16 and var_attn into out_var)
  attn_kernel<<<1024, 256, 0, stream>>>(Qh, Kh, Vt, Vvt, xk, xqb, lsf, lln,
      ctxh, ctx2h, out_var);

  // fused output projections: out_mean | out_var (grid 64 x 16)
  gemm_fused<1><<<1024, 256, 0, stream>>>(ctxh, ctx2h, Wocat,
      bo_mu, bo_rho, nullptr, nullptr,
      nullptr, nullptr, nullptr, nullptr, out_mean, out_var);
}

// Round 12
// 273.401 us; speedup vs baseline: 1.7410x; 1.1130x over previous
//
#include <hip/hip_runtime.h>
#include <hip/hip_bf16.h>
#include <stdint.h>

// Bayesian MHA forward for MI355X (round 12 = r11 + compile fix).
//  - exp2f -> __builtin_amdgcn_exp2f (raw v_exp_f32; OCML exp2f carries
//    range/denorm fixup VALU ops -- 64 exps/iter made it the VALU hotspot)
//  - P repack via __builtin_amdgcn_cvt_pkrtz (bit_cast from __fp16x2)
//  - ctx2h eliminated: out-projection seg1 squares ctxh fragments in-register

#define D_MODEL 1024
#define NSEQ    1024
#define BATCH   8
#define NHEADS  16
#define DK      64
#define TOK     8192   // BATCH*NSEQ

typedef _Float16  h8  __attribute__((ext_vector_type(8)));
typedef _Float16  h4  __attribute__((ext_vector_type(4)));
typedef _Float16  h2v __attribute__((ext_vector_type(2)));
typedef __fp16    g2  __attribute__((ext_vector_type(2)));
typedef float     f4  __attribute__((ext_vector_type(4)));

__device__ __forceinline__ f4 mfma_h(h8 a, h8 b, f4 c){
  return __builtin_amdgcn_mfma_f32_16x16x32_f16(a, b, c, 0, 0, 0);
}

__device__ __forceinline__ h2v pk_f16(float a, float b){
  g2 t = __builtin_amdgcn_cvt_pkrtz(a, b);
  return __builtin_bit_cast(h2v, t);
}

// global -> LDS async copy, 16B per lane. LDS dest must be (uniform base + lane*16).
__device__ __forceinline__ void async_copy16(void* lds, const void* g){
  __builtin_amdgcn_global_load_lds(
      (const __attribute__((address_space(1))) unsigned int*)(uintptr_t)g,
      (__attribute__((address_space(3))) unsigned int*)(unsigned int)(uintptr_t)lds,
      16, 0, 0);
}

__device__ __forceinline__ float softplusf(float x){
  return (x > 20.f) ? x : log1pf(__expf(x));
}

// ---------------- prep (single launch) ----------------
// bids [0,6144): weights -> 6 segments of 1M: f16(Wq|Wk|Wv|sp2(Wvr)) -> Wcat,
//                f16(Wo|sp2(Wor)) -> Wocat
// bids [6144,14336): Hh = f16(H), H2h = f16(H*H)
// bids [14336,14368): xk/xq padded RBF rows (256 tokens/block)
//   xk[t][32] = [x(16), x2hi, x2lo, 1, 1, 0(12)]
//   xq[t][32] = [2x(16), -1, -1, -x2hi, -x2lo, 0(12)]
//   => dot(xk[m], xq[q]) = -dist2(m,q)
__global__ __launch_bounds__(256) void prep_all(
    const float* __restrict__ Wq, const float* __restrict__ Wk,
    const float* __restrict__ Wv, const float* __restrict__ Wvr,
    const float* __restrict__ Wo, const float* __restrict__ Wor,
    const float* __restrict__ H, const float* __restrict__ x,
    _Float16* __restrict__ Wcat, _Float16* __restrict__ Wocat,
    _Float16* __restrict__ Hh, _Float16* __restrict__ H2h,
    _Float16* __restrict__ xk, _Float16* __restrict__ xq)
{
  const int bid = blockIdx.x;
  if (bid < 6144){
    const int seg = bid >> 10;
    const int i   = ((bid & 1023)*256 + threadIdx.x)*4;
    const float* src = seg==0 ? Wq : seg==1 ? Wk : seg==2 ? Wv : seg==3 ? Wvr : seg==4 ? Wo : Wor;
    _Float16* dst = (seg < 4) ? (Wcat + (size_t)seg*1048576)
                              : (Wocat + (size_t)(seg-4)*1048576);
    const bool sp2 = (seg==3) || (seg==5);
    float4 v = *(const float4*)(src + i);
    float vv[4] = {v.x, v.y, v.z, v.w};
    #pragma unroll
    for (int j=0;j<4;j++){
      float f = vv[j];
      if (sp2){ float s = softplusf(f); f = s*s; }
      dst[i+j] = (_Float16)f;
    }
  } else if (bid < 14336){
    int i = ((bid - 6144)*256 + threadIdx.x)*4;
    float4 v = *(const float4*)(H + i);
    float vv[4] = {v.x, v.y, v.z, v.w};
    #pragma unroll
    for (int j=0;j<4;j++){
      Hh[i+j]  = (_Float16)vv[j];
      H2h[i+j] = (_Float16)(vv[j]*vv[j]);
    }
  } else {
    int t = (bid - 14336)*256 + threadIdx.x;
    const float* p = x + (size_t)t*16;
    _Float16 a[32], bb[32];
    float s = 0.f;
    #pragma unroll
    for (int j=0;j<16;j++){
      float f = p[j];
      a[j]  = (_Float16)f;
      bb[j] = (_Float16)(2.f*f);
      s += f*f;
    }
    _Float16 shi = (_Float16)s;
    _Float16 slo = (_Float16)(s - (float)shi);
    a[16]=shi; a[17]=slo; a[18]=(_Float16)1.f; a[19]=(_Float16)1.f;
    bb[16]=(_Float16)-1.f; bb[17]=(_Float16)-1.f; bb[18]=-shi; bb[19]=-slo;
    #pragma unroll
    for (int j=20;j<32;j++){ a[j]=(_Float16)0.f; bb[j]=(_Float16)0.f; }
    #pragma unroll
    for (int j=0;j<4;j++){
      *(h8*)(xk + (size_t)t*32 + j*8) = *(const h8*)&a[j*8];
      *(h8*)(xq + (size_t)t*32 + j*8) = *(const h8*)&bb[j*8];
    }
  }
}

// ---------------- fused GEMM: C = A @ Wcat^T (+bias) ----------------
// MODE 0: projections. 4 segments of 1024 cols: Q, K, V, Vv.
//   A = Hh (segs 0-2) or H2h (seg 3). Q (scaled by cqk) / K stored
//   [row][col] f16; V/Vv transposed to [b][col][row&1023] via LDS transpose.
// MODE 1: outputs. 2 segments: out_mean (f32), out_var (f32, += addend).
//   A = ctxh for BOTH segs; seg1 squares A fragments in-register.
// 128x128 tile, BK=32, 4 waves (2x2). XOR-swizzled LDS chunks. XCD-grouped swizzle.
template<int MODE>
__global__ __launch_bounds__(256) void gemm_fused(
    const _Float16* __restrict__ A0, const _Float16* __restrict__ A1,
    const _Float16* __restrict__ Wcat,
    const float* __restrict__ bias0, const float* __restrict__ bias1,
    const float* __restrict__ bias2, const float* __restrict__ bias3,
    _Float16* __restrict__ Qo, _Float16* __restrict__ Ko,
    _Float16* __restrict__ Vto, _Float16* __restrict__ Vvto,
    float* __restrict__ meanO, float* __restrict__ varO)
{
  constexpr int NBN = (MODE==0) ? 32 : 16;     // n-tiles (4096 or 2048 cols)
  __shared__ _Float16 smem[8192];              // sA | sB; reused as transpose buf
  _Float16* sA = smem;
  _Float16* sB = smem + 4096;
  const int tid = threadIdx.x;
  const int lane = tid & 63;
  const int wid  = tid >> 6;
  const int wm = wid >> 1, wn = wid & 1;
  const int l15 = lane & 15, l4 = lane >> 4;
  // XCD-grouped bijective swizzle: XCD x owns bm in [8x,8x+8); within the
  // XCD, 8bm x 8bn groups keep A(2MB)+B(2MB) ~ L2-resident.
  const int bid = blockIdx.x;
  const int x   = bid & 7;
  const int idx = bid >> 3;
  const int grp = idx >> 6;                    // 0..(NBN/8-1)
  const int inr = idx & 63;
  const int bm  = (x << 3) + (inr & 7);
  const int bn  = (grp << 3) + (inr >> 3);
  const int row0 = bm << 7, col0 = bn << 7;
  const int seg = col0 >> 10;

  const _Float16* A = (MODE==0) ? (seg < 3 ? A0 : A1) : A0;
  const bool sqA = (MODE==1) && (seg==1);
  const _Float16* B = Wcat + (size_t)col0 * 1024;

  f4 acc[4][4];
  #pragma unroll
  for (int i=0;i<4;i++)
    #pragma unroll
    for (int j=0;j<4;j++)
      #pragma unroll
      for (int r=0;r<4;r++) acc[i][j][r] = 0.f;

  const int c0 = tid, c1 = tid + 256;
  const int r0 = c0 >> 2, ch0 = c0 & 3;
  const int r1 = c1 >> 2, ch1 = c1 & 3;
  const int k0off = ((ch0 ^ (r0 & 3)) << 3);
  const int k1off = ((ch1 ^ (r1 & 3)) << 3);

  for (int kt = 0; kt < 1024; kt += 32){
    __syncthreads();
    async_copy16(&sA[c0*8], A + (size_t)(row0+r0)*1024 + kt + k0off);
    async_copy16(&sA[c1*8], A + (size_t)(row0+r1)*1024 + kt + k1off);
    async_copy16(&sB[c0*8], B + (size_t)r0*1024 + kt + k0off);
    async_copy16(&sB[c1*8], B + (size_t)r1*1024 + kt + k1off);
    __syncthreads();

    h8 a[4], b[4];
    #pragma unroll
    for (int mf=0; mf<4; mf++){
      int r  = (wm<<6) + (mf<<4) + l15;
      int ck = l4 ^ (r & 3);
      a[mf] = *(const h8*)&sA[r*32 + ck*8];
      if (sqA) a[mf] = a[mf]*a[mf];
    }
    #pragma unroll
    for (int nf=0; nf<4; nf++){
      int r  = (wn<<6) + (nf<<4) + l15;
      int ck = l4 ^ (r & 3);
      b[nf] = *(const h8*)&sB[r*32 + ck*8];
    }
    #pragma unroll
    for (int mf=0; mf<4; mf++)
      #pragma unroll
      for (int nf=0; nf<4; nf++)
        acc[mf][nf] = mfma_h(a[mf], b[nf], acc[mf][nf]);
  }

  if (MODE==0 && seg >= 2){
    // --- V/Vv: transpose through LDS (XOR-swizzled), coalesced 16B stores ---
    _Float16* T = (seg==2) ? Vto : Vvto;
    const size_t tbase = ((size_t)(row0>>10)<<20)
                       + (size_t)(col0 & 1023)*1024 + (row0 & 1023);
    const int o  = tid >> 1;        // output row (= C col), 0..127
    const int hf = tid & 1;
    #pragma unroll
    for (int rh=0; rh<2; rh++){     // half-passes over C rows [rh*64, rh*64+64)
      __syncthreads();              // protect smem vs K-loop / prev pass reads
      if (wm == rh){
        #pragma unroll
        for (int nf=0; nf<4; nf++){
          int col = (wn<<6) + (nf<<4) + l15;          // 0..127
          float bb2 = (seg==2) ? bias2[(col0 + col) & 1023]
                               : bias3[(col0 + col) & 1023];
          float bv;
          if (seg==3){ float s = softplusf(bb2); bv = s*s; } else bv = bb2;
          #pragma unroll
          for (int mf=0; mf<4; mf++){
            int n   = (mf<<4) + (l4<<2);              // row-in-half, 4-aligned
            int nsw = n ^ ((col & 7) << 3);
            h4 hv;
            #pragma unroll
            for (int r=0;r<4;r++) hv[r] = (_Float16)(acc[mf][nf][r] + bv);
            *(h4*)&smem[col*64 + nsw] = hv;
          }
        }
      }
      __syncthreads();
      #pragma unroll
      for (int j=0; j<4; j++){
        int n   = hf*8 + j*16;                        // 8-aligned
        int nsw = n ^ ((o & 7) << 3);
        h8 v = *(const h8*)&smem[o*64 + nsw];
        *(h8*)(T + tbase + (size_t)o*1024 + rh*64 + n) = v;
      }
    }
    return;
  }

  // --- direct epilogues (Q/K f16 rows; MODE1 f32 outputs) ---
  const float* bias = (seg==0) ? bias0 : bias1;
  const bool sp2 = (MODE==1) && (seg==1);
  const float CQK = 0.18033688f;   // 0.125 * log2(e), folded into Q

  #pragma unroll
  for (int nf=0; nf<4; nf++){
    int colg = col0 + (wn<<6) + (nf<<4) + l15;
    int colm = colg & 1023;
    float bb = bias[colm];
    float bv = sp2 ? ({ float s = softplusf(bb); s*s; }) : bb;
    #pragma unroll
    for (int mf=0; mf<4; mf++){
      int rbase = row0 + (wm<<6) + (mf<<4) + (l4<<2);
      #pragma unroll
      for (int r=0;r<4;r++){
        int row = rbase + r;
        float v = acc[mf][nf][r] + bv;
        if (MODE==0){
          if (seg==0) Qo[(size_t)row*1024 + colm] = (_Float16)(v * CQK);
          else        Ko[(size_t)row*1024 + colm] = (_Float16)v;
        } else {
          size_t idxo = (size_t)row*1024 + colm;
          if (seg==0) meanO[idxo] = v;
          else        varO[idxo] = v + varO[idxo];
        }
      }
    }
  }
}

// ---------------- fused attention (flash-style, + RBF scores) ----------------
// 1024 blocks = 8 q-tiles x (B*H), 4 waves x 32 q-rows. All-dbuf staging,
// ONE barrier/iter (lockstep blocks -> L2 reuse). Swapped QK^T with K-row
// permutation rho(fm,w) = (fm&1)*4 + (w&3) + (w>>2)*8 + (fm>>1)*32 so the
// score C-regs repack in-lane straight into PV's A-fragment k-slots.
// Q pre-scaled by cqk; xq pre-scaled by e2c. Raw v_exp_f32 + cvt_pkrtz.
// 2 blocks/CU: 8 bh-groups x 384KB = 3MB per XCD L2 (fits; 3/CU thrashed).
__global__ __launch_bounds__(256, 2) void attn_kernel(
    const _Float16* __restrict__ Qh, const _Float16* __restrict__ Kh,
    const _Float16* __restrict__ Vt, const _Float16* __restrict__ Vvt,
    const _Float16* __restrict__ xk, const _Float16* __restrict__ xq,
    const float* __restrict__ log_sigma_f, const float* __restrict__ log_length,
    _Float16* __restrict__ ctx_out, float* __restrict__ var_out)
{
  const int bid = blockIdx.x;
  const int swz = (bid & 7) * 128 + (bid >> 3);
  const int qt = swz & 7;
  const int bh = swz >> 3;
  const int b  = bh >> 4, h = bh & 15;
  const int tid = threadIdx.x;
  const int lane = tid & 63, wid = tid >> 6;
  const int l15 = lane & 15, l4 = lane >> 4;
  const float L2E   = 1.44269504f;
  const float sig2l = __expf(2.f*log_sigma_f[h]) * L2E;      // sigma_f^2 * log2(e)
  const float e2c   = 0.5f*__expf(-2.f*log_length[h]) * L2E; // 1/(2 l^2) * log2(e)

  __shared__ _Float16 sK[2][4096];   // [m][d] 64x64, g-swizzled
  __shared__ _Float16 sV[2][4096];   // [d][m]
  __shared__ _Float16 sVv[2][4096];  // [d][m]

  const int t0 = b*NSEQ + qt*128;
  const int wq = wid*32;

  // permuted K-row for this lane per fm (constant across tiles)
  int krow_[4];
  #pragma unroll
  for (int fm=0; fm<4; fm++)
    krow_[fm] = ((fm&1)<<2) + (l15&3) + ((l15>>2)<<3) + ((fm>>1)<<5);

  // Q fragments (B-side: lane l15 = q-row); Q already carries cqk
  h8 qf[2][2];
  #pragma unroll
  for (int fq=0; fq<2; fq++)
    #pragma unroll
    for (int ks=0; ks<2; ks++){
      size_t off = (size_t)(t0 + wq + fq*16 + l15)*D_MODEL + h*DK + ks*32 + l4*8;
      qf[fq][ks] = *(const h8*)(Qh + off);
    }
  // RBF Q-side rows, scaled once by e2c (folds the per-score multiply)
  const _Float16 e2ch = (_Float16)e2c;
  h8 xqf[2];
  #pragma unroll
  for (int fq=0; fq<2; fq++){
    xqf[fq] = *(const h8*)(xq + (size_t)(t0 + wq + fq*16 + l15)*32 + l4*8);
    xqf[fq] = xqf[fq] * e2ch;
  }

  h8 ones;
  #pragma unroll
  for (int j=0;j<8;j++) ones[j] = (_Float16)1.f;

  float mrun[2] = {-1e30f, -1e30f};   // log2 domain
  f4 lacc[2], ctx[2][4], var[2][4];
  #pragma unroll
  for (int fq=0; fq<2; fq++){
    #pragma unroll
    for (int r=0;r<4;r++) lacc[fq][r] = 0.f;
    #pragma unroll
    for (int fd=0; fd<4; fd++)
      #pragma unroll
      for (int r=0;r<4;r++){ ctx[fq][fd][r] = 0.f; var[fq][fd][r] = 0.f; }
  }

  // staging: 1536 chunks of 16B (K 512 w/ g-swizzle, V 512, Vv 512)
  auto stage = [&](int bi, int mt){
    #pragma unroll
    for (int k=0;k<6;k++){
      int c = tid + k*256;
      if (k < 2){
        int rg = c >> 3, ch = c & 7;
        int g  = (rg & 3) | (((rg >> 3) & 1) << 2);
        int sw = ((ch ^ g) << 3);
        async_copy16(&sK[bi][c*8], Kh + (size_t)(b*NSEQ + mt + rg)*D_MODEL + h*DK + sw);
      } else if (k < 4){
        int cc = c - 512; int rg = cc >> 3, sw = (((cc & 7) ^ (rg & 7)) << 3);
        async_copy16(&sV[bi][cc*8], Vt + ((size_t)b << 20) + (size_t)(h*DK + rg)*NSEQ + mt + sw);
      } else {
        int cc = c - 1024; int rg = cc >> 3, sw = (((cc & 7) ^ (rg & 7)) << 3);
        async_copy16(&sVv[bi][cc*8], Vvt + ((size_t)b << 20) + (size_t)(h*DK + rg)*NSEQ + mt + sw);
      }
    }
  };

  // xk fragments: current tile (xkf) + next tile (xknxt), register-prefetched
  h8 xkf[4], xknxt[4];
  #pragma unroll
  for (int fm=0; fm<4; fm++)
    xkf[fm] = *(const h8*)(xk + (size_t)(b*NSEQ + krow_[fm])*32 + l4*8);

  stage(0, 0);
  __syncthreads();

  for (int it = 0; it < NSEQ/64; it++){
    const int bi = it & 1;
    const int mt = it*64;
    if (it + 1 < NSEQ/64){
      stage(bi^1, mt + 64);
      #pragma unroll
      for (int fm=0; fm<4; fm++)
        xknxt[fm] = *(const h8*)(xk + (size_t)(b*NSEQ + mt + 64 + krow_[fm])*32 + l4*8);
    }

    // scores (swapped): S'[fq][fm][r] for m-row rho(fm, l4*4+r), q = l15
    // S = qk*cqk (folded into Q) + sig2l * exp2(-dist2*e2c (folded into xq))
    f4 S[2][4];
    #pragma unroll
    for (int fm=0; fm<4; fm++){
      const int krow = krow_[fm];
      const int g    = (krow & 3) | (((krow >> 3) & 1) << 2);
      h8 kb0 = *(const h8*)&sK[bi][krow*64 + ((l4      ^ g))*8];
      h8 kb1 = *(const h8*)&sK[bi][krow*64 + (((4+l4) ^ g))*8];
      #pragma unroll
      for (int fq=0; fq<2; fq++){
        f4 s, xd;
        #pragma unroll
        for (int r=0;r<4;r++){ s[r]=0.f; xd[r]=0.f; }
        s  = mfma_h(kb0, qf[fq][0], s);
        s  = mfma_h(kb1, qf[fq][1], s);
        xd = mfma_h(xkf[fm], xqf[fq], xd);         // = -dist2*e2c
        #pragma unroll
        for (int r=0;r<4;r++)
          S[fq][fm][r] = s[r] + sig2l*__builtin_amdgcn_exp2f(xd[r]);
      }
    }

    // softmax (log2 domain), defer-max thr = 4*log2e = 5.77
    h8 pa[2][2];
    #pragma unroll
    for (int fq=0; fq<2; fq++){
      float tm = S[fq][0][0];
      #pragma unroll
      for (int fm=0; fm<4; fm++)
        #pragma unroll
        for (int r=0;r<4;r++) tm = fmaxf(tm, S[fq][fm][r]);
      tm = fmaxf(tm, __shfl_xor(tm, 16));
      tm = fmaxf(tm, __shfl_xor(tm, 32));
      int nd = tm > mrun[fq] + 5.7708f;
      if (__any(nd)){
        float mn = fmaxf(mrun[fq], tm);
        float sc = __builtin_amdgcn_exp2f(mrun[fq] - mn);   // per q = l15
        mrun[fq] = mn;
        float scr[4];
        #pragma unroll
        for (int r=0;r<4;r++) scr[r] = __shfl(sc, (l4<<2) + r);  // q = l4*4+r
        #pragma unroll
        for (int r=0;r<4;r++) lacc[fq][r] *= scr[r];
        #pragma unroll
        for (int fd=0; fd<4; fd++)
          #pragma unroll
          for (int r=0;r<4;r++){
            ctx[fq][fd][r] *= scr[r];
            var[fq][fd][r] *= scr[r]*scr[r];
          }
      }
      // P = exp2(S' - m'); in-lane repack: slot(ks=fm>>1, j=(fm&1)*4+r)
      // -> m = ks*32+l4*8+j.  cvt_pkrtz packs pairs straight into the h8.
      #pragma unroll
      for (int ks=0; ks<2; ks++){
        h2v q0 = pk_f16(__builtin_amdgcn_exp2f(S[fq][2*ks][0] - mrun[fq]),
                        __builtin_amdgcn_exp2f(S[fq][2*ks][1] - mrun[fq]));
        h2v q1 = pk_f16(__builtin_amdgcn_exp2f(S[fq][2*ks][2] - mrun[fq]),
                        __builtin_amdgcn_exp2f(S[fq][2*ks][3] - mrun[fq]));
        h2v q2 = pk_f16(__builtin_amdgcn_exp2f(S[fq][2*ks+1][0] - mrun[fq]),
                        __builtin_amdgcn_exp2f(S[fq][2*ks+1][1] - mrun[fq]));
        h2v q3 = pk_f16(__builtin_amdgcn_exp2f(S[fq][2*ks+1][2] - mrun[fq]),
                        __builtin_amdgcn_exp2f(S[fq][2*ks+1][3] - mrun[fq]));
        pa[fq][ks] = (h8){q0[0],q0[1],q1[0],q1[1],q2[0],q2[1],q3[0],q3[1]};
      }
    }

    // PV: ctx += P@V, var += P^2@Vv, l += P@1
    #pragma unroll
    for (int ks=0; ks<2; ks++){
      h8 pa2[2];
      #pragma unroll
      for (int fq=0; fq<2; fq++){
        pa2[fq] = pa[fq][ks]*pa[fq][ks];
        lacc[fq] = mfma_h(pa[fq][ks], ones, lacc[fq]);
      }
      #pragma unroll
      for (int fd=0; fd<4; fd++){
        int drow = fd*16 + l15;
        int ck = (ks*4 + l4) ^ (drow & 7);
        h8 vb  = *(const h8*)&sV[bi][drow*64 + ck*8];
        h8 vvb = *(const h8*)&sVv[bi][drow*64 + ck*8];
        #pragma unroll
        for (int fq=0; fq<2; fq++){
          ctx[fq][fd] = mfma_h(pa[fq][ks], vb,  ctx[fq][fd]);
          var[fq][fd] = mfma_h(pa2[fq],    vvb, var[fq][fd]);
        }
      }
    }
    __syncthreads();
    #pragma unroll
    for (int fm=0; fm<4; fm++) xkf[fm] = xknxt[fm];
  }

  // epilogue: normalize; write ctx f16 + var f32 (line-grouped)
  #pragma unroll
  for (int fq=0; fq<2; fq++)
    #pragma unroll
    for (int r=0;r<4;r++){
      int t = t0 + wq + fq*16 + l4*4 + r;
      float linv = 1.f / lacc[fq][r];
      size_t base = (size_t)t*D_MODEL + h*DK + l15;
      float c[4];
      #pragma unroll
      for (int fd=0; fd<4; fd++) c[fd] = ctx[fq][fd][r] * linv;
      #pragma unroll
      for (int fd=0; fd<4; fd++) ctx_out[base + fd*16] = (_Float16)c[fd];
      #pragma unroll
      for (int fd=0; fd<4; fd++) var_out[base + fd*16] = var[fq][fd][r] * linv * linv;
    }
}

// ---------------- host launch ----------------

extern "C" void kernel_launch(void* const* d_in, const int* in_sizes, int n_in,
                              void* d_out, int out_size, void* d_ws, size_t ws_size,
                              hipStream_t stream){
  (void)in_sizes; (void)n_in; (void)out_size; (void)ws_size;
  const float* H      = (const float*)d_in[0];
  const float* x_raw  = (const float*)d_in[1];
  const float* Wq_mu  = (const float*)d_in[2];
  const float* bq_mu  = (const float*)d_in[4];
  const float* Wk_mu  = (const float*)d_in[6];
  const float* bk_mu  = (const float*)d_in[8];
  const float* Wv_mu  = (const float*)d_in[10];
  const float* Wv_rho = (const float*)d_in[11];
  const float* bv_mu  = (const float*)d_in[12];
  const float* bv_rho = (const float*)d_in[13];
  const float* Wo_mu  = (const float*)d_in[14];
  const float* Wo_rho = (const float*)d_in[15];
  const float* bo_mu  = (const float*)d_in[16];
  const float* bo_rho = (const float*)d_in[17];
  const float* lsf    = (const float*)d_in[18];
  const float* lln    = (const float*)d_in[19];

  char* ws = (char*)d_ws;
  const size_t MB = 1024*1024;
  _Float16* Hh    = (_Float16*)(ws + 0*MB);     // 16MB
  _Float16* H2h   = (_Float16*)(ws + 16*MB);    // 16MB
  _Float16* Wcat  = (_Float16*)(ws + 32*MB);    // 8MB: [Wq|Wk|Wv|Wvs2] rows
  _Float16* Wocat = (_Float16*)(ws + 40*MB);    // 4MB: [Wo|Wos2] rows
  _Float16* Qh    = (_Float16*)(ws + 46*MB);    // 16MB
  _Float16* Kh    = (_Float16*)(ws + 62*MB);    // 16MB
  _Float16* Vt    = (_Float16*)(ws + 78*MB);    // 16MB, transposed [b][o][n]
  _Float16* Vvt   = (_Float16*)(ws + 94*MB);    // 16MB
  _Float16* ctxh  = (_Float16*)(ws + 110*MB);   // 16MB
  _Float16* xk    = (_Float16*)(ws + 142*MB);   // 512KB
  _Float16* xqb   = (_Float16*)(ws + 142*MB + 512*1024);  // 512KB

  float* out_mean = (float*)d_out;
  float* out_var  = out_mean + (size_t)TOK*D_MODEL;

  // prep (single launch: 6144 W-blocks + 8192 H-blocks + 32 x-blocks)
  prep_all<<<14368, 256, 0, stream>>>(Wq_mu, Wk_mu, Wv_mu, Wv_rho, Wo_mu, Wo_rho,
      H, x_raw, Wcat, Wocat, Hh, H2h, xk, xqb);

  // fused projections: Q | K | V | Vv in one launch (grid 64 x 32)
  gemm_fused<0><<<2048, 256, 0, stream>>>(Hh, H2h, Wcat,
      bq_mu, bk_mu, bv_mu, bv_rho,
      Qh, Kh, Vt, Vvt, nullptr, nullptr);

  // attention (writes ctxh f16 and var_attn into out_var)
  attn_kernel<<<1024, 256, 0, stream>>>(Qh, Kh, Vt, Vvt, xk, xqb, lsf, lln,
      ctxh, out_var);

  // fused output projections: out_mean | out_var (grid 64 x 16)
  // seg1 squares ctxh fragments in-register (ctx2 buffer eliminated)
  gemm_fused<1><<<1024, 256, 0, stream>>>(ctxh, nullptr, Wocat,
      bo_mu, bo_rho, nullptr, nullptr,
      nullptr, nullptr, nullptr, nullptr, out_mean, out_var);
}

// Round 13
// 256.804 us; speedup vs baseline: 1.8535x; 1.0646x over previous
//
#include <hip/hip_runtime.h>
#include <hip/hip_bf16.h>
#include <stdint.h>

// Bayesian MHA forward for MI355X (round 13).
// r12 + GEMM BK 32 -> 64: halves the per-iter vmcnt(0)+barrier drains
// (the short-K bottleneck) and moves to the 64-elem-row XOR swizzle that
// attn's K-staging proves conflict-free (old 32-elem rows: 8.65M conflicts).
// Accumulation order unchanged -> bitwise-identical outputs.

#define D_MODEL 1024
#define NSEQ    1024
#define BATCH   8
#define NHEADS  16
#define DK      64
#define TOK     8192   // BATCH*NSEQ

typedef _Float16  h8  __attribute__((ext_vector_type(8)));
typedef _Float16  h4  __attribute__((ext_vector_type(4)));
typedef _Float16  h2v __attribute__((ext_vector_type(2)));
typedef __fp16    g2  __attribute__((ext_vector_type(2)));
typedef float     f4  __attribute__((ext_vector_type(4)));

__device__ __forceinline__ f4 mfma_h(h8 a, h8 b, f4 c){
  return __builtin_amdgcn_mfma_f32_16x16x32_f16(a, b, c, 0, 0, 0);
}

__device__ __forceinline__ h2v pk_f16(float a, float b){
  g2 t = __builtin_amdgcn_cvt_pkrtz(a, b);
  return __builtin_bit_cast(h2v, t);
}

// global -> LDS async copy, 16B per lane. LDS dest must be (uniform base + lane*16).
__device__ __forceinline__ void async_copy16(void* lds, const void* g){
  __builtin_amdgcn_global_load_lds(
      (const __attribute__((address_space(1))) unsigned int*)(uintptr_t)g,
      (__attribute__((address_space(3))) unsigned int*)(unsigned int)(uintptr_t)lds,
      16, 0, 0);
}

__device__ __forceinline__ float softplusf(float x){
  return (x > 20.f) ? x : log1pf(__expf(x));
}

// ---------------- prep (single launch) ----------------
// bids [0,6144): weights -> 6 segments of 1M: f16(Wq|Wk|Wv|sp2(Wvr)) -> Wcat,
//                f16(Wo|sp2(Wor)) -> Wocat
// bids [6144,14336): Hh = f16(H), H2h = f16(H*H)
// bids [14336,14368): xk/xq padded RBF rows (256 tokens/block)
//   xk[t][32] = [x(16), x2hi, x2lo, 1, 1, 0(12)]
//   xq[t][32] = [2x(16), -1, -1, -x2hi, -x2lo, 0(12)]
//   => dot(xk[m], xq[q]) = -dist2(m,q)
__global__ __launch_bounds__(256) void prep_all(
    const float* __restrict__ Wq, const float* __restrict__ Wk,
    const float* __restrict__ Wv, const float* __restrict__ Wvr,
    const float* __restrict__ Wo, const float* __restrict__ Wor,
    const float* __restrict__ H, const float* __restrict__ x,
    _Float16* __restrict__ Wcat, _Float16* __restrict__ Wocat,
    _Float16* __restrict__ Hh, _Float16* __restrict__ H2h,
    _Float16* __restrict__ xk, _Float16* __restrict__ xq)
{
  const int bid = blockIdx.x;
  if (bid < 6144){
    const int seg = bid >> 10;
    const int i   = ((bid & 1023)*256 + threadIdx.x)*4;
    const float* src = seg==0 ? Wq : seg==1 ? Wk : seg==2 ? Wv : seg==3 ? Wvr : seg==4 ? Wo : Wor;
    _Float16* dst = (seg < 4) ? (Wcat + (size_t)seg*1048576)
                              : (Wocat + (size_t)(seg-4)*1048576);
    const bool sp2 = (seg==3) || (seg==5);
    float4 v = *(const float4*)(src + i);
    float vv[4] = {v.x, v.y, v.z, v.w};
    #pragma unroll
    for (int j=0;j<4;j++){
      float f = vv[j];
      if (sp2){ float s = softplusf(f); f = s*s; }
      dst[i+j] = (_Float16)f;
    }
  } else if (bid < 14336){
    int i = ((bid - 6144)*256 + threadIdx.x)*4;
    float4 v = *(const float4*)(H + i);
    float vv[4] = {v.x, v.y, v.z, v.w};
    #pragma unroll
    for (int j=0;j<4;j++){
      Hh[i+j]  = (_Float16)vv[j];
      H2h[i+j] = (_Float16)(vv[j]*vv[j]);
    }
  } else {
    int t = (bid - 14336)*256 + threadIdx.x;
    const float* p = x + (size_t)t*16;
    _Float16 a[32], bb[32];
    float s = 0.f;
    #pragma unroll
    for (int j=0;j<16;j++){
      float f = p[j];
      a[j]  = (_Float16)f;
      bb[j] = (_Float16)(2.f*f);
      s += f*f;
    }
    _Float16 shi = (_Float16)s;
    _Float16 slo = (_Float16)(s - (float)shi);
    a[16]=shi; a[17]=slo; a[18]=(_Float16)1.f; a[19]=(_Float16)1.f;
    bb[16]=(_Float16)-1.f; bb[17]=(_Float16)-1.f; bb[18]=-shi; bb[19]=-slo;
    #pragma unroll
    for (int j=20;j<32;j++){ a[j]=(_Float16)0.f; bb[j]=(_Float16)0.f; }
    #pragma unroll
    for (int j=0;j<4;j++){
      *(h8*)(xk + (size_t)t*32 + j*8) = *(const h8*)&a[j*8];
      *(h8*)(xq + (size_t)t*32 + j*8) = *(const h8*)&bb[j*8];
    }
  }
}

// ---------------- fused GEMM: C = A @ Wcat^T (+bias) ----------------
// MODE 0: projections. 4 segments of 1024 cols: Q, K, V, Vv.
//   A = Hh (segs 0-2) or H2h (seg 3). Q (scaled by cqk) / K stored
//   [row][col] f16; V/Vv transposed to [b][col][row&1023] via LDS transpose.
// MODE 1: outputs. 2 segments: out_mean (f32), out_var (f32, += addend).
//   A = ctxh for BOTH segs; seg1 squares A fragments in-register.
// 128x128 tile, BK=64, 4 waves (2x2). 8-chunk XOR-swizzled rows (attn-proven,
// conflict-free). XCD-grouped swizzle.
template<int MODE>
__global__ __launch_bounds__(256) void gemm_fused(
    const _Float16* __restrict__ A0, const _Float16* __restrict__ A1,
    const _Float16* __restrict__ Wcat,
    const float* __restrict__ bias0, const float* __restrict__ bias1,
    const float* __restrict__ bias2, const float* __restrict__ bias3,
    _Float16* __restrict__ Qo, _Float16* __restrict__ Ko,
    _Float16* __restrict__ Vto, _Float16* __restrict__ Vvto,
    float* __restrict__ meanO, float* __restrict__ varO)
{
  constexpr int NBN = (MODE==0) ? 32 : 16;     // n-tiles (4096 or 2048 cols)
  __shared__ _Float16 smem[16384];             // sA | sB (BK=64); transpose reuses front
  _Float16* sA = smem;
  _Float16* sB = smem + 8192;
  const int tid = threadIdx.x;
  const int lane = tid & 63;
  const int wid  = tid >> 6;
  const int wm = wid >> 1, wn = wid & 1;
  const int l15 = lane & 15, l4 = lane >> 4;
  // XCD-grouped bijective swizzle: XCD x owns bm in [8x,8x+8); within the
  // XCD, 8bm x 8bn groups keep A(2MB)+B(2MB) ~ L2-resident.
  const int bid = blockIdx.x;
  const int x   = bid & 7;
  const int idx = bid >> 3;
  const int grp = idx >> 6;                    // 0..(NBN/8-1)
  const int inr = idx & 63;
  const int bm  = (x << 3) + (inr & 7);
  const int bn  = (grp << 3) + (inr >> 3);
  const int row0 = bm << 7, col0 = bn << 7;
  const int seg = col0 >> 10;

  const _Float16* A = (MODE==0) ? (seg < 3 ? A0 : A1) : A0;
  const bool sqA = (MODE==1) && (seg==1);
  const _Float16* B = Wcat + (size_t)col0 * 1024;

  f4 acc[4][4];
  #pragma unroll
  for (int i=0;i<4;i++)
    #pragma unroll
    for (int j=0;j<4;j++)
      #pragma unroll
      for (int r=0;r<4;r++) acc[i][j][r] = 0.f;

  for (int kt = 0; kt < 1024; kt += 64){
    __syncthreads();
    // stage A+B 128x64 tiles: 1024 chunks each, 8 copies/thread
    #pragma unroll
    for (int k=0;k<4;k++){
      int c  = tid + k*256;
      int rg = c >> 3, ch = c & 7;
      int sw = ((ch ^ (rg & 7)) << 3);
      async_copy16(&sA[c*8], A + (size_t)(row0+rg)*1024 + kt + sw);
      async_copy16(&sB[c*8], B + (size_t)rg*1024 + kt + sw);
    }
    __syncthreads();

    #pragma unroll
    for (int ks=0; ks<2; ks++){
      h8 a[4], b[4];
      #pragma unroll
      for (int mf=0; mf<4; mf++){
        int r  = (wm<<6) + (mf<<4) + l15;
        int ck = (ks*4 + l4) ^ (r & 7);
        a[mf] = *(const h8*)&sA[r*64 + ck*8];
        if (sqA) a[mf] = a[mf]*a[mf];
      }
      #pragma unroll
      for (int nf=0; nf<4; nf++){
        int r  = (wn<<6) + (nf<<4) + l15;
        int ck = (ks*4 + l4) ^ (r & 7);
        b[nf] = *(const h8*)&sB[r*64 + ck*8];
      }
      #pragma unroll
      for (int mf=0; mf<4; mf++)
        #pragma unroll
        for (int nf=0; nf<4; nf++)
          acc[mf][nf] = mfma_h(a[mf], b[nf], acc[mf][nf]);
    }
  }

  if (MODE==0 && seg >= 2){
    // --- V/Vv: transpose through LDS (XOR-swizzled), coalesced 16B stores ---
    _Float16* T = (seg==2) ? Vto : Vvto;
    const size_t tbase = ((size_t)(row0>>10)<<20)
                       + (size_t)(col0 & 1023)*1024 + (row0 & 1023);
    const int o  = tid >> 1;        // output row (= C col), 0..127
    const int hf = tid & 1;
    #pragma unroll
    for (int rh=0; rh<2; rh++){     // half-passes over C rows [rh*64, rh*64+64)
      __syncthreads();              // protect smem vs K-loop / prev pass reads
      if (wm == rh){
        #pragma unroll
        for (int nf=0; nf<4; nf++){
          int col = (wn<<6) + (nf<<4) + l15;          // 0..127
          float bb2 = (seg==2) ? bias2[(col0 + col) & 1023]
                               : bias3[(col0 + col) & 1023];
          float bv;
          if (seg==3){ float s = softplusf(bb2); bv = s*s; } else bv = bb2;
          #pragma unroll
          for (int mf=0; mf<4; mf++){
            int n   = (mf<<4) + (l4<<2);              // row-in-half, 4-aligned
            int nsw = n ^ ((col & 7) << 3);
            h4 hv;
            #pragma unroll
            for (int r=0;r<4;r++) hv[r] = (_Float16)(acc[mf][nf][r] + bv);
            *(h4*)&smem[col*64 + nsw] = hv;
          }
        }
      }
      __syncthreads();
      #pragma unroll
      for (int j=0; j<4; j++){
        int n   = hf*8 + j*16;                        // 8-aligned
        int nsw = n ^ ((o & 7) << 3);
        h8 v = *(const h8*)&smem[o*64 + nsw];
        *(h8*)(T + tbase + (size_t)o*1024 + rh*64 + n) = v;
      }
    }
    return;
  }

  // --- direct epilogues (Q/K f16 rows; MODE1 f32 outputs) ---
  const float* bias = (seg==0) ? bias0 : bias1;
  const bool sp2 = (MODE==1) && (seg==1);
  const float CQK = 0.18033688f;   // 0.125 * log2(e), folded into Q

  #pragma unroll
  for (int nf=0; nf<4; nf++){
    int colg = col0 + (wn<<6) + (nf<<4) + l15;
    int colm = colg & 1023;
    float bb = bias[colm];
    float bv = sp2 ? ({ float s = softplusf(bb); s*s; }) : bb;
    #pragma unroll
    for (int mf=0; mf<4; mf++){
      int rbase = row0 + (wm<<6) + (mf<<4) + (l4<<2);
      #pragma unroll
      for (int r=0;r<4;r++){
        int row = rbase + r;
        float v = acc[mf][nf][r] + bv;
        if (MODE==0){
          if (seg==0) Qo[(size_t)row*1024 + colm] = (_Float16)(v * CQK);
          else        Ko[(size_t)row*1024 + colm] = (_Float16)v;
        } else {
          size_t idxo = (size_t)row*1024 + colm;
          if (seg==0) meanO[idxo] = v;
          else        varO[idxo] = v + varO[idxo];
        }
      }
    }
  }
}

// ---------------- fused attention (flash-style, + RBF scores) ----------------
// 1024 blocks = 8 q-tiles x (B*H), 4 waves x 32 q-rows. All-dbuf staging,
// ONE barrier/iter (lockstep blocks -> L2 reuse). Swapped QK^T with K-row
// permutation rho(fm,w) = (fm&1)*4 + (w&3) + (w>>2)*8 + (fm>>1)*32 so the
// score C-regs repack in-lane straight into PV's A-fragment k-slots.
// Q pre-scaled by cqk; xq pre-scaled by e2c. Raw v_exp_f32 + cvt_pkrtz.
// 2 blocks/CU: 8 bh-groups x 384KB = 3MB per XCD L2 (fits; 3/CU thrashed).
__global__ __launch_bounds__(256, 2) void attn_kernel(
    const _Float16* __restrict__ Qh, const _Float16* __restrict__ Kh,
    const _Float16* __restrict__ Vt, const _Float16* __restrict__ Vvt,
    const _Float16* __restrict__ xk, const _Float16* __restrict__ xq,
    const float* __restrict__ log_sigma_f, const float* __restrict__ log_length,
    _Float16* __restrict__ ctx_out, float* __restrict__ var_out)
{
  const int bid = blockIdx.x;
  const int swz = (bid & 7) * 128 + (bid >> 3);
  const int qt = swz & 7;
  const int bh = swz >> 3;
  const int b  = bh >> 4, h = bh & 15;
  const int tid = threadIdx.x;
  const int lane = tid & 63, wid = tid >> 6;
  const int l15 = lane & 15, l4 = lane >> 4;
  const float L2E   = 1.44269504f;
  const float sig2l = __expf(2.f*log_sigma_f[h]) * L2E;      // sigma_f^2 * log2(e)
  const float e2c   = 0.5f*__expf(-2.f*log_length[h]) * L2E; // 1/(2 l^2) * log2(e)

  __shared__ _Float16 sK[2][4096];   // [m][d] 64x64, g-swizzled
  __shared__ _Float16 sV[2][4096];   // [d][m]
  __shared__ _Float16 sVv[2][4096];  // [d][m]

  const int t0 = b*NSEQ + qt*128;
  const int wq = wid*32;

  // permuted K-row for this lane per fm (constant across tiles)
  int krow_[4];
  #pragma unroll
  for (int fm=0; fm<4; fm++)
    krow_[fm] = ((fm&1)<<2) + (l15&3) + ((l15>>2)<<3) + ((fm>>1)<<5);

  // Q fragments (B-side: lane l15 = q-row); Q already carries cqk
  h8 qf[2][2];
  #pragma unroll
  for (int fq=0; fq<2; fq++)
    #pragma unroll
    for (int ks=0; ks<2; ks++){
      size_t off = (size_t)(t0 + wq + fq*16 + l15)*D_MODEL + h*DK + ks*32 + l4*8;
      qf[fq][ks] = *(const h8*)(Qh + off);
    }
  // RBF Q-side rows, scaled once by e2c (folds the per-score multiply)
  const _Float16 e2ch = (_Float16)e2c;
  h8 xqf[2];
  #pragma unroll
  for (int fq=0; fq<2; fq++){
    xqf[fq] = *(const h8*)(xq + (size_t)(t0 + wq + fq*16 + l15)*32 + l4*8);
    xqf[fq] = xqf[fq] * e2ch;
  }

  h8 ones;
  #pragma unroll
  for (int j=0;j<8;j++) ones[j] = (_Float16)1.f;

  float mrun[2] = {-1e30f, -1e30f};   // log2 domain
  f4 lacc[2], ctx[2][4], var[2][4];
  #pragma unroll
  for (int fq=0; fq<2; fq++){
    #pragma unroll
    for (int r=0;r<4;r++) lacc[fq][r] = 0.f;
    #pragma unroll
    for (int fd=0; fd<4; fd++)
      #pragma unroll
      for (int r=0;r<4;r++){ ctx[fq][fd][r] = 0.f; var[fq][fd][r] = 0.f; }
  }

  // staging: 1536 chunks of 16B (K 512 w/ g-swizzle, V 512, Vv 512)
  auto stage = [&](int bi, int mt){
    #pragma unroll
    for (int k=0;k<6;k++){
      int c = tid + k*256;
      if (k < 2){
        int rg = c >> 3, ch = c & 7;
        int g  = (rg & 3) | (((rg >> 3) & 1) << 2);
        int sw = ((ch ^ g) << 3);
        async_copy16(&sK[bi][c*8], Kh + (size_t)(b*NSEQ + mt + rg)*D_MODEL + h*DK + sw);
      } else if (k < 4){
        int cc = c - 512; int rg = cc >> 3, sw = (((cc & 7) ^ (rg & 7)) << 3);
        async_copy16(&sV[bi][cc*8], Vt + ((size_t)b << 20) + (size_t)(h*DK + rg)*NSEQ + mt + sw);
      } else {
        int cc = c - 1024; int rg = cc >> 3, sw = (((cc & 7) ^ (rg & 7)) << 3);
        async_copy16(&sVv[bi][cc*8], Vvt + ((size_t)b << 20) + (size_t)(h*DK + rg)*NSEQ + mt + sw);
      }
    }
  };

  // xk fragments: current tile (xkf) + next tile (xknxt), register-prefetched
  h8 xkf[4], xknxt[4];
  #pragma unroll
  for (int fm=0; fm<4; fm++)
    xkf[fm] = *(const h8*)(xk + (size_t)(b*NSEQ + krow_[fm])*32 + l4*8);

  stage(0, 0);
  __syncthreads();

  for (int it = 0; it < NSEQ/64; it++){
    const int bi = it & 1;
    const int mt = it*64;
    if (it + 1 < NSEQ/64){
      stage(bi^1, mt + 64);
      #pragma unroll
      for (int fm=0; fm<4; fm++)
        xknxt[fm] = *(const h8*)(xk + (size_t)(b*NSEQ + mt + 64 + krow_[fm])*32 + l4*8);
    }

    // scores (swapped): S'[fq][fm][r] for m-row rho(fm, l4*4+r), q = l15
    // S = qk*cqk (folded into Q) + sig2l * exp2(-dist2*e2c (folded into xq))
    f4 S[2][4];
    #pragma unroll
    for (int fm=0; fm<4; fm++){
      const int krow = krow_[fm];
      const int g    = (krow & 3) | (((krow >> 3) & 1) << 2);
      h8 kb0 = *(const h8*)&sK[bi][krow*64 + ((l4      ^ g))*8];
      h8 kb1 = *(const h8*)&sK[bi][krow*64 + (((4+l4) ^ g))*8];
      #pragma unroll
      for (int fq=0; fq<2; fq++){
        f4 s, xd;
        #pragma unroll
        for (int r=0;r<4;r++){ s[r]=0.f; xd[r]=0.f; }
        s  = mfma_h(kb0, qf[fq][0], s);
        s  = mfma_h(kb1, qf[fq][1], s);
        xd = mfma_h(xkf[fm], xqf[fq], xd);         // = -dist2*e2c
        #pragma unroll
        for (int r=0;r<4;r++)
          S[fq][fm][r] = s[r] + sig2l*__builtin_amdgcn_exp2f(xd[r]);
      }
    }

    // softmax (log2 domain), defer-max thr = 4*log2e = 5.77
    h8 pa[2][2];
    #pragma unroll
    for (int fq=0; fq<2; fq++){
      float tm = S[fq][0][0];
      #pragma unroll
      for (int fm=0; fm<4; fm++)
        #pragma unroll
        for (int r=0;r<4;r++) tm = fmaxf(tm, S[fq][fm][r]);
      tm = fmaxf(tm, __shfl_xor(tm, 16));
      tm = fmaxf(tm, __shfl_xor(tm, 32));
      int nd = tm > mrun[fq] + 5.7708f;
      if (__any(nd)){
        float mn = fmaxf(mrun[fq], tm);
        float sc = __builtin_amdgcn_exp2f(mrun[fq] - mn);   // per q = l15
        mrun[fq] = mn;
        float scr[4];
        #pragma unroll
        for (int r=0;r<4;r++) scr[r] = __shfl(sc, (l4<<2) + r);  // q = l4*4+r
        #pragma unroll
        for (int r=0;r<4;r++) lacc[fq][r] *= scr[r];
        #pragma unroll
        for (int fd=0; fd<4; fd++)
          #pragma unroll
          for (int r=0;r<4;r++){
            ctx[fq][fd][r] *= scr[r];
            var[fq][fd][r] *= scr[r]*scr[r];
          }
      }
      // P = exp2(S' - m'); in-lane repack: slot(ks=fm>>1, j=(fm&1)*4+r)
      // -> m = ks*32+l4*8+j.  cvt_pkrtz packs pairs straight into the h8.
      #pragma unroll
      for (int ks=0; ks<2; ks++){
        h2v q0 = pk_f16(__builtin_amdgcn_exp2f(S[fq][2*ks][0] - mrun[fq]),
                        __builtin_amdgcn_exp2f(S[fq][2*ks][1] - mrun[fq]));
        h2v q1 = pk_f16(__builtin_amdgcn_exp2f(S[fq][2*ks][2] - mrun[fq]),
                        __builtin_amdgcn_exp2f(S[fq][2*ks][3] - mrun[fq]));
        h2v q2 = pk_f16(__builtin_amdgcn_exp2f(S[fq][2*ks+1][0] - mrun[fq]),
                        __builtin_amdgcn_exp2f(S[fq][2*ks+1][1] - mrun[fq]));
        h2v q3 = pk_f16(__builtin_amdgcn_exp2f(S[fq][2*ks+1][2] - mrun[fq]),
                        __builtin_amdgcn_exp2f(S[fq][2*ks+1][3] - mrun[fq]));
        pa[fq][ks] = (h8){q0[0],q0[1],q1[0],q1[1],q2[0],q2[1],q3[0],q3[1]};
      }
    }

    // PV: ctx += P@V, var += P^2@Vv, l += P@1
    #pragma unroll
    for (int ks=0; ks<2; ks++){
      h8 pa2[2];
      #pragma unroll
      for (int fq=0; fq<2; fq++){
        pa2[fq] = pa[fq][ks]*pa[fq][ks];
        lacc[fq] = mfma_h(pa[fq][ks], ones, lacc[fq]);
      }
      #pragma unroll
      for (int fd=0; fd<4; fd++){
        int drow = fd*16 + l15;
        int ck = (ks*4 + l4) ^ (drow & 7);
        h8 vb  = *(const h8*)&sV[bi][drow*64 + ck*8];
        h8 vvb = *(const h8*)&sVv[bi][drow*64 + ck*8];
        #pragma unroll
        for (int fq=0; fq<2; fq++){
          ctx[fq][fd] = mfma_h(pa[fq][ks], vb,  ctx[fq][fd]);
          var[fq][fd] = mfma_h(pa2[fq],    vvb, var[fq][fd]);
        }
      }
    }
    __syncthreads();
    #pragma unroll
    for (int fm=0; fm<4; fm++) xkf[fm] = xknxt[fm];
  }

  // epilogue: normalize; write ctx f16 + var f32 (line-grouped)
  #pragma unroll
  for (int fq=0; fq<2; fq++)
    #pragma unroll
    for (int r=0;r<4;r++){
      int t = t0 + wq + fq*16 + l4*4 + r;
      float linv = 1.f / lacc[fq][r];
      size_t base = (size_t)t*D_MODEL + h*DK + l15;
      float c[4];
      #pragma unroll
      for (int fd=0; fd<4; fd++) c[fd] = ctx[fq][fd][r] * linv;
      #pragma unroll
      for (int fd=0; fd<4; fd++) ctx_out[base + fd*16] = (_Float16)c[fd];
      #pragma unroll
      for (int fd=0; fd<4; fd++) var_out[base + fd*16] = var[fq][fd][r] * linv * linv;
    }
}

// ---------------- host launch ----------------

extern "C" void kernel_launch(void* const* d_in, const int* in_sizes, int n_in,
                              void* d_out, int out_size, void* d_ws, size_t ws_size,
                              hipStream_t stream){
  (void)in_sizes; (void)n_in; (void)out_size; (void)ws_size;
  const float* H      = (const float*)d_in[0];
  const float* x_raw  = (const float*)d_in[1];
  const float* Wq_mu  = (const float*)d_in[2];
  const float* bq_mu  = (const float*)d_in[4];
  const float* Wk_mu  = (const float*)d_in[6];
  const float* bk_mu  = (const float*)d_in[8];
  const float* Wv_mu  = (const float*)d_in[10];
  const float* Wv_rho = (const float*)d_in[11];
  const float* bv_mu  = (const float*)d_in[12];
  const float* bv_rho = (const float*)d_in[13];
  const float* Wo_mu  = (const float*)d_in[14];
  const float* Wo_rho = (const float*)d_in[15];
  const float* bo_mu  = (const float*)d_in[16];
  const float* bo_rho = (const float*)d_in[17];
  const float* lsf    = (const float*)d_in[18];
  const float* lln    = (const float*)d_in[19];

  char* ws = (char*)d_ws;
  const size_t MB = 1024*1024;
  _Float16* Hh    = (_Float16*)(ws + 0*MB);     // 16MB
  _Float16* H2h   = (_Float16*)(ws + 16*MB);    // 16MB
  _Float16* Wcat  = (_Float16*)(ws + 32*MB);    // 8MB: [Wq|Wk|Wv|Wvs2] rows
  _Float16* Wocat = (_Float16*)(ws + 40*MB);    // 4MB: [Wo|Wos2] rows
  _Float16* Qh    = (_Float16*)(ws + 46*MB);    // 16MB
  _Float16* Kh    = (_Float16*)(ws + 62*MB);    // 16MB
  _Float16* Vt    = (_Float16*)(ws + 78*MB);    // 16MB, transposed [b][o][n]
  _Float16* Vvt   = (_Float16*)(ws + 94*MB);    // 16MB
  _Float16* ctxh  = (_Float16*)(ws + 110*MB);   // 16MB
  _Float16* xk    = (_Float16*)(ws + 142*MB);   // 512KB
  _Float16* xqb   = (_Float16*)(ws + 142*MB + 512*1024);  // 512KB

  float* out_mean = (float*)d_out;
  float* out_var  = out_mean + (size_t)TOK*D_MODEL;

  // prep (single launch: 6144 W-blocks + 8192 H-blocks + 32 x-blocks)
  prep_all<<<14368, 256, 0, stream>>>(Wq_mu, Wk_mu, Wv_mu, Wv_rho, Wo_mu, Wo_rho,
      H, x_raw, Wcat, Wocat, Hh, H2h, xk, xqb);

  // fused projections: Q | K | V | Vv in one launch (grid 64 x 32)
  gemm_fused<0><<<2048, 256, 0, stream>>>(Hh, H2h, Wcat,
      bq_mu, bk_mu, bv_mu, bv_rho,
      Qh, Kh, Vt, Vvt, nullptr, nullptr);

  // attention (writes ctxh f16 and var_attn into out_var)
  attn_kernel<<<1024, 256, 0, stream>>>(Qh, Kh, Vt, Vvt, xk, xqb, lsf, lln,
      ctxh, out_var);

  // fused output projections: out_mean | out_var (grid 64 x 16)
  // seg1 squares ctxh fragments in-register (ctx2 buffer eliminated)
  gemm_fused<1><<<1024, 256, 0, stream>>>(ctxh, nullptr, Wocat,
      bo_mu, bo_rho, nullptr, nullptr,
      nullptr, nullptr, nullptr, nullptr, out_mean, out_var);
}

// Round 14
// 246.569 us; speedup vs baseline: 1.9304x; 1.0415x over previous
//
#include <hip/hip_runtime.h>
#include <hip/hip_bf16.h>
#include <stdint.h>

// Bayesian MHA forward for MI355X (round 14).
// r13 + GEMM BK 64 -> 128: 8 drains/block (was 16), 64 MFMAs per drain.
// m132's BK=128 regression was an occupancy 3->2 cliff; we're already at
// 2 blocks/CU (VGPR-bound), and 64KB LDS still fits 2 -> no cliff here.
// 16-chunk XOR swizzle; accumulation order unchanged (bitwise-identical).

#define D_MODEL 1024
#define NSEQ    1024
#define BATCH   8
#define NHEADS  16
#define DK      64
#define TOK     8192   // BATCH*NSEQ

typedef _Float16  h8  __attribute__((ext_vector_type(8)));
typedef _Float16  h4  __attribute__((ext_vector_type(4)));
typedef _Float16  h2v __attribute__((ext_vector_type(2)));
typedef __fp16    g2  __attribute__((ext_vector_type(2)));
typedef float     f4  __attribute__((ext_vector_type(4)));

__device__ __forceinline__ f4 mfma_h(h8 a, h8 b, f4 c){
  return __builtin_amdgcn_mfma_f32_16x16x32_f16(a, b, c, 0, 0, 0);
}

__device__ __forceinline__ h2v pk_f16(float a, float b){
  g2 t = __builtin_amdgcn_cvt_pkrtz(a, b);
  return __builtin_bit_cast(h2v, t);
}

// global -> LDS async copy, 16B per lane. LDS dest must be (uniform base + lane*16).
__device__ __forceinline__ void async_copy16(void* lds, const void* g){
  __builtin_amdgcn_global_load_lds(
      (const __attribute__((address_space(1))) unsigned int*)(uintptr_t)g,
      (__attribute__((address_space(3))) unsigned int*)(unsigned int)(uintptr_t)lds,
      16, 0, 0);
}

__device__ __forceinline__ float softplusf(float x){
  return (x > 20.f) ? x : log1pf(__expf(x));
}

// ---------------- prep (single launch) ----------------
// bids [0,6144): weights -> 6 segments of 1M: f16(Wq|Wk|Wv|sp2(Wvr)) -> Wcat,
//                f16(Wo|sp2(Wor)) -> Wocat
// bids [6144,14336): Hh = f16(H), H2h = f16(H*H)
// bids [14336,14368): xk/xq padded RBF rows (256 tokens/block)
//   xk[t][32] = [x(16), x2hi, x2lo, 1, 1, 0(12)]
//   xq[t][32] = [2x(16), -1, -1, -x2hi, -x2lo, 0(12)]
//   => dot(xk[m], xq[q]) = -dist2(m,q)
__global__ __launch_bounds__(256) void prep_all(
    const float* __restrict__ Wq, const float* __restrict__ Wk,
    const float* __restrict__ Wv, const float* __restrict__ Wvr,
    const float* __restrict__ Wo, const float* __restrict__ Wor,
    const float* __restrict__ H, const float* __restrict__ x,
    _Float16* __restrict__ Wcat, _Float16* __restrict__ Wocat,
    _Float16* __restrict__ Hh, _Float16* __restrict__ H2h,
    _Float16* __restrict__ xk, _Float16* __restrict__ xq)
{
  const int bid = blockIdx.x;
  if (bid < 6144){
    const int seg = bid >> 10;
    const int i   = ((bid & 1023)*256 + threadIdx.x)*4;
    const float* src = seg==0 ? Wq : seg==1 ? Wk : seg==2 ? Wv : seg==3 ? Wvr : seg==4 ? Wo : Wor;
    _Float16* dst = (seg < 4) ? (Wcat + (size_t)seg*1048576)
                              : (Wocat + (size_t)(seg-4)*1048576);
    const bool sp2 = (seg==3) || (seg==5);
    float4 v = *(const float4*)(src + i);
    float vv[4] = {v.x, v.y, v.z, v.w};
    #pragma unroll
    for (int j=0;j<4;j++){
      float f = vv[j];
      if (sp2){ float s = softplusf(f); f = s*s; }
      dst[i+j] = (_Float16)f;
    }
  } else if (bid < 14336){
    int i = ((bid - 6144)*256 + threadIdx.x)*4;
    float4 v = *(const float4*)(H + i);
    float vv[4] = {v.x, v.y, v.z, v.w};
    #pragma unroll
    for (int j=0;j<4;j++){
      Hh[i+j]  = (_Float16)vv[j];
      H2h[i+j] = (_Float16)(vv[j]*vv[j]);
    }
  } else {
    int t = (bid - 14336)*256 + threadIdx.x;
    const float* p = x + (size_t)t*16;
    _Float16 a[32], bb[32];
    float s = 0.f;
    #pragma unroll
    for (int j=0;j<16;j++){
      float f = p[j];
      a[j]  = (_Float16)f;
      bb[j] = (_Float16)(2.f*f);
      s += f*f;
    }
    _Float16 shi = (_Float16)s;
    _Float16 slo = (_Float16)(s - (float)shi);
    a[16]=shi; a[17]=slo; a[18]=(_Float16)1.f; a[19]=(_Float16)1.f;
    bb[16]=(_Float16)-1.f; bb[17]=(_Float16)-1.f; bb[18]=-shi; bb[19]=-slo;
    #pragma unroll
    for (int j=20;j<32;j++){ a[j]=(_Float16)0.f; bb[j]=(_Float16)0.f; }
    #pragma unroll
    for (int j=0;j<4;j++){
      *(h8*)(xk + (size_t)t*32 + j*8) = *(const h8*)&a[j*8];
      *(h8*)(xq + (size_t)t*32 + j*8) = *(const h8*)&bb[j*8];
    }
  }
}

// ---------------- fused GEMM: C = A @ Wcat^T (+bias) ----------------
// MODE 0: projections. 4 segments of 1024 cols: Q, K, V, Vv.
//   A = Hh (segs 0-2) or H2h (seg 3). Q (scaled by cqk) / K stored
//   [row][col] f16; V/Vv transposed to [b][col][row&1023] via LDS transpose.
// MODE 1: outputs. 2 segments: out_mean (f32), out_var (f32, += addend).
//   A = ctxh for BOTH segs; seg1 squares A fragments in-register.
// 128x128 tile, BK=128, 4 waves (2x2). 16-chunk XOR-swizzled rows.
// XCD-grouped swizzle.
template<int MODE>
__global__ __launch_bounds__(256) void gemm_fused(
    const _Float16* __restrict__ A0, const _Float16* __restrict__ A1,
    const _Float16* __restrict__ Wcat,
    const float* __restrict__ bias0, const float* __restrict__ bias1,
    const float* __restrict__ bias2, const float* __restrict__ bias3,
    _Float16* __restrict__ Qo, _Float16* __restrict__ Ko,
    _Float16* __restrict__ Vto, _Float16* __restrict__ Vvto,
    float* __restrict__ meanO, float* __restrict__ varO)
{
  constexpr int NBN = (MODE==0) ? 32 : 16;     // n-tiles (4096 or 2048 cols)
  __shared__ _Float16 smem[32768];             // sA | sB (BK=128); transpose reuses front
  _Float16* sA = smem;
  _Float16* sB = smem + 16384;
  const int tid = threadIdx.x;
  const int lane = tid & 63;
  const int wid  = tid >> 6;
  const int wm = wid >> 1, wn = wid & 1;
  const int l15 = lane & 15, l4 = lane >> 4;
  // XCD-grouped bijective swizzle: XCD x owns bm in [8x,8x+8); within the
  // XCD, 8bm x 8bn groups keep A(2MB)+B(2MB) ~ L2-resident.
  const int bid = blockIdx.x;
  const int x   = bid & 7;
  const int idx = bid >> 3;
  const int grp = idx >> 6;                    // 0..(NBN/8-1)
  const int inr = idx & 63;
  const int bm  = (x << 3) + (inr & 7);
  const int bn  = (grp << 3) + (inr >> 3);
  const int row0 = bm << 7, col0 = bn << 7;
  const int seg = col0 >> 10;

  const _Float16* A = (MODE==0) ? (seg < 3 ? A0 : A1) : A0;
  const bool sqA = (MODE==1) && (seg==1);
  const _Float16* B = Wcat + (size_t)col0 * 1024;

  f4 acc[4][4];
  #pragma unroll
  for (int i=0;i<4;i++)
    #pragma unroll
    for (int j=0;j<4;j++)
      #pragma unroll
      for (int r=0;r<4;r++) acc[i][j][r] = 0.f;

  for (int kt = 0; kt < 1024; kt += 128){
    __syncthreads();
    // stage A+B 128x128 tiles: 2048 chunks each, 8+8 copies/thread
    #pragma unroll
    for (int k=0;k<8;k++){
      int c  = tid + k*256;
      int rg = c >> 4, ch = c & 15;
      int sw = ((ch ^ (rg & 15)) << 3);
      async_copy16(&sA[c*8], A + (size_t)(row0+rg)*1024 + kt + sw);
      async_copy16(&sB[c*8], B + (size_t)rg*1024 + kt + sw);
    }
    __syncthreads();

    #pragma unroll
    for (int ks=0; ks<4; ks++){
      h8 a[4], b[4];
      #pragma unroll
      for (int mf=0; mf<4; mf++){
        int r  = (wm<<6) + (mf<<4) + l15;
        int ck = (ks*4 + l4) ^ (r & 15);
        a[mf] = *(const h8*)&sA[r*128 + ck*8];
        if (sqA) a[mf] = a[mf]*a[mf];
      }
      #pragma unroll
      for (int nf=0; nf<4; nf++){
        int r  = (wn<<6) + (nf<<4) + l15;
        int ck = (ks*4 + l4) ^ (r & 15);
        b[nf] = *(const h8*)&sB[r*128 + ck*8];
      }
      #pragma unroll
      for (int mf=0; mf<4; mf++)
        #pragma unroll
        for (int nf=0; nf<4; nf++)
          acc[mf][nf] = mfma_h(a[mf], b[nf], acc[mf][nf]);
    }
  }

  if (MODE==0 && seg >= 2){
    // --- V/Vv: transpose through LDS (XOR-swizzled), coalesced 16B stores ---
    _Float16* T = (seg==2) ? Vto : Vvto;
    const size_t tbase = ((size_t)(row0>>10)<<20)
                       + (size_t)(col0 & 1023)*1024 + (row0 & 1023);
    const int o  = tid >> 1;        // output row (= C col), 0..127
    const int hf = tid & 1;
    #pragma unroll
    for (int rh=0; rh<2; rh++){     // half-passes over C rows [rh*64, rh*64+64)
      __syncthreads();              // protect smem vs K-loop / prev pass reads
      if (wm == rh){
        #pragma unroll
        for (int nf=0; nf<4; nf++){
          int col = (wn<<6) + (nf<<4) + l15;          // 0..127
          float bb2 = (seg==2) ? bias2[(col0 + col) & 1023]
                               : bias3[(col0 + col) & 1023];
          float bv;
          if (seg==3){ float s = softplusf(bb2); bv = s*s; } else bv = bb2;
          #pragma unroll
          for (int mf=0; mf<4; mf++){
            int n   = (mf<<4) + (l4<<2);              // row-in-half, 4-aligned
            int nsw = n ^ ((col & 7) << 3);
            h4 hv;
            #pragma unroll
            for (int r=0;r<4;r++) hv[r] = (_Float16)(acc[mf][nf][r] + bv);
            *(h4*)&smem[col*64 + nsw] = hv;
          }
        }
      }
      __syncthreads();
      #pragma unroll
      for (int j=0; j<4; j++){
        int n   = hf*8 + j*16;                        // 8-aligned
        int nsw = n ^ ((o & 7) << 3);
        h8 v = *(const h8*)&smem[o*64 + nsw];
        *(h8*)(T + tbase + (size_t)o*1024 + rh*64 + n) = v;
      }
    }
    return;
  }

  // --- direct epilogues (Q/K f16 rows; MODE1 f32 outputs) ---
  const float* bias = (seg==0) ? bias0 : bias1;
  const bool sp2 = (MODE==1) && (seg==1);
  const float CQK = 0.18033688f;   // 0.125 * log2(e), folded into Q

  #pragma unroll
  for (int nf=0; nf<4; nf++){
    int colg = col0 + (wn<<6) + (nf<<4) + l15;
    int colm = colg & 1023;
    float bb = bias[colm];
    float bv = sp2 ? ({ float s = softplusf(bb); s*s; }) : bb;
    #pragma unroll
    for (int mf=0; mf<4; mf++){
      int rbase = row0 + (wm<<6) + (mf<<4) + (l4<<2);
      #pragma unroll
      for (int r=0;r<4;r++){
        int row = rbase + r;
        float v = acc[mf][nf][r] + bv;
        if (MODE==0){
          if (seg==0) Qo[(size_t)row*1024 + colm] = (_Float16)(v * CQK);
          else        Ko[(size_t)row*1024 + colm] = (_Float16)v;
        } else {
          size_t idxo = (size_t)row*1024 + colm;
          if (seg==0) meanO[idxo] = v;
          else        varO[idxo] = v + varO[idxo];
        }
      }
    }
  }
}

// ---------------- fused attention (flash-style, + RBF scores) ----------------
// 1024 blocks = 8 q-tiles x (B*H), 4 waves x 32 q-rows. All-dbuf staging,
// ONE barrier/iter (lockstep blocks -> L2 reuse). Swapped QK^T with K-row
// permutation rho(fm,w) = (fm&1)*4 + (w&3) + (w>>2)*8 + (fm>>1)*32 so the
// score C-regs repack in-lane straight into PV's A-fragment k-slots.
// Q pre-scaled by cqk; xq pre-scaled by e2c. Raw v_exp_f32 + cvt_pkrtz.
// 2 blocks/CU: 8 bh-groups x 384KB = 3MB per XCD L2 (fits; 3/CU thrashed).
__global__ __launch_bounds__(256, 2) void attn_kernel(
    const _Float16* __restrict__ Qh, const _Float16* __restrict__ Kh,
    const _Float16* __restrict__ Vt, const _Float16* __restrict__ Vvt,
    const _Float16* __restrict__ xk, const _Float16* __restrict__ xq,
    const float* __restrict__ log_sigma_f, const float* __restrict__ log_length,
    _Float16* __restrict__ ctx_out, float* __restrict__ var_out)
{
  const int bid = blockIdx.x;
  const int swz = (bid & 7) * 128 + (bid >> 3);
  const int qt = swz & 7;
  const int bh = swz >> 3;
  const int b  = bh >> 4, h = bh & 15;
  const int tid = threadIdx.x;
  const int lane = tid & 63, wid = tid >> 6;
  const int l15 = lane & 15, l4 = lane >> 4;
  const float L2E   = 1.44269504f;
  const float sig2l = __expf(2.f*log_sigma_f[h]) * L2E;      // sigma_f^2 * log2(e)
  const float e2c   = 0.5f*__expf(-2.f*log_length[h]) * L2E; // 1/(2 l^2) * log2(e)

  __shared__ _Float16 sK[2][4096];   // [m][d] 64x64, g-swizzled
  __shared__ _Float16 sV[2][4096];   // [d][m]
  __shared__ _Float16 sVv[2][4096];  // [d][m]

  const int t0 = b*NSEQ + qt*128;
  const int wq = wid*32;

  // permuted K-row for this lane per fm (constant across tiles)
  int krow_[4];
  #pragma unroll
  for (int fm=0; fm<4; fm++)
    krow_[fm] = ((fm&1)<<2) + (l15&3) + ((l15>>2)<<3) + ((fm>>1)<<5);

  // Q fragments (B-side: lane l15 = q-row); Q already carries cqk
  h8 qf[2][2];
  #pragma unroll
  for (int fq=0; fq<2; fq++)
    #pragma unroll
    for (int ks=0; ks<2; ks++){
      size_t off = (size_t)(t0 + wq + fq*16 + l15)*D_MODEL + h*DK + ks*32 + l4*8;
      qf[fq][ks] = *(const h8*)(Qh + off);
    }
  // RBF Q-side rows, scaled once by e2c (folds the per-score multiply)
  const _Float16 e2ch = (_Float16)e2c;
  h8 xqf[2];
  #pragma unroll
  for (int fq=0; fq<2; fq++){
    xqf[fq] = *(const h8*)(xq + (size_t)(t0 + wq + fq*16 + l15)*32 + l4*8);
    xqf[fq] = xqf[fq] * e2ch;
  }

  h8 ones;
  #pragma unroll
  for (int j=0;j<8;j++) ones[j] = (_Float16)1.f;

  float mrun[2] = {-1e30f, -1e30f};   // log2 domain
  f4 lacc[2], ctx[2][4], var[2][4];
  #pragma unroll
  for (int fq=0; fq<2; fq++){
    #pragma unroll
    for (int r=0;r<4;r++) lacc[fq][r] = 0.f;
    #pragma unroll
    for (int fd=0; fd<4; fd++)
      #pragma unroll
      for (int r=0;r<4;r++){ ctx[fq][fd][r] = 0.f; var[fq][fd][r] = 0.f; }
  }

  // staging: 1536 chunks of 16B (K 512 w/ g-swizzle, V 512, Vv 512)
  auto stage = [&](int bi, int mt){
    #pragma unroll
    for (int k=0;k<6;k++){
      int c = tid + k*256;
      if (k < 2){
        int rg = c >> 3, ch = c & 7;
        int g  = (rg & 3) | (((rg >> 3) & 1) << 2);
        int sw = ((ch ^ g) << 3);
        async_copy16(&sK[bi][c*8], Kh + (size_t)(b*NSEQ + mt + rg)*D_MODEL + h*DK + sw);
      } else if (k < 4){
        int cc = c - 512; int rg = cc >> 3, sw = (((cc & 7) ^ (rg & 7)) << 3);
        async_copy16(&sV[bi][cc*8], Vt + ((size_t)b << 20) + (size_t)(h*DK + rg)*NSEQ + mt + sw);
      } else {
        int cc = c - 1024; int rg = cc >> 3, sw = (((cc & 7) ^ (rg & 7)) << 3);
        async_copy16(&sVv[bi][cc*8], Vvt + ((size_t)b << 20) + (size_t)(h*DK + rg)*NSEQ + mt + sw);
      }
    }
  };

  // xk fragments: current tile (xkf) + next tile (xknxt), register-prefetched
  h8 xkf[4], xknxt[4];
  #pragma unroll
  for (int fm=0; fm<4; fm++)
    xkf[fm] = *(const h8*)(xk + (size_t)(b*NSEQ + krow_[fm])*32 + l4*8);

  stage(0, 0);
  __syncthreads();

  for (int it = 0; it < NSEQ/64; it++){
    const int bi = it & 1;
    const int mt = it*64;
    if (it + 1 < NSEQ/64){
      stage(bi^1, mt + 64);
      #pragma unroll
      for (int fm=0; fm<4; fm++)
        xknxt[fm] = *(const h8*)(xk + (size_t)(b*NSEQ + mt + 64 + krow_[fm])*32 + l4*8);
    }

    // scores (swapped): S'[fq][fm][r] for m-row rho(fm, l4*4+r), q = l15
    // S = qk*cqk (folded into Q) + sig2l * exp2(-dist2*e2c (folded into xq))
    f4 S[2][4];
    #pragma unroll
    for (int fm=0; fm<4; fm++){
      const int krow = krow_[fm];
      const int g    = (krow & 3) | (((krow >> 3) & 1) << 2);
      h8 kb0 = *(const h8*)&sK[bi][krow*64 + ((l4      ^ g))*8];
      h8 kb1 = *(const h8*)&sK[bi][krow*64 + (((4+l4) ^ g))*8];
      #pragma unroll
      for (int fq=0; fq<2; fq++){
        f4 s, xd;
        #pragma unroll
        for (int r=0;r<4;r++){ s[r]=0.f; xd[r]=0.f; }
        s  = mfma_h(kb0, qf[fq][0], s);
        s  = mfma_h(kb1, qf[fq][1], s);
        xd = mfma_h(xkf[fm], xqf[fq], xd);         // = -dist2*e2c
        #pragma unroll
        for (int r=0;r<4;r++)
          S[fq][fm][r] = s[r] + sig2l*__builtin_amdgcn_exp2f(xd[r]);
      }
    }

    // softmax (log2 domain), defer-max thr = 4*log2e = 5.77
    h8 pa[2][2];
    #pragma unroll
    for (int fq=0; fq<2; fq++){
      float tm = S[fq][0][0];
      #pragma unroll
      for (int fm=0; fm<4; fm++)
        #pragma unroll
        for (int r=0;r<4;r++) tm = fmaxf(tm, S[fq][fm][r]);
      tm = fmaxf(tm, __shfl_xor(tm, 16));
      tm = fmaxf(tm, __shfl_xor(tm, 32));
      int nd = tm > mrun[fq] + 5.7708f;
      if (__any(nd)){
        float mn = fmaxf(mrun[fq], tm);
        float sc = __builtin_amdgcn_exp2f(mrun[fq] - mn);   // per q = l15
        mrun[fq] = mn;
        float scr[4];
        #pragma unroll
        for (int r=0;r<4;r++) scr[r] = __shfl(sc, (l4<<2) + r);  // q = l4*4+r
        #pragma unroll
        for (int r=0;r<4;r++) lacc[fq][r] *= scr[r];
        #pragma unroll
        for (int fd=0; fd<4; fd++)
          #pragma unroll
          for (int r=0;r<4;r++){
            ctx[fq][fd][r] *= scr[r];
            var[fq][fd][r] *= scr[r]*scr[r];
          }
      }
      // P = exp2(S' - m'); in-lane repack: slot(ks=fm>>1, j=(fm&1)*4+r)
      // -> m = ks*32+l4*8+j.  cvt_pkrtz packs pairs straight into the h8.
      #pragma unroll
      for (int ks=0; ks<2; ks++){
        h2v q0 = pk_f16(__builtin_amdgcn_exp2f(S[fq][2*ks][0] - mrun[fq]),
                        __builtin_amdgcn_exp2f(S[fq][2*ks][1] - mrun[fq]));
        h2v q1 = pk_f16(__builtin_amdgcn_exp2f(S[fq][2*ks][2] - mrun[fq]),
                        __builtin_amdgcn_exp2f(S[fq][2*ks][3] - mrun[fq]));
        h2v q2 = pk_f16(__builtin_amdgcn_exp2f(S[fq][2*ks+1][0] - mrun[fq]),
                        __builtin_amdgcn_exp2f(S[fq][2*ks+1][1] - mrun[fq]));
        h2v q3 = pk_f16(__builtin_amdgcn_exp2f(S[fq][2*ks+1][2] - mrun[fq]),
                        __builtin_amdgcn_exp2f(S[fq][2*ks+1][3] - mrun[fq]));
        pa[fq][ks] = (h8){q0[0],q0[1],q1[0],q1[1],q2[0],q2[1],q3[0],q3[1]};
      }
    }

    // PV: ctx += P@V, var += P^2@Vv, l += P@1
    #pragma unroll
    for (int ks=0; ks<2; ks++){
      h8 pa2[2];
      #pragma unroll
      for (int fq=0; fq<2; fq++){
        pa2[fq] = pa[fq][ks]*pa[fq][ks];
        lacc[fq] = mfma_h(pa[fq][ks], ones, lacc[fq]);
      }
      #pragma unroll
      for (int fd=0; fd<4; fd++){
        int drow = fd*16 + l15;
        int ck = (ks*4 + l4) ^ (drow & 7);
        h8 vb  = *(const h8*)&sV[bi][drow*64 + ck*8];
        h8 vvb = *(const h8*)&sVv[bi][drow*64 + ck*8];
        #pragma unroll
        for (int fq=0; fq<2; fq++){
          ctx[fq][fd] = mfma_h(pa[fq][ks], vb,  ctx[fq][fd]);
          var[fq][fd] = mfma_h(pa2[fq],    vvb, var[fq][fd]);
        }
      }
    }
    __syncthreads();
    #pragma unroll
    for (int fm=0; fm<4; fm++) xkf[fm] = xknxt[fm];
  }

  // epilogue: normalize; write ctx f16 + var f32 (line-grouped)
  #pragma unroll
  for (int fq=0; fq<2; fq++)
    #pragma unroll
    for (int r=0;r<4;r++){
      int t = t0 + wq + fq*16 + l4*4 + r;
      float linv = 1.f / lacc[fq][r];
      size_t base = (size_t)t*D_MODEL + h*DK + l15;
      float c[4];
      #pragma unroll
      for (int fd=0; fd<4; fd++) c[fd] = ctx[fq][fd][r] * linv;
      #pragma unroll
      for (int fd=0; fd<4; fd++) ctx_out[base + fd*16] = (_Float16)c[fd];
      #pragma unroll
      for (int fd=0; fd<4; fd++) var_out[base + fd*16] = var[fq][fd][r] * linv * linv;
    }
}

// ---------------- host launch ----------------

extern "C" void kernel_launch(void* const* d_in, const int* in_sizes, int n_in,
                              void* d_out, int out_size, void* d_ws, size_t ws_size,
                              hipStream_t stream){
  (void)in_sizes; (void)n_in; (void)out_size; (void)ws_size;
  const float* H      = (const float*)d_in[0];
  const float* x_raw  = (const float*)d_in[1];
  const float* Wq_mu  = (const float*)d_in[2];
  const float* bq_mu  = (const float*)d_in[4];
  const float* Wk_mu  = (const float*)d_in[6];
  const float* bk_mu  = (const float*)d_in[8];
  const float* Wv_mu  = (const float*)d_in[10];
  const float* Wv_rho = (const float*)d_in[11];
  const float* bv_mu  = (const float*)d_in[12];
  const float* bv_rho = (const float*)d_in[13];
  const float* Wo_mu  = (const float*)d_in[14];
  const float* Wo_rho = (const float*)d_in[15];
  const float* bo_mu  = (const float*)d_in[16];
  const float* bo_rho = (const float*)d_in[17];
  const float* lsf    = (const float*)d_in[18];
  const float* lln    = (const float*)d_in[19];

  char* ws = (char*)d_ws;
  const size_t MB = 1024*1024;
  _Float16* Hh    = (_Float16*)(ws + 0*MB);     // 16MB
  _Float16* H2h   = (_Float16*)(ws + 16*MB);    // 16MB
  _Float16* Wcat  = (_Float16*)(ws + 32*MB);    // 8MB: [Wq|Wk|Wv|Wvs2] rows
  _Float16* Wocat = (_Float16*)(ws + 40*MB);    // 4MB: [Wo|Wos2] rows
  _Float16* Qh    = (_Float16*)(ws + 46*MB);    // 16MB
  _Float16* Kh    = (_Float16*)(ws + 62*MB);    // 16MB
  _Float16* Vt    = (_Float16*)(ws + 78*MB);    // 16MB, transposed [b][o][n]
  _Float16* Vvt   = (_Float16*)(ws + 94*MB);    // 16MB
  _Float16* ctxh  = (_Float16*)(ws + 110*MB);   // 16MB
  _Float16* xk    = (_Float16*)(ws + 142*MB);   // 512KB
  _Float16* xqb   = (_Float16*)(ws + 142*MB + 512*1024);  // 512KB

  float* out_mean = (float*)d_out;
  float* out_var  = out_mean + (size_t)TOK*D_MODEL;

  // prep (single launch: 6144 W-blocks + 8192 H-blocks + 32 x-blocks)
  prep_all<<<14368, 256, 0, stream>>>(Wq_mu, Wk_mu, Wv_mu, Wv_rho, Wo_mu, Wo_rho,
      H, x_raw, Wcat, Wocat, Hh, H2h, xk, xqb);

  // fused projections: Q | K | V | Vv in one launch (grid 64 x 32)
  gemm_fused<0><<<2048, 256, 0, stream>>>(Hh, H2h, Wcat,
      bq_mu, bk_mu, bv_mu, bv_rho,
      Qh, Kh, Vt, Vvt, nullptr, nullptr);

  // attention (writes ctxh f16 and var_attn into out_var)
  attn_kernel<<<1024, 256, 0, stream>>>(Qh, Kh, Vt, Vvt, xk, xqb, lsf, lln,
      ctxh, out_var);

  // fused output projections: out_mean | out_var (grid 64 x 16)
  // seg1 squares ctxh fragments in-register (ctx2 buffer eliminated)
  gemm_fused<1><<<1024, 256, 0, stream>>>(ctxh, nullptr, Wocat,
      bo_mu, bo_rho, nullptr, nullptr,
      nullptr, nullptr, nullptr, nullptr, out_mean, out_var);
}